// Round 5
// baseline (3175.105 us; speedup 1.0000x reference)
//
#include <hip/hip_runtime.h>
#include <hip/hip_bf16.h>

// MotherNet forward — R5: R2 tiled pipeline, OUTPUT AS FLOAT32 (the R0-R4 bug:
// output was written as bf16; harness buffer is f32 per reference dtype).

#define BATCH  2
#define FDIM   100
#define EDIM   512
#define NHEADS 8
#define HD     64
#define NHID   1024
#define NLAYER 4
#define HDIM   128
#define NOUTD  10
#define DECD   2048
#define SEPP   1024
#define TOTALW 30730
#define NTOK   2048

__device__ __forceinline__ float nanfix(float v) {
    if (isnan(v)) return 0.f;
    if (isinf(v)) return v > 0.f ? 3.4028234663852886e38f : -3.4028234663852886e38f;
    return v;
}

// ---------------------------------------------------------------------------
// Generic batched f32 GEMM: C = act(alpha * A @ B^T + bias)
// 64x64 tile, 256 threads, 4x4 per thread, K-tile 16. btrans: B is [K,N].
// ---------------------------------------------------------------------------
__global__ __launch_bounds__(256) void gemm_f32(
    const float* __restrict__ A, int lda, long long s1A, long long s2A,
    const float* __restrict__ B, int ldb, long long s1B, long long s2B, int btrans,
    float* __restrict__ C, int ldc, long long s1C, long long s2C,
    int c2, int M, int N, int K, float alpha,
    const float* __restrict__ bias, int act)
{
    int z = blockIdx.z;
    long long offA = (long long)(z / c2) * s1A + (long long)(z % c2) * s2A;
    long long offB = (long long)(z / c2) * s1B + (long long)(z % c2) * s2B;
    long long offC = (long long)(z / c2) * s1C + (long long)(z % c2) * s2C;

    __shared__ float As[16][65];
    __shared__ float Bs[16][65];

    int tid = threadIdx.x;
    int tx = tid & 15, ty = tid >> 4;
    int mBase = blockIdx.y * 64, nBase = blockIdx.x * 64;

    float acc[4][4] = {};

    for (int k0 = 0; k0 < K; k0 += 16) {
        int kk = tid & 15, rr = tid >> 4;
        #pragma unroll
        for (int i = 0; i < 4; i++) {
            int m = rr + 16 * i;
            int gm = mBase + m; if (gm >= M) gm = M - 1;
            As[kk][m] = A[offA + (long long)gm * lda + (k0 + kk)];
        }
        if (!btrans) {
            #pragma unroll
            for (int i = 0; i < 4; i++) {
                int n = rr + 16 * i;
                int gn = nBase + n; if (gn >= N) gn = N - 1;
                Bs[kk][n] = B[offB + (long long)gn * ldb + (k0 + kk)];
            }
        } else {
            int nn = tid & 63, ww = tid >> 6;
            #pragma unroll
            for (int i = 0; i < 4; i++) {
                int kx = ww * 4 + i;
                int gn = nBase + nn; if (gn >= N) gn = N - 1;
                Bs[kx][nn] = B[offB + (long long)(k0 + kx) * ldb + gn];
            }
        }
        __syncthreads();
        #pragma unroll
        for (int k = 0; k < 16; k++) {
            float a[4], b[4];
            #pragma unroll
            for (int i = 0; i < 4; i++) a[i] = As[k][ty + 16 * i];
            #pragma unroll
            for (int j = 0; j < 4; j++) b[j] = Bs[k][tx + 16 * j];
            #pragma unroll
            for (int i = 0; i < 4; i++)
                #pragma unroll
                for (int j = 0; j < 4; j++)
                    acc[i][j] = fmaf(a[i], b[j], acc[i][j]);
        }
        __syncthreads();
    }

    #pragma unroll
    for (int i = 0; i < 4; i++) {
        int m = mBase + ty + 16 * i;
        if (m >= M) continue;
        #pragma unroll
        for (int j = 0; j < 4; j++) {
            int n = nBase + tx + 16 * j;
            if (n >= N) continue;
            float c = acc[i][j] * alpha;
            if (bias) c += bias[n];
            if (act == 1) {
                c = fmaxf(c, 0.f);
            } else if (act == 2) {  // jax.nn.gelu approximate=True (tanh form)
                float u = 0.7978845608028654f * (c + 0.044715f * c * c * c);
                c = 0.5f * c * (1.f + tanhf(u));
            }
            C[offC + (long long)m * ldc + n] = c;
        }
    }
}

__global__ __launch_bounds__(512) void encoder_kernel(
    const float* __restrict__ x, const float* __restrict__ y,
    const float* __restrict__ enc_w, const float* __restrict__ enc_b,
    const float* __restrict__ yenc_w, const float* __restrict__ yenc_b,
    float* __restrict__ h)
{
    int t = blockIdx.x;
    __shared__ float xs[FDIM];
    int tid = threadIdx.x;
    if (tid < FDIM) xs[tid] = nanfix(x[(long long)t * FDIM + tid]);
    __syncthreads();
    float yv = y[t];
    int e = tid;
    float acc = enc_b[e] + yv * yenc_w[e] + yenc_b[e];
    const float* wr = enc_w + (long long)e * FDIM;
    #pragma unroll 4
    for (int f = 0; f < FDIM; f++) acc = fmaf(xs[f], wr[f], acc);
    h[(long long)t * EDIM + e] = acc;
}

// out = LN(a + r) * g + beta  (rows of E=512). a may alias out.
__global__ __launch_bounds__(256) void add_ln_kernel(
    const float* a, const float* __restrict__ r,
    const float* __restrict__ g, const float* __restrict__ be,
    float* out)
{
    int row = blockIdx.x;
    int tid = threadIdx.x;
    const float* pa = a + (long long)row * EDIM;
    const float* pr = r + (long long)row * EDIM;
    float v0 = pa[tid] + pr[tid];
    float v1 = pa[tid + 256] + pr[tid + 256];
    float s = v0 + v1, q = v0 * v0 + v1 * v1;
    #pragma unroll
    for (int off = 32; off; off >>= 1) {
        s += __shfl_xor(s, off);
        q += __shfl_xor(q, off);
    }
    __shared__ float ss[4], sq[4];
    int w = tid >> 6, lane = tid & 63;
    if (lane == 0) { ss[w] = s; sq[w] = q; }
    __syncthreads();
    s = ss[0] + ss[1] + ss[2] + ss[3];
    q = sq[0] + sq[1] + sq[2] + sq[3];
    float mean = s * (1.f / EDIM);
    float var = q * (1.f / EDIM) - mean * mean;
    float rstd = rsqrtf(var + 1e-5f);
    float* po = out + (long long)row * EDIM;
    po[tid]       = (v0 - mean) * rstd * g[tid] + be[tid];
    po[tid + 256] = (v1 - mean) * rstd * g[tid + 256] + be[tid + 256];
}

// one-pass softmax over rows of length 1024
__global__ __launch_bounds__(256) void softmax_kernel(float* __restrict__ p)
{
    long long row = blockIdx.x;
    float* pr = p + row * 1024;
    int tid = threadIdx.x;
    float v0 = pr[tid], v1 = pr[tid + 256], v2 = pr[tid + 512], v3 = pr[tid + 768];
    float m = fmaxf(fmaxf(v0, v1), fmaxf(v2, v3));
    #pragma unroll
    for (int off = 32; off; off >>= 1) m = fmaxf(m, __shfl_xor(m, off));
    __shared__ float sm[4];
    __shared__ float ssum[4];
    int w = tid >> 6, lane = tid & 63;
    if (lane == 0) sm[w] = m;
    __syncthreads();
    m = fmaxf(fmaxf(sm[0], sm[1]), fmaxf(sm[2], sm[3]));
    float e0 = __expf(v0 - m), e1 = __expf(v1 - m), e2 = __expf(v2 - m), e3 = __expf(v3 - m);
    float s = e0 + e1 + e2 + e3;
    #pragma unroll
    for (int off = 32; off; off >>= 1) s += __shfl_xor(s, off);
    if (lane == 0) ssum[w] = s;
    __syncthreads();
    s = ssum[0] + ssum[1] + ssum[2] + ssum[3];
    float inv = 1.f / s;
    pr[tid] = e0 * inv; pr[tid + 256] = e1 * inv;
    pr[tid + 512] = e2 * inv; pr[tid + 768] = e3 * inv;
}

__global__ __launch_bounds__(256) void pool_kernel(
    const float* __restrict__ h, float* __restrict__ pooled)
{
    int idx = blockIdx.x * 256 + threadIdx.x;   // 0..1023
    int b = idx / EDIM, e = idx % EDIM;
    float s = 0.f;
    for (int si = 0; si < SEPP; si++)
        s += h[((long long)si * BATCH + b) * EDIM + e];
    pooled[(long long)b * EDIM + e] = s * (1.f / SEPP);
}

// wave-per-row dual dot (K multiple of 256), float4-coalesced W stream
__global__ __launch_bounds__(256) void wavedot2_kernel(
    const float* __restrict__ v0, const float* __restrict__ v1,
    const float* __restrict__ W, const float* __restrict__ bias,
    float* __restrict__ out0, float* __restrict__ out1,
    int R, int K, int act)
{
    int gw = (blockIdx.x * 256 + threadIdx.x) >> 6;
    int lane = threadIdx.x & 63;
    int nw = (gridDim.x * 256) >> 6;
    const float4* x0 = (const float4*)v0;
    const float4* x1 = (const float4*)v1;
    for (int r = gw; r < R; r += nw) {
        const float4* w4 = (const float4*)(W + (long long)r * K);
        float a0 = 0.f, a1 = 0.f;
        for (int i = lane; i < (K >> 2); i += 64) {
            float4 w = w4[i];
            float4 p = x0[i];
            float4 q = x1[i];
            a0 += w.x * p.x + w.y * p.y + w.z * p.z + w.w * p.w;
            a1 += w.x * q.x + w.y * q.y + w.z * q.z + w.w * q.w;
        }
        #pragma unroll
        for (int off = 32; off; off >>= 1) {
            a0 += __shfl_xor(a0, off);
            a1 += __shfl_xor(a1, off);
        }
        if (lane == 0) {
            float bb = bias[r];
            float o0 = a0 + bb, o1 = a1 + bb;
            if (act == 1) { o0 = fmaxf(o0, 0.f); o1 = fmaxf(o1, 0.f); }
            out0[r] = o0; out1[r] = o1;
        }
    }
}

// Final per-sample MLP; block per eval token; OUTPUT = FLOAT32.
__global__ __launch_bounds__(128) void final_mlp_kernel(
    const float* __restrict__ x, const float* __restrict__ flat,
    float* __restrict__ out)
{
    int t = blockIdx.x;            // 0..2047 = si*B + b
    int b = t & 1;
    int tid = threadIdx.x;
    const float* fl = flat + (long long)b * TOTALW;
    __shared__ float xs[FDIM], t1s[HDIM], t2s[HDIM];
    if (tid < FDIM) xs[tid] = nanfix(x[(long long)(NTOK + t) * FDIM + tid]);
    __syncthreads();
    {
        float acc = fl[tid];                       // b1
        const float* w1 = fl + HDIM;               // [F][H]
        #pragma unroll 4
        for (int f = 0; f < FDIM; f++) acc = fmaf(xs[f], w1[f * HDIM + tid], acc);
        t1s[tid] = fmaxf(acc, 0.f);
    }
    __syncthreads();
    {
        float acc = fl[12928 + tid];               // b2
        const float* w2 = fl + 13056;              // [H][H]
        #pragma unroll 4
        for (int hh = 0; hh < HDIM; hh++) acc = fmaf(t1s[hh], w2[hh * HDIM + tid], acc);
        t2s[tid] = fmaxf(acc, 0.f);
    }
    __syncthreads();
    if (tid < NOUTD) {
        float acc = fl[29440 + tid];               // b3
        const float* w3 = fl + 29450;              // [H][NOUT]
        #pragma unroll 4
        for (int hh = 0; hh < HDIM; hh++) acc = fmaf(t2s[hh], w3[hh * NOUTD + tid], acc);
        out[(long long)t * NOUTD + tid] = acc;     // f32 store
    }
}

// ---------------------------------------------------------------------------
extern "C" void kernel_launch(void* const* d_in, const int* in_sizes, int n_in,
                              void* d_out, int out_size, void* d_ws, size_t ws_size,
                              hipStream_t stream) {
    const float* x      = (const float*)d_in[0];
    const float* y      = (const float*)d_in[1];
    const float* enc_w  = (const float*)d_in[2];
    const float* enc_b  = (const float*)d_in[3];
    const float* yenc_w = (const float*)d_in[4];
    const float* yenc_b = (const float*)d_in[5];
    const float* qkv_w  = (const float*)d_in[6];
    const float* qkv_b  = (const float*)d_in[7];
    const float* out_w  = (const float*)d_in[8];
    const float* out_b  = (const float*)d_in[9];
    const float* ln1_g  = (const float*)d_in[10];
    const float* ln1_b  = (const float*)d_in[11];
    const float* ln2_g  = (const float*)d_in[12];
    const float* ln2_b  = (const float*)d_in[13];
    const float* ff1_w  = (const float*)d_in[14];
    const float* ff1_b  = (const float*)d_in[15];
    const float* ff2_w  = (const float*)d_in[16];
    const float* ff2_b  = (const float*)d_in[17];
    const float* dec_w1 = (const float*)d_in[18];
    const float* dec_b1 = (const float*)d_in[19];
    const float* dec_w2 = (const float*)d_in[20];
    const float* dec_b2 = (const float*)d_in[21];

    // ws layout, ~38 MB
    float* ws     = (float*)d_ws;
    float* h      = ws;
    float* qkv    = h + (size_t)NTOK * EDIM;
    float* attn   = qkv + (size_t)NTOK * 3 * EDIM;
    float* big    = attn + (size_t)NTOK * EDIM;
    float* pooled = big + (size_t)4 * SEPP * SEPP;
    float* dbuf   = pooled + BATCH * EDIM;
    float* flat   = dbuf + BATCH * DECD;

    encoder_kernel<<<NTOK, EDIM, 0, stream>>>(x, y, enc_w, enc_b, yenc_w, yenc_b, h);

    for (int l = 0; l < NLAYER; l++) {
        // qkv = h @ qkv_w[l].T + qkv_b[l]    [2048 x 1536]
        gemm_f32<<<dim3(3 * EDIM / 64, NTOK / 64, 1), 256, 0, stream>>>(
            h, EDIM, 0, 0,
            qkv_w + (size_t)l * 3 * EDIM * EDIM, EDIM, 0, 0, 0,
            qkv, 3 * EDIM, 0, 0,
            1, NTOK, 3 * EDIM, EDIM, 1.f, qkv_b + (size_t)l * 3 * EDIM, 0);

        // attention in 4 chunks (batch cb, 4-head group ch); big holds scores
        for (int cb = 0; cb < BATCH; cb++) {
            for (int ch = 0; ch < 2; ch++) {
                const float* qbase = qkv + cb * 3 * EDIM + ch * 4 * HD;
                const float* kbase = qbase + EDIM;
                const float* vbase = qbase + 2 * EDIM;

                gemm_f32<<<dim3(SEPP / 64, SEPP / 64, 4), 256, 0, stream>>>(
                    qbase, BATCH * 3 * EDIM, 0, HD,
                    kbase, BATCH * 3 * EDIM, 0, HD, 0,
                    big, SEPP, 0, (long long)SEPP * SEPP,
                    4, SEPP, SEPP, HD, 0.125f, nullptr, 0);

                softmax_kernel<<<4 * SEPP, 256, 0, stream>>>(big);

                gemm_f32<<<dim3(1, SEPP / 64, 4), 256, 0, stream>>>(
                    big, SEPP, 0, (long long)SEPP * SEPP,
                    vbase, BATCH * 3 * EDIM, 0, HD, 1,
                    attn + cb * EDIM + ch * 4 * HD, BATCH * EDIM, 0, HD,
                    4, SEPP, HD, SEPP, 1.f, nullptr, 0);
            }
        }

        // proj = attn @ out_w[l].T + out_b[l] -> big
        gemm_f32<<<dim3(EDIM / 64, NTOK / 64, 1), 256, 0, stream>>>(
            attn, EDIM, 0, 0,
            out_w + (size_t)l * EDIM * EDIM, EDIM, 0, 0, 0,
            big, EDIM, 0, 0,
            1, NTOK, EDIM, EDIM, 1.f, out_b + (size_t)l * EDIM, 0);

        add_ln_kernel<<<NTOK, 256, 0, stream>>>(h, big,
            ln1_g + (size_t)l * EDIM, ln1_b + (size_t)l * EDIM, h);

        // ffb = gelu(h @ ff1_w[l].T + ff1_b[l]) -> big  [2048 x 1024]
        gemm_f32<<<dim3(NHID / 64, NTOK / 64, 1), 256, 0, stream>>>(
            h, EDIM, 0, 0,
            ff1_w + (size_t)l * NHID * EDIM, EDIM, 0, 0, 0,
            big, NHID, 0, 0,
            1, NTOK, NHID, EDIM, 1.f, ff1_b + (size_t)l * NHID, 2);

        // f = ffb @ ff2_w[l].T + ff2_b[l] -> attn (dead)  [2048 x 512]
        gemm_f32<<<dim3(EDIM / 64, NTOK / 64, 1), 256, 0, stream>>>(
            big, NHID, 0, 0,
            ff2_w + (size_t)l * EDIM * NHID, NHID, 0, 0, 0,
            attn, EDIM, 0, 0,
            1, NTOK, EDIM, NHID, 1.f, ff2_b + (size_t)l * EDIM, 0);

        add_ln_kernel<<<NTOK, 256, 0, stream>>>(h, attn,
            ln2_g + (size_t)l * EDIM, ln2_b + (size_t)l * EDIM, h);
    }

    pool_kernel<<<4, 256, 0, stream>>>(h, pooled);

    wavedot2_kernel<<<512, 256, 0, stream>>>(
        pooled, pooled + EDIM, dec_w1, dec_b1, dbuf, dbuf + DECD, DECD, EDIM, 1);

    wavedot2_kernel<<<7683, 256, 0, stream>>>(
        dbuf, dbuf + DECD, dec_w2, dec_b2, flat, flat + TOTALW, TOTALW, DECD, 0);

    final_mlp_kernel<<<2048, 128, 0, stream>>>(x, flat, (float*)d_out);
}

// Round 6
// 812.460 us; speedup vs baseline: 3.9080x; 3.9080x over previous
//
#include <hip/hip_runtime.h>

// MotherNet forward — R6: transformer GEMMs + attention on MFMA bf16.
// f32 path retained for encoder, LN, pool, decoder (dec_w2 stream), final MLP.

#define BATCH  2
#define FDIM   100
#define EDIM   512
#define NHEADS 8
#define HD     64
#define NHID   1024
#define NLAYER 4
#define HDIM   128
#define NOUTD  10
#define DECD   2048
#define SEPP   1024
#define TOTALW 30730
#define NTOK   2048

typedef unsigned short u16;
typedef __attribute__((ext_vector_type(8))) short bf16x8;
typedef __attribute__((ext_vector_type(4))) float f32x4;

__device__ __forceinline__ float nanfix(float v) {
    if (isnan(v)) return 0.f;
    if (isinf(v)) return v > 0.f ? 3.4028234663852886e38f : -3.4028234663852886e38f;
    return v;
}
__device__ __forceinline__ u16 f2bf(float f) {   // RTNE, finite inputs
    unsigned u = __float_as_uint(f);
    u += 0x7fffu + ((u >> 16) & 1u);
    return (u16)(u >> 16);
}
__device__ __forceinline__ float bf2f(u16 h) {
    return __uint_as_float(((unsigned)h) << 16);
}

// ---------------------------------------------------------------------------
// bf16 MFMA GEMM: C[z][m][n] = act(alpha * sum_k A[z][m][k]*B[z][n][k] + bias[n])
// A: [M,K] bf16 rows contiguous-in-k (lda). B: [N,K] bf16 rows contiguous-in-k.
// Batch offset: (z/c2)*s1 + (z%c2)*s2 per tensor. C f32 (cbf=0) or bf16 (cbf=1).
// Block: 64x64 tile, 4 waves of 32x32 (2x2 mfma_16x16x32 frags). Direct global
// loads (operands are L2-resident at these sizes). M,N multiples of 64; K of 32.
// ---------------------------------------------------------------------------
__global__ __launch_bounds__(256) void gemm_bf16(
    const u16* __restrict__ A, int lda, long long s1A, long long s2A,
    const u16* __restrict__ B, int ldb, long long s1B, long long s2B,
    void* __restrict__ Cv, int ldc, long long s1C, long long s2C, int cbf,
    int c2, int K, float alpha, const float* __restrict__ bias, int act)
{
    int z = blockIdx.z;
    long long offA = (long long)(z / c2) * s1A + (long long)(z % c2) * s2A;
    long long offB = (long long)(z / c2) * s1B + (long long)(z % c2) * s2B;
    long long offC = (long long)(z / c2) * s1C + (long long)(z % c2) * s2C;
    int tid = threadIdx.x;
    int lane = tid & 63, wid = tid >> 6;
    int wr = wid >> 1, wc = wid & 1;
    int mBase = blockIdx.y * 64 + wr * 32;
    int nBase = blockIdx.x * 64 + wc * 32;
    int r16 = lane & 15, kg = lane >> 4;

    f32x4 acc00 = {0.f, 0.f, 0.f, 0.f};
    f32x4 acc01 = acc00, acc10 = acc00, acc11 = acc00;
    const u16* Ap = A + offA + (long long)(mBase + r16) * lda + kg * 8;
    const u16* Bp = B + offB + (long long)(nBase + r16) * ldb + kg * 8;
    long long a16 = (long long)16 * lda, b16 = (long long)16 * ldb;

    for (int k0 = 0; k0 < K; k0 += 32) {
        bf16x8 a0 = *(const bf16x8*)(Ap);
        bf16x8 a1 = *(const bf16x8*)(Ap + a16);
        bf16x8 b0 = *(const bf16x8*)(Bp);
        bf16x8 b1 = *(const bf16x8*)(Bp + b16);
        acc00 = __builtin_amdgcn_mfma_f32_16x16x32_bf16(a0, b0, acc00, 0, 0, 0);
        acc01 = __builtin_amdgcn_mfma_f32_16x16x32_bf16(a0, b1, acc01, 0, 0, 0);
        acc10 = __builtin_amdgcn_mfma_f32_16x16x32_bf16(a1, b0, acc10, 0, 0, 0);
        acc11 = __builtin_amdgcn_mfma_f32_16x16x32_bf16(a1, b1, acc11, 0, 0, 0);
        Ap += 32; Bp += 32;
    }

    #pragma unroll
    for (int i = 0; i < 2; i++) {
        #pragma unroll
        for (int j = 0; j < 2; j++) {
            f32x4 v = (i == 0) ? (j == 0 ? acc00 : acc01) : (j == 0 ? acc10 : acc11);
            int col = nBase + j * 16 + r16;
            float bv = bias ? bias[col] : 0.f;
            long long base = offC + (long long)(mBase + i * 16 + kg * 4) * ldc + col;
            #pragma unroll
            for (int r = 0; r < 4; r++) {
                float c = v[r] * alpha + bv;
                if (act == 2) {  // jax.nn.gelu approximate=True (tanh form)
                    float u = 0.7978845608028654f * (c + 0.044715f * c * c * c);
                    c = 0.5f * c * (1.f + tanhf(u));
                }
                if (cbf) ((u16*)Cv)[base + (long long)r * ldc] = f2bf(c);
                else     ((float*)Cv)[base + (long long)r * ldc] = c;
            }
        }
    }
}

// f32 -> bf16 grid-stride convert
__global__ __launch_bounds__(256) void cvt_bf(
    const float* __restrict__ s, u16* __restrict__ d, int n)
{
    int i = blockIdx.x * 256 + threadIdx.x;
    int st = gridDim.x * 256;
    for (; i < n; i += st) d[i] = f2bf(s[i]);
}

// Encoder: h[t][e] (f32 + bf16 copies)
__global__ __launch_bounds__(512) void encoder_kernel(
    const float* __restrict__ x, const float* __restrict__ y,
    const float* __restrict__ enc_w, const float* __restrict__ enc_b,
    const float* __restrict__ yenc_w, const float* __restrict__ yenc_b,
    float* __restrict__ h, u16* __restrict__ h_bf)
{
    int t = blockIdx.x;
    __shared__ float xs[FDIM];
    int tid = threadIdx.x;
    if (tid < FDIM) xs[tid] = nanfix(x[(long long)t * FDIM + tid]);
    __syncthreads();
    float yv = y[t];
    int e = tid;
    float acc = enc_b[e] + yv * yenc_w[e] + yenc_b[e];
    const float* wr = enc_w + (long long)e * FDIM;
    #pragma unroll 4
    for (int f = 0; f < FDIM; f++) acc = fmaf(xs[f], wr[f], acc);
    h[(long long)t * EDIM + e] = acc;
    h_bf[(long long)t * EDIM + e] = f2bf(acc);
}

// out = LN(a + r)*g + beta; writes f32 + bf16. a may alias out.
__global__ __launch_bounds__(256) void add_ln_kernel(
    const float* a, const float* __restrict__ r,
    const float* __restrict__ g, const float* __restrict__ be,
    float* out, u16* __restrict__ out_bf)
{
    int row = blockIdx.x;
    int tid = threadIdx.x;
    const float* pa = a + (long long)row * EDIM;
    const float* pr = r + (long long)row * EDIM;
    float v0 = pa[tid] + pr[tid];
    float v1 = pa[tid + 256] + pr[tid + 256];
    float s = v0 + v1, q = v0 * v0 + v1 * v1;
    #pragma unroll
    for (int off = 32; off; off >>= 1) {
        s += __shfl_xor(s, off);
        q += __shfl_xor(q, off);
    }
    __shared__ float ss[4], sq[4];
    int w = tid >> 6, lane = tid & 63;
    if (lane == 0) { ss[w] = s; sq[w] = q; }
    __syncthreads();
    s = ss[0] + ss[1] + ss[2] + ss[3];
    q = sq[0] + sq[1] + sq[2] + sq[3];
    float mean = s * (1.f / EDIM);
    float var = q * (1.f / EDIM) - mean * mean;
    float rstd = rsqrtf(var + 1e-5f);
    float o0 = (v0 - mean) * rstd * g[tid] + be[tid];
    float o1 = (v1 - mean) * rstd * g[tid + 256] + be[tid + 256];
    float* po = out + (long long)row * EDIM;
    u16* pb = out_bf + (long long)row * EDIM;
    po[tid] = o0;        po[tid + 256] = o1;
    pb[tid] = f2bf(o0);  pb[tid + 256] = f2bf(o1);
}

// one-pass softmax over f32 rows of 1024 -> bf16 P
__global__ __launch_bounds__(256) void softmax_f2b(
    const float* __restrict__ S, u16* __restrict__ P)
{
    long long row = blockIdx.x;
    const float* pr = S + row * 1024;
    u16* po = P + row * 1024;
    int tid = threadIdx.x;
    float v0 = pr[tid], v1 = pr[tid + 256], v2 = pr[tid + 512], v3 = pr[tid + 768];
    float m = fmaxf(fmaxf(v0, v1), fmaxf(v2, v3));
    #pragma unroll
    for (int off = 32; off; off >>= 1) m = fmaxf(m, __shfl_xor(m, off));
    __shared__ float sm[4], ssum[4];
    int w = tid >> 6, lane = tid & 63;
    if (lane == 0) sm[w] = m;
    __syncthreads();
    m = fmaxf(fmaxf(sm[0], sm[1]), fmaxf(sm[2], sm[3]));
    float e0 = __expf(v0 - m), e1 = __expf(v1 - m), e2 = __expf(v2 - m), e3 = __expf(v3 - m);
    float s = e0 + e1 + e2 + e3;
    #pragma unroll
    for (int off = 32; off; off >>= 1) s += __shfl_xor(s, off);
    if (lane == 0) ssum[w] = s;
    __syncthreads();
    s = ssum[0] + ssum[1] + ssum[2] + ssum[3];
    float inv = 1.f / s;
    po[tid]       = f2bf(e0 * inv);
    po[tid + 256] = f2bf(e1 * inv);
    po[tid + 512] = f2bf(e2 * inv);
    po[tid + 768] = f2bf(e3 * inv);
}

// V transpose: vt[(cb*8+hh)*64 + d][s] = qkv_bf[(s*2+cb)*1536 + 1024 + hh*64 + d]
__global__ __launch_bounds__(256) void vtrans_kernel(
    const u16* __restrict__ qkvb, u16* __restrict__ vt)
{
    __shared__ u16 tile[64][66];
    int bx = blockIdx.x;        // s-tile (16)
    int by = blockIdx.y;        // cb*8+hh (16)
    int cb = by >> 3, hh = by & 7;
    int tid = threadIdx.x;
    int c = tid & 63, w4 = tid >> 6;
    #pragma unroll 4
    for (int i = 0; i < 16; i++) {
        int sl = w4 * 16 + i;
        tile[sl][c] = qkvb[((long long)((bx * 64 + sl) * 2 + cb)) * 1536 + 1024 + hh * 64 + c];
    }
    __syncthreads();
    #pragma unroll 4
    for (int i = 0; i < 16; i++) {
        int dl = w4 * 16 + i;
        vt[((long long)(by * 64 + dl)) * 1024 + bx * 64 + c] = tile[c][dl];
    }
}

__global__ __launch_bounds__(256) void pool_kernel(
    const float* __restrict__ h, float* __restrict__ pooled)
{
    int idx = blockIdx.x * 256 + threadIdx.x;   // 0..1023
    int b = idx / EDIM, e = idx % EDIM;
    float s = 0.f;
    for (int si = 0; si < SEPP; si++)
        s += h[((long long)si * BATCH + b) * EDIM + e];
    pooled[(long long)b * EDIM + e] = s * (1.f / SEPP);
}

__global__ __launch_bounds__(256) void wavedot2_kernel(
    const float* __restrict__ v0, const float* __restrict__ v1,
    const float* __restrict__ W, const float* __restrict__ bias,
    float* __restrict__ out0, float* __restrict__ out1,
    int R, int K, int act)
{
    int gw = (blockIdx.x * 256 + threadIdx.x) >> 6;
    int lane = threadIdx.x & 63;
    int nw = (gridDim.x * 256) >> 6;
    const float4* x0 = (const float4*)v0;
    const float4* x1 = (const float4*)v1;
    for (int r = gw; r < R; r += nw) {
        const float4* w4 = (const float4*)(W + (long long)r * K);
        float a0 = 0.f, a1 = 0.f;
        for (int i = lane; i < (K >> 2); i += 64) {
            float4 w = w4[i];
            float4 p = x0[i];
            float4 q = x1[i];
            a0 += w.x * p.x + w.y * p.y + w.z * p.z + w.w * p.w;
            a1 += w.x * q.x + w.y * q.y + w.z * q.z + w.w * q.w;
        }
        #pragma unroll
        for (int off = 32; off; off >>= 1) {
            a0 += __shfl_xor(a0, off);
            a1 += __shfl_xor(a1, off);
        }
        if (lane == 0) {
            float bb = bias[r];
            float o0 = a0 + bb, o1 = a1 + bb;
            if (act == 1) { o0 = fmaxf(o0, 0.f); o1 = fmaxf(o1, 0.f); }
            out0[r] = o0; out1[r] = o1;
        }
    }
}

__global__ __launch_bounds__(128) void final_mlp_kernel(
    const float* __restrict__ x, const float* __restrict__ flat,
    float* __restrict__ out)
{
    int t = blockIdx.x;            // 0..2047 = si*B + b
    int b = t & 1;
    int tid = threadIdx.x;
    const float* fl = flat + (long long)b * TOTALW;
    __shared__ float xs[FDIM], t1s[HDIM], t2s[HDIM];
    if (tid < FDIM) xs[tid] = nanfix(x[(long long)(NTOK + t) * FDIM + tid]);
    __syncthreads();
    {
        float acc = fl[tid];
        const float* w1 = fl + HDIM;
        #pragma unroll 4
        for (int f = 0; f < FDIM; f++) acc = fmaf(xs[f], w1[f * HDIM + tid], acc);
        t1s[tid] = fmaxf(acc, 0.f);
    }
    __syncthreads();
    {
        float acc = fl[12928 + tid];
        const float* w2 = fl + 13056;
        #pragma unroll 4
        for (int hh = 0; hh < HDIM; hh++) acc = fmaf(t1s[hh], w2[hh * HDIM + tid], acc);
        t2s[tid] = fmaxf(acc, 0.f);
    }
    __syncthreads();
    if (tid < NOUTD) {
        float acc = fl[29440 + tid];
        const float* w3 = fl + 29450;
        #pragma unroll 4
        for (int hh = 0; hh < HDIM; hh++) acc = fmaf(t2s[hh], w3[hh * NOUTD + tid], acc);
        out[(long long)t * NOUTD + tid] = acc;
    }
}

// ---------------------------------------------------------------------------
extern "C" void kernel_launch(void* const* d_in, const int* in_sizes, int n_in,
                              void* d_out, int out_size, void* d_ws, size_t ws_size,
                              hipStream_t stream) {
    const float* x      = (const float*)d_in[0];
    const float* y      = (const float*)d_in[1];
    const float* enc_w  = (const float*)d_in[2];
    const float* enc_b  = (const float*)d_in[3];
    const float* yenc_w = (const float*)d_in[4];
    const float* yenc_b = (const float*)d_in[5];
    const float* qkv_w  = (const float*)d_in[6];
    const float* qkv_b  = (const float*)d_in[7];
    const float* out_w  = (const float*)d_in[8];
    const float* out_b  = (const float*)d_in[9];
    const float* ln1_g  = (const float*)d_in[10];
    const float* ln1_b  = (const float*)d_in[11];
    const float* ln2_g  = (const float*)d_in[12];
    const float* ln2_b  = (const float*)d_in[13];
    const float* ff1_w  = (const float*)d_in[14];
    const float* ff1_b  = (const float*)d_in[15];
    const float* ff2_w  = (const float*)d_in[16];
    const float* ff2_b  = (const float*)d_in[17];
    const float* dec_w1 = (const float*)d_in[18];
    const float* dec_b1 = (const float*)d_in[19];
    const float* dec_w2 = (const float*)d_in[20];
    const float* dec_b2 = (const float*)d_in[21];

    // ws layout (~137 MB; ws is ~1 GB per fill evidence). All 16B-aligned.
    float* ws     = (float*)d_ws;
    float* h      = ws;                                  // 1,048,576 f
    u16*   h_bf   = (u16*)(h + 1048576);                 // 1,048,576 u16
    u16*   qkv_bf = h_bf + 1048576;                      // 3,145,728 u16
    u16*   vt     = qkv_bf + 3145728;                    // 1,048,576 u16
    u16*   attn_bf= vt + 1048576;                        // 1,048,576 u16
    u16*   ffb_bf = attn_bf + 1048576;                   // 2,097,152 u16
    u16*   wq     = ffb_bf + 2097152;                    // 3,145,728 u16
    u16*   wo     = wq + 3145728;                        // 1,048,576 u16
    u16*   wf1    = wo + 1048576;                        // 2,097,152 u16
    u16*   wf2    = wf1 + 2097152;                       // 2,097,152 u16
    u16*   p_bf   = wf2 + 2097152;                       // 16,777,216 u16
    float* scores = (float*)(p_bf + 16777216);           // 16,777,216 f
    float* big    = scores + 16777216;                   // 1,048,576 f
    float* pooled = big + 1048576;                       // 1,024
    float* dbuf   = pooled + 1024;                       // 4,096
    float* flat   = dbuf + 4096;                         // 61,460

    // weights -> bf16 (once per call)
    cvt_bf<<<2048, 256, 0, stream>>>(qkv_w, wq, 4 * 786432);
    cvt_bf<<<2048, 256, 0, stream>>>(out_w, wo, 4 * 262144);
    cvt_bf<<<2048, 256, 0, stream>>>(ff1_w, wf1, 4 * 524288);
    cvt_bf<<<2048, 256, 0, stream>>>(ff2_w, wf2, 4 * 524288);

    encoder_kernel<<<NTOK, EDIM, 0, stream>>>(x, y, enc_w, enc_b, yenc_w, yenc_b, h, h_bf);

    for (int l = 0; l < NLAYER; l++) {
        // qkv = h @ qkv_w[l].T + qkv_b[l]  -> bf16 [2048 x 1536]
        gemm_bf16<<<dim3(24, 32, 1), 256, 0, stream>>>(
            h_bf, EDIM, 0, 0,
            wq + (size_t)l * 786432, EDIM, 0, 0,
            qkv_bf, 1536, 0, 0, 1,
            1, EDIM, 1.f, qkv_b + (size_t)l * 1536, 0);

        // vt[(cb*8+hh)*64+d][s] = V
        vtrans_kernel<<<dim3(16, 16), 256, 0, stream>>>(qkv_bf, vt);

        // scores[z=cb*8+hh] = Q @ K^T / 8 -> f32 [16][1024][1024]
        gemm_bf16<<<dim3(16, 16, 16), 256, 0, stream>>>(
            qkv_bf,       3072, 1536, 64,
            qkv_bf + 512, 3072, 1536, 64,
            scores, 1024, 8388608LL, 1048576LL, 0,
            8, HD, 0.125f, nullptr, 0);

        // P = softmax(scores) -> bf16
        softmax_f2b<<<16 * SEPP, 256, 0, stream>>>(scores, p_bf);

        // attn[z] = P @ V -> bf16 into attn_bf[t][512]
        gemm_bf16<<<dim3(1, 16, 16), 256, 0, stream>>>(
            p_bf, 1024, 8388608LL, 1048576LL,
            vt,   1024, 524288LL, 65536LL,
            attn_bf, 1024, 512LL, 64LL, 1,
            8, SEPP, 1.f, nullptr, 0);

        // proj = attn @ out_w[l].T + out_b[l] -> f32 big
        gemm_bf16<<<dim3(8, 32, 1), 256, 0, stream>>>(
            attn_bf, EDIM, 0, 0,
            wo + (size_t)l * 262144, EDIM, 0, 0,
            big, EDIM, 0, 0, 0,
            1, EDIM, 1.f, out_b + (size_t)l * EDIM, 0);

        add_ln_kernel<<<NTOK, 256, 0, stream>>>(h, big,
            ln1_g + (size_t)l * EDIM, ln1_b + (size_t)l * EDIM, h, h_bf);

        // ffb = gelu(h @ ff1_w[l].T + ff1_b[l]) -> bf16 [2048 x 1024]
        gemm_bf16<<<dim3(16, 32, 1), 256, 0, stream>>>(
            h_bf, EDIM, 0, 0,
            wf1 + (size_t)l * 524288, EDIM, 0, 0,
            ffb_bf, NHID, 0, 0, 1,
            1, EDIM, 1.f, ff1_b + (size_t)l * NHID, 2);

        // f = ffb @ ff2_w[l].T + ff2_b[l] -> f32 big
        gemm_bf16<<<dim3(8, 32, 1), 256, 0, stream>>>(
            ffb_bf, NHID, 0, 0,
            wf2 + (size_t)l * 524288, NHID, 0, 0,
            big, EDIM, 0, 0, 0,
            1, NHID, 1.f, ff2_b + (size_t)l * EDIM, 0);

        add_ln_kernel<<<NTOK, 256, 0, stream>>>(h, big,
            ln2_g + (size_t)l * EDIM, ln2_b + (size_t)l * EDIM, h, h_bf);
    }

    pool_kernel<<<4, 256, 0, stream>>>(h, pooled);

    wavedot2_kernel<<<512, 256, 0, stream>>>(
        pooled, pooled + EDIM, dec_w1, dec_b1, dbuf, dbuf + DECD, DECD, EDIM, 1);

    wavedot2_kernel<<<7683, 256, 0, stream>>>(
        dbuf, dbuf + DECD, dec_w2, dec_b2, flat, flat + TOTALW, TOTALW, DECD, 0);

    final_mlp_kernel<<<2048, 128, 0, stream>>>(x, flat, (float*)d_out);
}

// Round 7
// 807.854 us; speedup vs baseline: 3.9303x; 1.0057x over previous
//
#include <hip/hip_runtime.h>

// MotherNet forward — R7: fused flash attention (QK^T+softmax+PV in one kernel).
// R6 minus: scores buffer, softmax_f2b kernel, PV GEMM. Everything else identical.

#define BATCH  2
#define FDIM   100
#define EDIM   512
#define NHEADS 8
#define HD     64
#define NHID   1024
#define NLAYER 4
#define HDIM   128
#define NOUTD  10
#define DECD   2048
#define SEPP   1024
#define TOTALW 30730
#define NTOK   2048

typedef unsigned short u16;
typedef __attribute__((ext_vector_type(8))) short bf16x8;
typedef __attribute__((ext_vector_type(4))) float f32x4;

__device__ __forceinline__ float nanfix(float v) {
    if (isnan(v)) return 0.f;
    if (isinf(v)) return v > 0.f ? 3.4028234663852886e38f : -3.4028234663852886e38f;
    return v;
}
__device__ __forceinline__ u16 f2bf(float f) {   // RTNE, finite inputs
    unsigned u = __float_as_uint(f);
    u += 0x7fffu + ((u >> 16) & 1u);
    return (u16)(u >> 16);
}

// ---------------------------------------------------------------------------
// bf16 MFMA GEMM (unchanged from R6): C = act(alpha * A @ B^T + bias)
// ---------------------------------------------------------------------------
__global__ __launch_bounds__(256) void gemm_bf16(
    const u16* __restrict__ A, int lda, long long s1A, long long s2A,
    const u16* __restrict__ B, int ldb, long long s1B, long long s2B,
    void* __restrict__ Cv, int ldc, long long s1C, long long s2C, int cbf,
    int c2, int K, float alpha, const float* __restrict__ bias, int act)
{
    int z = blockIdx.z;
    long long offA = (long long)(z / c2) * s1A + (long long)(z % c2) * s2A;
    long long offB = (long long)(z / c2) * s1B + (long long)(z % c2) * s2B;
    long long offC = (long long)(z / c2) * s1C + (long long)(z % c2) * s2C;
    int tid = threadIdx.x;
    int lane = tid & 63, wid = tid >> 6;
    int wr = wid >> 1, wc = wid & 1;
    int mBase = blockIdx.y * 64 + wr * 32;
    int nBase = blockIdx.x * 64 + wc * 32;
    int r16 = lane & 15, kg = lane >> 4;

    f32x4 acc00 = {0.f, 0.f, 0.f, 0.f};
    f32x4 acc01 = acc00, acc10 = acc00, acc11 = acc00;
    const u16* Ap = A + offA + (long long)(mBase + r16) * lda + kg * 8;
    const u16* Bp = B + offB + (long long)(nBase + r16) * ldb + kg * 8;
    long long a16 = (long long)16 * lda, b16 = (long long)16 * ldb;

    for (int k0 = 0; k0 < K; k0 += 32) {
        bf16x8 a0 = *(const bf16x8*)(Ap);
        bf16x8 a1 = *(const bf16x8*)(Ap + a16);
        bf16x8 b0 = *(const bf16x8*)(Bp);
        bf16x8 b1 = *(const bf16x8*)(Bp + b16);
        acc00 = __builtin_amdgcn_mfma_f32_16x16x32_bf16(a0, b0, acc00, 0, 0, 0);
        acc01 = __builtin_amdgcn_mfma_f32_16x16x32_bf16(a0, b1, acc01, 0, 0, 0);
        acc10 = __builtin_amdgcn_mfma_f32_16x16x32_bf16(a1, b0, acc10, 0, 0, 0);
        acc11 = __builtin_amdgcn_mfma_f32_16x16x32_bf16(a1, b1, acc11, 0, 0, 0);
        Ap += 32; Bp += 32;
    }

    #pragma unroll
    for (int i = 0; i < 2; i++) {
        #pragma unroll
        for (int j = 0; j < 2; j++) {
            f32x4 v = (i == 0) ? (j == 0 ? acc00 : acc01) : (j == 0 ? acc10 : acc11);
            int col = nBase + j * 16 + r16;
            float bv = bias ? bias[col] : 0.f;
            long long base = offC + (long long)(mBase + i * 16 + kg * 4) * ldc + col;
            #pragma unroll
            for (int r = 0; r < 4; r++) {
                float c = v[r] * alpha + bv;
                if (act == 2) {
                    float u = 0.7978845608028654f * (c + 0.044715f * c * c * c);
                    c = 0.5f * c * (1.f + tanhf(u));
                }
                if (cbf) ((u16*)Cv)[base + (long long)r * ldc] = f2bf(c);
                else     ((float*)Cv)[base + (long long)r * ldc] = c;
            }
        }
    }
}

// ---------------------------------------------------------------------------
// Fused flash attention. Grid (16 q-tiles, 16 b*h), 256 threads = 4 waves.
// Wave w owns q-rows [qt*64 + w*16, +16). Iterates 16 kv-tiles of 64 keys.
// S scale 1/8. P via per-wave swizzled LDS (C-layout -> A-layout transpose).
// ---------------------------------------------------------------------------
__global__ __launch_bounds__(256) void flash_attn(
    const u16* __restrict__ qkvb,   // [2048][1536] bf16 (q|k|v per token)
    const u16* __restrict__ vtm,    // [16*64][1024] bf16 V^T per head
    u16* __restrict__ attnb)        // [2048][512] bf16
{
    int qt = blockIdx.x;
    int bh = blockIdx.y;
    int cb = bh >> 3, hh = bh & 7;
    int tid = threadIdx.x;
    int w = tid >> 6, lane = tid & 63;
    int r16 = lane & 15, kg = lane >> 4;

    __shared__ __align__(16) u16 plds[4][2048];   // per-wave 16x64 bf16 (swizzled)
    u16* pl = &plds[w][0];

    // Q fragments (A-layout): row = lane&15 within wave's strip
    int qrow = qt * 64 + w * 16 + r16;
    const u16* qp = qkvb + ((long long)qrow * 2 + cb) * 1536 + hh * 64 + kg * 8;
    bf16x8 qf0 = *(const bf16x8*)(qp);
    bf16x8 qf1 = *(const bf16x8*)(qp + 32);

    const u16* kbase = qkvb + (long long)cb * 1536 + 512 + hh * 64;  // + key*3072
    const u16* vbase = vtm + ((long long)bh * 64) * 1024;            // + d*1024 + s

    f32x4 m = {-3e38f, -3e38f, -3e38f, -3e38f};
    f32x4 l = {0.f, 0.f, 0.f, 0.f};
    f32x4 o[4] = {};   // db-blocks, C-layout rows = kg*4+reg

    // precomputed swizzled read offsets (u16 index) for P A-frags
    int rb0 = (((r16 * 64 + kg * 8) * 2) ^ ((r16 & 7) << 4)) >> 1;
    int rb1 = (((r16 * 64 + 32 + kg * 8) * 2) ^ ((r16 & 7) << 4)) >> 1;

    for (int kt = 0; kt < 16; kt++) {
        // ---- S tile = Q K^T * 0.125  (4 nb-blocks of 16 keys) ----
        f32x4 s[4];
        #pragma unroll
        for (int nb = 0; nb < 4; nb++) {
            int key = kt * 64 + nb * 16 + r16;
            const u16* kp = kbase + (long long)key * 3072 + kg * 8;
            bf16x8 kf0 = *(const bf16x8*)(kp);
            bf16x8 kf1 = *(const bf16x8*)(kp + 32);
            f32x4 acc = {};
            acc = __builtin_amdgcn_mfma_f32_16x16x32_bf16(qf0, kf0, acc, 0, 0, 0);
            acc = __builtin_amdgcn_mfma_f32_16x16x32_bf16(qf1, kf1, acc, 0, 0, 0);
            s[nb] = acc;
        }
        #pragma unroll
        for (int nb = 0; nb < 4; nb++)
            #pragma unroll
            for (int r = 0; r < 4; r++) s[nb][r] *= 0.125f;

        // ---- online softmax (rows = kg*4+reg, cols spread over 16-lane group) ----
        f32x4 tm;
        #pragma unroll
        for (int r = 0; r < 4; r++)
            tm[r] = fmaxf(fmaxf(s[0][r], s[1][r]), fmaxf(s[2][r], s[3][r]));
        #pragma unroll
        for (int off = 1; off < 16; off <<= 1) {
            #pragma unroll
            for (int r = 0; r < 4; r++) tm[r] = fmaxf(tm[r], __shfl_xor(tm[r], off));
        }
        f32x4 mn, al;
        #pragma unroll
        for (int r = 0; r < 4; r++) {
            mn[r] = fmaxf(m[r], tm[r]);
            al[r] = __expf(m[r] - mn[r]);
            m[r] = mn[r];
        }
        f32x4 rs = {};
        #pragma unroll
        for (int nb = 0; nb < 4; nb++)
            #pragma unroll
            for (int r = 0; r < 4; r++) {
                float p = __expf(s[nb][r] - mn[r]);
                s[nb][r] = p;
                rs[r] += p;
            }
        #pragma unroll
        for (int off = 1; off < 16; off <<= 1) {
            #pragma unroll
            for (int r = 0; r < 4; r++) rs[r] += __shfl_xor(rs[r], off);
        }
        #pragma unroll
        for (int r = 0; r < 4; r++) l[r] = l[r] * al[r] + rs[r];
        #pragma unroll
        for (int db = 0; db < 4; db++)
            #pragma unroll
            for (int r = 0; r < 4; r++) o[db][r] *= al[r];

        // ---- P -> LDS bf16 (C-layout write, swizzled) ----
        #pragma unroll
        for (int nb = 0; nb < 4; nb++)
            #pragma unroll
            for (int r = 0; r < 4; r++) {
                int row = kg * 4 + r;
                int col = nb * 16 + r16;
                int byi = (((row * 64 + col) * 2) ^ ((row & 7) << 4)) >> 1;
                pl[byi] = f2bf(s[nb][r]);
            }
        __syncthreads();

        // ---- PV: A = P (LDS), B = V^T frags ----
        bf16x8 pa0 = *(const bf16x8*)(pl + rb0);
        bf16x8 pa1 = *(const bf16x8*)(pl + rb1);
        #pragma unroll
        for (int db = 0; db < 4; db++) {
            const u16* vp = vbase + (long long)(db * 16 + r16) * 1024 + kt * 64 + kg * 8;
            bf16x8 vf0 = *(const bf16x8*)(vp);
            bf16x8 vf1 = *(const bf16x8*)(vp + 32);
            o[db] = __builtin_amdgcn_mfma_f32_16x16x32_bf16(pa0, vf0, o[db], 0, 0, 0);
            o[db] = __builtin_amdgcn_mfma_f32_16x16x32_bf16(pa1, vf1, o[db], 0, 0, 0);
        }
    }

    // ---- epilogue: O / l -> attn_bf ----
    f32x4 linv;
    #pragma unroll
    for (int r = 0; r < 4; r++) linv[r] = 1.f / l[r];
    #pragma unroll
    for (int db = 0; db < 4; db++)
        #pragma unroll
        for (int r = 0; r < 4; r++) {
            int row = qt * 64 + w * 16 + kg * 4 + r;
            attnb[((long long)row * 2 + cb) * 512 + hh * 64 + db * 16 + r16] =
                f2bf(o[db][r] * linv[r]);
        }
}

// f32 -> bf16 grid-stride convert
__global__ __launch_bounds__(256) void cvt_bf(
    const float* __restrict__ s, u16* __restrict__ d, int n)
{
    int i = blockIdx.x * 256 + threadIdx.x;
    int st = gridDim.x * 256;
    for (; i < n; i += st) d[i] = f2bf(s[i]);
}

__global__ __launch_bounds__(512) void encoder_kernel(
    const float* __restrict__ x, const float* __restrict__ y,
    const float* __restrict__ enc_w, const float* __restrict__ enc_b,
    const float* __restrict__ yenc_w, const float* __restrict__ yenc_b,
    float* __restrict__ h, u16* __restrict__ h_bf)
{
    int t = blockIdx.x;
    __shared__ float xs[FDIM];
    int tid = threadIdx.x;
    if (tid < FDIM) xs[tid] = nanfix(x[(long long)t * FDIM + tid]);
    __syncthreads();
    float yv = y[t];
    int e = tid;
    float acc = enc_b[e] + yv * yenc_w[e] + yenc_b[e];
    const float* wr = enc_w + (long long)e * FDIM;
    #pragma unroll 4
    for (int f = 0; f < FDIM; f++) acc = fmaf(xs[f], wr[f], acc);
    h[(long long)t * EDIM + e] = acc;
    h_bf[(long long)t * EDIM + e] = f2bf(acc);
}

__global__ __launch_bounds__(256) void add_ln_kernel(
    const float* a, const float* __restrict__ r,
    const float* __restrict__ g, const float* __restrict__ be,
    float* out, u16* __restrict__ out_bf)
{
    int row = blockIdx.x;
    int tid = threadIdx.x;
    const float* pa = a + (long long)row * EDIM;
    const float* pr = r + (long long)row * EDIM;
    float v0 = pa[tid] + pr[tid];
    float v1 = pa[tid + 256] + pr[tid + 256];
    float s = v0 + v1, q = v0 * v0 + v1 * v1;
    #pragma unroll
    for (int off = 32; off; off >>= 1) {
        s += __shfl_xor(s, off);
        q += __shfl_xor(q, off);
    }
    __shared__ float ss[4], sq[4];
    int w = tid >> 6, lane = tid & 63;
    if (lane == 0) { ss[w] = s; sq[w] = q; }
    __syncthreads();
    s = ss[0] + ss[1] + ss[2] + ss[3];
    q = sq[0] + sq[1] + sq[2] + sq[3];
    float mean = s * (1.f / EDIM);
    float var = q * (1.f / EDIM) - mean * mean;
    float rstd = rsqrtf(var + 1e-5f);
    float o0 = (v0 - mean) * rstd * g[tid] + be[tid];
    float o1 = (v1 - mean) * rstd * g[tid + 256] + be[tid + 256];
    float* po = out + (long long)row * EDIM;
    u16* pb = out_bf + (long long)row * EDIM;
    po[tid] = o0;        po[tid + 256] = o1;
    pb[tid] = f2bf(o0);  pb[tid + 256] = f2bf(o1);
}

// V transpose: vt[(cb*8+hh)*64 + d][s] = qkv_bf[(s*2+cb)*1536 + 1024 + hh*64 + d]
__global__ __launch_bounds__(256) void vtrans_kernel(
    const u16* __restrict__ qkvb, u16* __restrict__ vt)
{
    __shared__ u16 tile[64][66];
    int bx = blockIdx.x;        // s-tile (16)
    int by = blockIdx.y;        // cb*8+hh (16)
    int cb = by >> 3, hh = by & 7;
    int tid = threadIdx.x;
    int c = tid & 63, w4 = tid >> 6;
    #pragma unroll 4
    for (int i = 0; i < 16; i++) {
        int sl = w4 * 16 + i;
        tile[sl][c] = qkvb[((long long)((bx * 64 + sl) * 2 + cb)) * 1536 + 1024 + hh * 64 + c];
    }
    __syncthreads();
    #pragma unroll 4
    for (int i = 0; i < 16; i++) {
        int dl = w4 * 16 + i;
        vt[((long long)(by * 64 + dl)) * 1024 + bx * 64 + c] = tile[c][dl];
    }
}

__global__ __launch_bounds__(256) void pool_kernel(
    const float* __restrict__ h, float* __restrict__ pooled)
{
    int idx = blockIdx.x * 256 + threadIdx.x;   // 0..1023
    int b = idx / EDIM, e = idx % EDIM;
    float s = 0.f;
    for (int si = 0; si < SEPP; si++)
        s += h[((long long)si * BATCH + b) * EDIM + e];
    pooled[(long long)b * EDIM + e] = s * (1.f / SEPP);
}

__global__ __launch_bounds__(256) void wavedot2_kernel(
    const float* __restrict__ v0, const float* __restrict__ v1,
    const float* __restrict__ W, const float* __restrict__ bias,
    float* __restrict__ out0, float* __restrict__ out1,
    int R, int K, int act)
{
    int gw = (blockIdx.x * 256 + threadIdx.x) >> 6;
    int lane = threadIdx.x & 63;
    int nw = (gridDim.x * 256) >> 6;
    const float4* x0 = (const float4*)v0;
    const float4* x1 = (const float4*)v1;
    for (int r = gw; r < R; r += nw) {
        const float4* w4 = (const float4*)(W + (long long)r * K);
        float a0 = 0.f, a1 = 0.f;
        for (int i = lane; i < (K >> 2); i += 64) {
            float4 w = w4[i];
            float4 p = x0[i];
            float4 q = x1[i];
            a0 += w.x * p.x + w.y * p.y + w.z * p.z + w.w * p.w;
            a1 += w.x * q.x + w.y * q.y + w.z * q.z + w.w * q.w;
        }
        #pragma unroll
        for (int off = 32; off; off >>= 1) {
            a0 += __shfl_xor(a0, off);
            a1 += __shfl_xor(a1, off);
        }
        if (lane == 0) {
            float bb = bias[r];
            float o0 = a0 + bb, o1 = a1 + bb;
            if (act == 1) { o0 = fmaxf(o0, 0.f); o1 = fmaxf(o1, 0.f); }
            out0[r] = o0; out1[r] = o1;
        }
    }
}

__global__ __launch_bounds__(128) void final_mlp_kernel(
    const float* __restrict__ x, const float* __restrict__ flat,
    float* __restrict__ out)
{
    int t = blockIdx.x;            // 0..2047 = si*B + b
    int b = t & 1;
    int tid = threadIdx.x;
    const float* fl = flat + (long long)b * TOTALW;
    __shared__ float xs[FDIM], t1s[HDIM], t2s[HDIM];
    if (tid < FDIM) xs[tid] = nanfix(x[(long long)(NTOK + t) * FDIM + tid]);
    __syncthreads();
    {
        float acc = fl[tid];
        const float* w1 = fl + HDIM;
        #pragma unroll 4
        for (int f = 0; f < FDIM; f++) acc = fmaf(xs[f], w1[f * HDIM + tid], acc);
        t1s[tid] = fmaxf(acc, 0.f);
    }
    __syncthreads();
    {
        float acc = fl[12928 + tid];
        const float* w2 = fl + 13056;
        #pragma unroll 4
        for (int hh = 0; hh < HDIM; hh++) acc = fmaf(t1s[hh], w2[hh * HDIM + tid], acc);
        t2s[tid] = fmaxf(acc, 0.f);
    }
    __syncthreads();
    if (tid < NOUTD) {
        float acc = fl[29440 + tid];
        const float* w3 = fl + 29450;
        #pragma unroll 4
        for (int hh = 0; hh < HDIM; hh++) acc = fmaf(t2s[hh], w3[hh * NOUTD + tid], acc);
        out[(long long)t * NOUTD + tid] = acc;
    }
}

// ---------------------------------------------------------------------------
extern "C" void kernel_launch(void* const* d_in, const int* in_sizes, int n_in,
                              void* d_out, int out_size, void* d_ws, size_t ws_size,
                              hipStream_t stream) {
    const float* x      = (const float*)d_in[0];
    const float* y      = (const float*)d_in[1];
    const float* enc_w  = (const float*)d_in[2];
    const float* enc_b  = (const float*)d_in[3];
    const float* yenc_w = (const float*)d_in[4];
    const float* yenc_b = (const float*)d_in[5];
    const float* qkv_w  = (const float*)d_in[6];
    const float* qkv_b  = (const float*)d_in[7];
    const float* out_w  = (const float*)d_in[8];
    const float* out_b  = (const float*)d_in[9];
    const float* ln1_g  = (const float*)d_in[10];
    const float* ln1_b  = (const float*)d_in[11];
    const float* ln2_g  = (const float*)d_in[12];
    const float* ln2_b  = (const float*)d_in[13];
    const float* ff1_w  = (const float*)d_in[14];
    const float* ff1_b  = (const float*)d_in[15];
    const float* ff2_w  = (const float*)d_in[16];
    const float* ff2_b  = (const float*)d_in[17];
    const float* dec_w1 = (const float*)d_in[18];
    const float* dec_b1 = (const float*)d_in[19];
    const float* dec_w2 = (const float*)d_in[20];
    const float* dec_b2 = (const float*)d_in[21];

    float* ws     = (float*)d_ws;
    float* h      = ws;                                  // 1,048,576 f
    u16*   h_bf   = (u16*)(h + 1048576);                 // 1,048,576 u16
    u16*   qkv_bf = h_bf + 1048576;                      // 3,145,728 u16
    u16*   vt     = qkv_bf + 3145728;                    // 1,048,576 u16
    u16*   attn_bf= vt + 1048576;                        // 1,048,576 u16
    u16*   ffb_bf = attn_bf + 1048576;                   // 2,097,152 u16
    u16*   wq     = ffb_bf + 2097152;                    // 3,145,728 u16
    u16*   wo     = wq + 3145728;                        // 1,048,576 u16
    u16*   wf1    = wo + 1048576;                        // 2,097,152 u16
    u16*   wf2    = wf1 + 2097152;                       // 2,097,152 u16
    float* big    = (float*)(wf2 + 2097152);             // 1,048,576 f
    float* pooled = big + 1048576;                       // 1,024
    float* dbuf   = pooled + 1024;                       // 4,096
    float* flat   = dbuf + 4096;                         // 61,460

    cvt_bf<<<2048, 256, 0, stream>>>(qkv_w, wq, 4 * 786432);
    cvt_bf<<<2048, 256, 0, stream>>>(out_w, wo, 4 * 262144);
    cvt_bf<<<2048, 256, 0, stream>>>(ff1_w, wf1, 4 * 524288);
    cvt_bf<<<2048, 256, 0, stream>>>(ff2_w, wf2, 4 * 524288);

    encoder_kernel<<<NTOK, EDIM, 0, stream>>>(x, y, enc_w, enc_b, yenc_w, yenc_b, h, h_bf);

    for (int l = 0; l < NLAYER; l++) {
        // qkv = h @ qkv_w[l].T + qkv_b[l]  -> bf16 [2048 x 1536]
        gemm_bf16<<<dim3(24, 32, 1), 256, 0, stream>>>(
            h_bf, EDIM, 0, 0,
            wq + (size_t)l * 786432, EDIM, 0, 0,
            qkv_bf, 1536, 0, 0, 1,
            1, EDIM, 1.f, qkv_b + (size_t)l * 1536, 0);

        vtrans_kernel<<<dim3(16, 16), 256, 0, stream>>>(qkv_bf, vt);

        // fused attention -> attn_bf
        flash_attn<<<dim3(16, 16), 256, 0, stream>>>(qkv_bf, vt, attn_bf);

        // proj = attn @ out_w[l].T + out_b[l] -> f32 big
        gemm_bf16<<<dim3(8, 32, 1), 256, 0, stream>>>(
            attn_bf, EDIM, 0, 0,
            wo + (size_t)l * 262144, EDIM, 0, 0,
            big, EDIM, 0, 0, 0,
            1, EDIM, 1.f, out_b + (size_t)l * EDIM, 0);

        add_ln_kernel<<<NTOK, 256, 0, stream>>>(h, big,
            ln1_g + (size_t)l * EDIM, ln1_b + (size_t)l * EDIM, h, h_bf);

        // ffb = gelu(h @ ff1_w[l].T + ff1_b[l]) -> bf16 [2048 x 1024]
        gemm_bf16<<<dim3(16, 32, 1), 256, 0, stream>>>(
            h_bf, EDIM, 0, 0,
            wf1 + (size_t)l * 524288, EDIM, 0, 0,
            ffb_bf, NHID, 0, 0, 1,
            1, EDIM, 1.f, ff1_b + (size_t)l * NHID, 2);

        // f = ffb @ ff2_w[l].T + ff2_b[l] -> f32 big
        gemm_bf16<<<dim3(8, 32, 1), 256, 0, stream>>>(
            ffb_bf, NHID, 0, 0,
            wf2 + (size_t)l * 524288, NHID, 0, 0,
            big, EDIM, 0, 0, 0,
            1, NHID, 1.f, ff2_b + (size_t)l * EDIM, 0);

        add_ln_kernel<<<NTOK, 256, 0, stream>>>(h, big,
            ln2_g + (size_t)l * EDIM, ln2_b + (size_t)l * EDIM, h, h_bf);
    }

    pool_kernel<<<4, 256, 0, stream>>>(h, pooled);

    wavedot2_kernel<<<512, 256, 0, stream>>>(
        pooled, pooled + EDIM, dec_w1, dec_b1, dbuf, dbuf + DECD, DECD, EDIM, 1);

    wavedot2_kernel<<<7683, 256, 0, stream>>>(
        dbuf, dbuf + DECD, dec_w2, dec_b2, flat, flat + TOTALW, TOTALW, DECD, 0);

    final_mlp_kernel<<<2048, 128, 0, stream>>>(x, flat, (float*)d_out);
}

// Round 8
// 626.047 us; speedup vs baseline: 5.0717x; 1.2904x over previous
//
#include <hip/hip_runtime.h>

// MotherNet forward — R8: 2-phase global_load_lds GEMM (T3 minimum recipe),
// coalesced two-stage pool, merged weight-convert. Flash attention unchanged.

#define BATCH  2
#define FDIM   100
#define EDIM   512
#define NHEADS 8
#define HD     64
#define NHID   1024
#define NLAYER 4
#define HDIM   128
#define NOUTD  10
#define DECD   2048
#define SEPP   1024
#define TOTALW 30730
#define NTOK   2048

typedef unsigned short u16;
typedef __attribute__((ext_vector_type(8))) short bf16x8;
typedef __attribute__((ext_vector_type(4))) float f32x4;

__device__ __forceinline__ float nanfix(float v) {
    if (isnan(v)) return 0.f;
    if (isinf(v)) return v > 0.f ? 3.4028234663852886e38f : -3.4028234663852886e38f;
    return v;
}
__device__ __forceinline__ u16 f2bf(float f) {   // RTNE, finite inputs
    unsigned u = __float_as_uint(f);
    u += 0x7fffu + ((u >> 16) & 1u);
    return (u16)(u >> 16);
}

#define GLOAD16(gsrc, ldst) \
    __builtin_amdgcn_global_load_lds( \
        (const __attribute__((address_space(1))) void*)(gsrc), \
        (__attribute__((address_space(3))) void*)(ldst), 16, 0, 0)

// ---------------------------------------------------------------------------
// 2-phase double-buffered bf16 GEMM: C = act(alpha * A @ B^T + bias)
// A[M,K], B[N,K] bf16; 64x64 tile, BK=64, 4 waves (each 32x32 = 2x2 frags).
// LDS XOR swizzle (r&7)<<4 on byte col; global source pre-swizzled (rule #21).
// M,N multiples of 64; K multiple of 64.
// ---------------------------------------------------------------------------
__global__ __launch_bounds__(256) void gemm2(
    const u16* __restrict__ A, int lda,
    const u16* __restrict__ B, int ldb,
    void* __restrict__ Cv, int ldc, int cbf,
    int K, float alpha, const float* __restrict__ bias, int act)
{
    __shared__ __align__(16) u16 lds[2][8192];   // [buf][A:0..4095 | B:4096..8191]

    int tid = threadIdx.x;
    int lane = tid & 63, w = tid >> 6;
    int wr = w >> 1, wc = w & 1;
    int mBase = blockIdx.y * 64, nBase = blockIdx.x * 64;
    int r16 = lane & 15, kg = lane >> 4;

    // --- staging source map (inverse swizzle): chunk c -> (row, elem) ---
    // c = (q*4+w)*64 + lane ; r = c>>3 ; elem = (((c&7)*16) ^ ((r&7)<<4)) >> 1
    int c0 = w * 64 + lane;            // q=0
    int c1 = 256 + w * 64 + lane;      // q=1
    int r0 = c0 >> 3, r1 = c1 >> 3;
    int e0 = ((((c0 & 7) * 16) ^ ((r0 & 7) << 4)) >> 1);
    int e1 = ((((c1 & 7) * 16) ^ ((r1 & 7) << 4)) >> 1);
    const u16* sA0 = A + (long long)(mBase + r0) * lda + e0;
    const u16* sA1 = A + (long long)(mBase + r1) * lda + e1;
    const u16* sB0 = B + (long long)(nBase + r0) * ldb + e0;
    const u16* sB1 = B + (long long)(nBase + r1) * ldb + e1;
    // wave-uniform LDS dests (u16 units; 1024 B = 512 u16 per wave-issue)
    int dA0 = w * 512, dA1 = 2048 + w * 512;
    int dB0 = 4096 + w * 512, dB1 = 6144 + w * 512;

    // --- compute-side swizzled read offsets (u16 units) ---
    int ra0 = wr * 32 + r16,      ra1 = wr * 32 + 16 + r16;
    int rb0 = wc * 32 + r16,      rb1 = wc * 32 + 16 + r16;
    int cb0 = kg * 16;             // ksub 0 byte-col
    int cb1 = 64 + kg * 16;        // ksub 1 byte-col
    int oa00 = (ra0 * 128 + (cb0 ^ ((ra0 & 7) << 4))) >> 1;
    int oa01 = (ra0 * 128 + (cb1 ^ ((ra0 & 7) << 4))) >> 1;
    int oa10 = (ra1 * 128 + (cb0 ^ ((ra1 & 7) << 4))) >> 1;
    int oa11 = (ra1 * 128 + (cb1 ^ ((ra1 & 7) << 4))) >> 1;
    int ob00 = 4096 + ((rb0 * 128 + (cb0 ^ ((rb0 & 7) << 4))) >> 1);
    int ob01 = 4096 + ((rb0 * 128 + (cb1 ^ ((rb0 & 7) << 4))) >> 1);
    int ob10 = 4096 + ((rb1 * 128 + (cb0 ^ ((rb1 & 7) << 4))) >> 1);
    int ob11 = 4096 + ((rb1 * 128 + (cb1 ^ ((rb1 & 7) << 4))) >> 1);

    f32x4 acc00 = {0.f, 0.f, 0.f, 0.f};
    f32x4 acc01 = acc00, acc10 = acc00, acc11 = acc00;

    int nt = K >> 6;
    // prologue: stage tile 0 into buf 0
    GLOAD16(sA0, &lds[0][dA0]);
    GLOAD16(sA1, &lds[0][dA1]);
    GLOAD16(sB0, &lds[0][dB0]);
    GLOAD16(sB1, &lds[0][dB1]);
    __syncthreads();

    int cur = 0;
    for (int t = 0; t < nt; t++) {
        if (t + 1 < nt) {   // issue next-tile loads into other buffer
            int ko = (t + 1) << 6;
            GLOAD16(sA0 + ko, &lds[cur ^ 1][dA0]);
            GLOAD16(sA1 + ko, &lds[cur ^ 1][dA1]);
            GLOAD16(sB0 + ko, &lds[cur ^ 1][dB0]);
            GLOAD16(sB1 + ko, &lds[cur ^ 1][dB1]);
        }
        const u16* L = &lds[cur][0];
        // ksub 0
        bf16x8 a0 = *(const bf16x8*)(L + oa00);
        bf16x8 a1 = *(const bf16x8*)(L + oa10);
        bf16x8 b0 = *(const bf16x8*)(L + ob00);
        bf16x8 b1 = *(const bf16x8*)(L + ob10);
        acc00 = __builtin_amdgcn_mfma_f32_16x16x32_bf16(a0, b0, acc00, 0, 0, 0);
        acc01 = __builtin_amdgcn_mfma_f32_16x16x32_bf16(a0, b1, acc01, 0, 0, 0);
        acc10 = __builtin_amdgcn_mfma_f32_16x16x32_bf16(a1, b0, acc10, 0, 0, 0);
        acc11 = __builtin_amdgcn_mfma_f32_16x16x32_bf16(a1, b1, acc11, 0, 0, 0);
        // ksub 1
        a0 = *(const bf16x8*)(L + oa01);
        a1 = *(const bf16x8*)(L + oa11);
        b0 = *(const bf16x8*)(L + ob01);
        b1 = *(const bf16x8*)(L + ob11);
        acc00 = __builtin_amdgcn_mfma_f32_16x16x32_bf16(a0, b0, acc00, 0, 0, 0);
        acc01 = __builtin_amdgcn_mfma_f32_16x16x32_bf16(a0, b1, acc01, 0, 0, 0);
        acc10 = __builtin_amdgcn_mfma_f32_16x16x32_bf16(a1, b0, acc10, 0, 0, 0);
        acc11 = __builtin_amdgcn_mfma_f32_16x16x32_bf16(a1, b1, acc11, 0, 0, 0);
        __syncthreads();   // drains vmcnt -> next buffer ready; reads done
        cur ^= 1;
    }

    #pragma unroll
    for (int i = 0; i < 2; i++) {
        #pragma unroll
        for (int j = 0; j < 2; j++) {
            f32x4 v = (i == 0) ? (j == 0 ? acc00 : acc01) : (j == 0 ? acc10 : acc11);
            int col = nBase + wc * 32 + j * 16 + r16;
            float bv = bias ? bias[col] : 0.f;
            long long base = (long long)(mBase + wr * 32 + i * 16 + kg * 4) * ldc + col;
            #pragma unroll
            for (int r = 0; r < 4; r++) {
                float c = v[r] * alpha + bv;
                if (act == 2) {  // jax.nn.gelu approximate=True
                    float u = 0.7978845608028654f * (c + 0.044715f * c * c * c);
                    c = 0.5f * c * (1.f + tanhf(u));
                }
                if (cbf) ((u16*)Cv)[base + (long long)r * ldc] = f2bf(c);
                else     ((float*)Cv)[base + (long long)r * ldc] = c;
            }
        }
    }
}

// ---------------------------------------------------------------------------
// Fused flash attention (unchanged from R7).
// ---------------------------------------------------------------------------
__global__ __launch_bounds__(256) void flash_attn(
    const u16* __restrict__ qkvb, const u16* __restrict__ vtm,
    u16* __restrict__ attnb)
{
    int qt = blockIdx.x;
    int bh = blockIdx.y;
    int cb = bh >> 3, hh = bh & 7;
    int tid = threadIdx.x;
    int w = tid >> 6, lane = tid & 63;
    int r16 = lane & 15, kg = lane >> 4;

    __shared__ __align__(16) u16 plds[4][2048];
    u16* pl = &plds[w][0];

    int qrow = qt * 64 + w * 16 + r16;
    const u16* qp = qkvb + ((long long)qrow * 2 + cb) * 1536 + hh * 64 + kg * 8;
    bf16x8 qf0 = *(const bf16x8*)(qp);
    bf16x8 qf1 = *(const bf16x8*)(qp + 32);

    const u16* kbase = qkvb + (long long)cb * 1536 + 512 + hh * 64;
    const u16* vbase = vtm + ((long long)bh * 64) * 1024;

    f32x4 m = {-3e38f, -3e38f, -3e38f, -3e38f};
    f32x4 l = {0.f, 0.f, 0.f, 0.f};
    f32x4 o[4] = {};

    int rb0 = (((r16 * 64 + kg * 8) * 2) ^ ((r16 & 7) << 4)) >> 1;
    int rb1 = (((r16 * 64 + 32 + kg * 8) * 2) ^ ((r16 & 7) << 4)) >> 1;

    for (int kt = 0; kt < 16; kt++) {
        f32x4 s[4];
        #pragma unroll
        for (int nb = 0; nb < 4; nb++) {
            int key = kt * 64 + nb * 16 + r16;
            const u16* kp = kbase + (long long)key * 3072 + kg * 8;
            bf16x8 kf0 = *(const bf16x8*)(kp);
            bf16x8 kf1 = *(const bf16x8*)(kp + 32);
            f32x4 acc = {};
            acc = __builtin_amdgcn_mfma_f32_16x16x32_bf16(qf0, kf0, acc, 0, 0, 0);
            acc = __builtin_amdgcn_mfma_f32_16x16x32_bf16(qf1, kf1, acc, 0, 0, 0);
            s[nb] = acc;
        }
        #pragma unroll
        for (int nb = 0; nb < 4; nb++)
            #pragma unroll
            for (int r = 0; r < 4; r++) s[nb][r] *= 0.125f;

        f32x4 tm;
        #pragma unroll
        for (int r = 0; r < 4; r++)
            tm[r] = fmaxf(fmaxf(s[0][r], s[1][r]), fmaxf(s[2][r], s[3][r]));
        #pragma unroll
        for (int off = 1; off < 16; off <<= 1) {
            #pragma unroll
            for (int r = 0; r < 4; r++) tm[r] = fmaxf(tm[r], __shfl_xor(tm[r], off));
        }
        f32x4 mn, al;
        #pragma unroll
        for (int r = 0; r < 4; r++) {
            mn[r] = fmaxf(m[r], tm[r]);
            al[r] = __expf(m[r] - mn[r]);
            m[r] = mn[r];
        }
        f32x4 rs = {};
        #pragma unroll
        for (int nb = 0; nb < 4; nb++)
            #pragma unroll
            for (int r = 0; r < 4; r++) {
                float p = __expf(s[nb][r] - mn[r]);
                s[nb][r] = p;
                rs[r] += p;
            }
        #pragma unroll
        for (int off = 1; off < 16; off <<= 1) {
            #pragma unroll
            for (int r = 0; r < 4; r++) rs[r] += __shfl_xor(rs[r], off);
        }
        #pragma unroll
        for (int r = 0; r < 4; r++) l[r] = l[r] * al[r] + rs[r];
        #pragma unroll
        for (int db = 0; db < 4; db++)
            #pragma unroll
            for (int r = 0; r < 4; r++) o[db][r] *= al[r];

        #pragma unroll
        for (int nb = 0; nb < 4; nb++)
            #pragma unroll
            for (int r = 0; r < 4; r++) {
                int row = kg * 4 + r;
                int col = nb * 16 + r16;
                int byi = (((row * 64 + col) * 2) ^ ((row & 7) << 4)) >> 1;
                pl[byi] = f2bf(s[nb][r]);
            }
        __syncthreads();

        bf16x8 pa0 = *(const bf16x8*)(pl + rb0);
        bf16x8 pa1 = *(const bf16x8*)(pl + rb1);
        #pragma unroll
        for (int db = 0; db < 4; db++) {
            const u16* vp = vbase + (long long)(db * 16 + r16) * 1024 + kt * 64 + kg * 8;
            bf16x8 vf0 = *(const bf16x8*)(vp);
            bf16x8 vf1 = *(const bf16x8*)(vp + 32);
            o[db] = __builtin_amdgcn_mfma_f32_16x16x32_bf16(pa0, vf0, o[db], 0, 0, 0);
            o[db] = __builtin_amdgcn_mfma_f32_16x16x32_bf16(pa1, vf1, o[db], 0, 0, 0);
        }
    }

    f32x4 linv;
    #pragma unroll
    for (int r = 0; r < 4; r++) linv[r] = 1.f / l[r];
    #pragma unroll
    for (int db = 0; db < 4; db++)
        #pragma unroll
        for (int r = 0; r < 4; r++) {
            int row = qt * 64 + w * 16 + kg * 4 + r;
            attnb[((long long)row * 2 + cb) * 512 + hh * 64 + db * 16 + r16] =
                f2bf(o[db][r] * linv[r]);
        }
}

// merged f32->bf16 convert for the 4 transformer weight tensors
__global__ __launch_bounds__(256) void cvt_all(
    const float* __restrict__ s0, const float* __restrict__ s1,
    const float* __restrict__ s2, const float* __restrict__ s3,
    u16* __restrict__ d0, u16* __restrict__ d1,
    u16* __restrict__ d2, u16* __restrict__ d3)
{
    const int n0 = 3145728, n1 = 1048576, n2 = 2097152, n3 = 2097152;
    int i = blockIdx.x * 256 + threadIdx.x;
    int st = gridDim.x * 256;
    for (; i < n0 + n1 + n2 + n3; i += st) {
        if (i < n0) d0[i] = f2bf(s0[i]);
        else if (i < n0 + n1) d1[i - n0] = f2bf(s1[i - n0]);
        else if (i < n0 + n1 + n2) d2[i - n0 - n1] = f2bf(s2[i - n0 - n1]);
        else d3[i - n0 - n1 - n2] = f2bf(s3[i - n0 - n1 - n2]);
    }
}

__global__ __launch_bounds__(512) void encoder_kernel(
    const float* __restrict__ x, const float* __restrict__ y,
    const float* __restrict__ enc_w, const float* __restrict__ enc_b,
    const float* __restrict__ yenc_w, const float* __restrict__ yenc_b,
    float* __restrict__ h, u16* __restrict__ h_bf)
{
    int t = blockIdx.x;
    __shared__ float xs[FDIM];
    int tid = threadIdx.x;
    if (tid < FDIM) xs[tid] = nanfix(x[(long long)t * FDIM + tid]);
    __syncthreads();
    float yv = y[t];
    int e = tid;
    float acc = enc_b[e] + yv * yenc_w[e] + yenc_b[e];
    const float* wr = enc_w + (long long)e * FDIM;
    #pragma unroll 4
    for (int f = 0; f < FDIM; f++) acc = fmaf(xs[f], wr[f], acc);
    h[(long long)t * EDIM + e] = acc;
    h_bf[(long long)t * EDIM + e] = f2bf(acc);
}

__global__ __launch_bounds__(256) void add_ln_kernel(
    const float* a, const float* __restrict__ r,
    const float* __restrict__ g, const float* __restrict__ be,
    float* out, u16* __restrict__ out_bf)
{
    int row = blockIdx.x;
    int tid = threadIdx.x;
    const float* pa = a + (long long)row * EDIM;
    const float* pr = r + (long long)row * EDIM;
    float v0 = pa[tid] + pr[tid];
    float v1 = pa[tid + 256] + pr[tid + 256];
    float s = v0 + v1, q = v0 * v0 + v1 * v1;
    #pragma unroll
    for (int off = 32; off; off >>= 1) {
        s += __shfl_xor(s, off);
        q += __shfl_xor(q, off);
    }
    __shared__ float ss[4], sq[4];
    int w = tid >> 6, lane = tid & 63;
    if (lane == 0) { ss[w] = s; sq[w] = q; }
    __syncthreads();
    s = ss[0] + ss[1] + ss[2] + ss[3];
    q = sq[0] + sq[1] + sq[2] + sq[3];
    float mean = s * (1.f / EDIM);
    float var = q * (1.f / EDIM) - mean * mean;
    float rstd = rsqrtf(var + 1e-5f);
    float o0 = (v0 - mean) * rstd * g[tid] + be[tid];
    float o1 = (v1 - mean) * rstd * g[tid + 256] + be[tid + 256];
    float* po = out + (long long)row * EDIM;
    u16* pb = out_bf + (long long)row * EDIM;
    po[tid] = o0;        po[tid + 256] = o1;
    pb[tid] = f2bf(o0);  pb[tid + 256] = f2bf(o1);
}

// V transpose (unchanged)
__global__ __launch_bounds__(256) void vtrans_kernel(
    const u16* __restrict__ qkvb, u16* __restrict__ vt)
{
    __shared__ u16 tile[64][66];
    int bx = blockIdx.x;
    int by = blockIdx.y;
    int cb = by >> 3, hh = by & 7;
    int tid = threadIdx.x;
    int c = tid & 63, w4 = tid >> 6;
    #pragma unroll 4
    for (int i = 0; i < 16; i++) {
        int sl = w4 * 16 + i;
        tile[sl][c] = qkvb[((long long)((bx * 64 + sl) * 2 + cb)) * 1536 + 1024 + hh * 64 + c];
    }
    __syncthreads();
    #pragma unroll 4
    for (int i = 0; i < 16; i++) {
        int dl = w4 * 16 + i;
        vt[((long long)(by * 64 + dl)) * 1024 + bx * 64 + c] = tile[c][dl];
    }
}

// two-stage coalesced mean-pool: h rows (si*2+b)*512+e ; idx = b*512+e
__global__ __launch_bounds__(1024) void pool1_kernel(
    const float* __restrict__ h, float* __restrict__ part)
{
    int j = blockIdx.x;            // 0..31
    int idx = threadIdx.x;         // 0..1023
    float s = 0.f;
    #pragma unroll 8
    for (int k = 0; k < 32; k++)
        s += h[(long long)(j * 32 + k) * 1024 + idx];
    part[j * 1024 + idx] = s;
}
__global__ __launch_bounds__(1024) void pool2_kernel(
    const float* __restrict__ part, float* __restrict__ pooled)
{
    int idx = threadIdx.x;
    float s = 0.f;
    #pragma unroll 8
    for (int j = 0; j < 32; j++) s += part[j * 1024 + idx];
    pooled[idx] = s * (1.f / 1024.f);
}

__global__ __launch_bounds__(256) void wavedot2_kernel(
    const float* __restrict__ v0, const float* __restrict__ v1,
    const float* __restrict__ W, const float* __restrict__ bias,
    float* __restrict__ out0, float* __restrict__ out1,
    int R, int K, int act)
{
    int gw = (blockIdx.x * 256 + threadIdx.x) >> 6;
    int lane = threadIdx.x & 63;
    int nw = (gridDim.x * 256) >> 6;
    const float4* x0 = (const float4*)v0;
    const float4* x1 = (const float4*)v1;
    for (int r = gw; r < R; r += nw) {
        const float4* w4 = (const float4*)(W + (long long)r * K);
        float a0 = 0.f, a1 = 0.f;
        for (int i = lane; i < (K >> 2); i += 64) {
            float4 w = w4[i];
            float4 p = x0[i];
            float4 q = x1[i];
            a0 += w.x * p.x + w.y * p.y + w.z * p.z + w.w * p.w;
            a1 += w.x * q.x + w.y * q.y + w.z * q.z + w.w * q.w;
        }
        #pragma unroll
        for (int off = 32; off; off >>= 1) {
            a0 += __shfl_xor(a0, off);
            a1 += __shfl_xor(a1, off);
        }
        if (lane == 0) {
            float bb = bias[r];
            float o0 = a0 + bb, o1 = a1 + bb;
            if (act == 1) { o0 = fmaxf(o0, 0.f); o1 = fmaxf(o1, 0.f); }
            out0[r] = o0; out1[r] = o1;
        }
    }
}

__global__ __launch_bounds__(128) void final_mlp_kernel(
    const float* __restrict__ x, const float* __restrict__ flat,
    float* __restrict__ out)
{
    int t = blockIdx.x;
    int b = t & 1;
    int tid = threadIdx.x;
    const float* fl = flat + (long long)b * TOTALW;
    __shared__ float xs[FDIM], t1s[HDIM], t2s[HDIM];
    if (tid < FDIM) xs[tid] = nanfix(x[(long long)(NTOK + t) * FDIM + tid]);
    __syncthreads();
    {
        float acc = fl[tid];
        const float* w1 = fl + HDIM;
        #pragma unroll 4
        for (int f = 0; f < FDIM; f++) acc = fmaf(xs[f], w1[f * HDIM + tid], acc);
        t1s[tid] = fmaxf(acc, 0.f);
    }
    __syncthreads();
    {
        float acc = fl[12928 + tid];
        const float* w2 = fl + 13056;
        #pragma unroll 4
        for (int hh = 0; hh < HDIM; hh++) acc = fmaf(t1s[hh], w2[hh * HDIM + tid], acc);
        t2s[tid] = fmaxf(acc, 0.f);
    }
    __syncthreads();
    if (tid < NOUTD) {
        float acc = fl[29440 + tid];
        const float* w3 = fl + 29450;
        #pragma unroll 4
        for (int hh = 0; hh < HDIM; hh++) acc = fmaf(t2s[hh], w3[hh * NOUTD + tid], acc);
        out[(long long)t * NOUTD + tid] = acc;
    }
}

// ---------------------------------------------------------------------------
extern "C" void kernel_launch(void* const* d_in, const int* in_sizes, int n_in,
                              void* d_out, int out_size, void* d_ws, size_t ws_size,
                              hipStream_t stream) {
    const float* x      = (const float*)d_in[0];
    const float* y      = (const float*)d_in[1];
    const float* enc_w  = (const float*)d_in[2];
    const float* enc_b  = (const float*)d_in[3];
    const float* yenc_w = (const float*)d_in[4];
    const float* yenc_b = (const float*)d_in[5];
    const float* qkv_w  = (const float*)d_in[6];
    const float* qkv_b  = (const float*)d_in[7];
    const float* out_w  = (const float*)d_in[8];
    const float* out_b  = (const float*)d_in[9];
    const float* ln1_g  = (const float*)d_in[10];
    const float* ln1_b  = (const float*)d_in[11];
    const float* ln2_g  = (const float*)d_in[12];
    const float* ln2_b  = (const float*)d_in[13];
    const float* ff1_w  = (const float*)d_in[14];
    const float* ff1_b  = (const float*)d_in[15];
    const float* ff2_w  = (const float*)d_in[16];
    const float* ff2_b  = (const float*)d_in[17];
    const float* dec_w1 = (const float*)d_in[18];
    const float* dec_b1 = (const float*)d_in[19];
    const float* dec_w2 = (const float*)d_in[20];
    const float* dec_b2 = (const float*)d_in[21];

    float* ws     = (float*)d_ws;
    float* h      = ws;                                  // 1,048,576 f
    u16*   h_bf   = (u16*)(h + 1048576);                 // 1,048,576 u16
    u16*   qkv_bf = h_bf + 1048576;                      // 3,145,728 u16
    u16*   vt     = qkv_bf + 3145728;                    // 1,048,576 u16
    u16*   attn_bf= vt + 1048576;                        // 1,048,576 u16
    u16*   ffb_bf = attn_bf + 1048576;                   // 2,097,152 u16
    u16*   wq     = ffb_bf + 2097152;                    // 3,145,728 u16
    u16*   wo     = wq + 3145728;                        // 1,048,576 u16
    u16*   wf1    = wo + 1048576;                        // 2,097,152 u16
    u16*   wf2    = wf1 + 2097152;                       // 2,097,152 u16
    float* big    = (float*)(wf2 + 2097152);             // 1,048,576 f
    float* part   = big + 1048576;                       // 32,768
    float* pooled = part + 32768;                        // 1,024
    float* dbuf   = pooled + 1024;                       // 4,096
    float* flat   = dbuf + 4096;                         // 61,460

    cvt_all<<<4096, 256, 0, stream>>>(qkv_w, out_w, ff1_w, ff2_w, wq, wo, wf1, wf2);

    encoder_kernel<<<NTOK, EDIM, 0, stream>>>(x, y, enc_w, enc_b, yenc_w, yenc_b, h, h_bf);

    for (int l = 0; l < NLAYER; l++) {
        // qkv = h @ qkv_w[l].T + qkv_b[l]  -> bf16 [2048 x 1536]
        gemm2<<<dim3(24, 32), 256, 0, stream>>>(
            h_bf, EDIM, wq + (size_t)l * 786432, EDIM,
            qkv_bf, 1536, 1, EDIM, 1.f, qkv_b + (size_t)l * 1536, 0);

        vtrans_kernel<<<dim3(16, 16), 256, 0, stream>>>(qkv_bf, vt);

        flash_attn<<<dim3(16, 16), 256, 0, stream>>>(qkv_bf, vt, attn_bf);

        // proj = attn @ out_w[l].T + out_b[l] -> f32 big
        gemm2<<<dim3(8, 32), 256, 0, stream>>>(
            attn_bf, EDIM, wo + (size_t)l * 262144, EDIM,
            big, EDIM, 0, EDIM, 1.f, out_b + (size_t)l * EDIM, 0);

        add_ln_kernel<<<NTOK, 256, 0, stream>>>(h, big,
            ln1_g + (size_t)l * EDIM, ln1_b + (size_t)l * EDIM, h, h_bf);

        // ffb = gelu(h @ ff1_w[l].T + ff1_b[l]) -> bf16 [2048 x 1024]
        gemm2<<<dim3(16, 32), 256, 0, stream>>>(
            h_bf, EDIM, wf1 + (size_t)l * 524288, EDIM,
            ffb_bf, NHID, 1, EDIM, 1.f, ff1_b + (size_t)l * NHID, 2);

        // f = ffb @ ff2_w[l].T + ff2_b[l] -> f32 big
        gemm2<<<dim3(8, 32), 256, 0, stream>>>(
            ffb_bf, NHID, wf2 + (size_t)l * 524288, NHID,
            big, EDIM, 0, NHID, 1.f, ff2_b + (size_t)l * EDIM, 0);

        add_ln_kernel<<<NTOK, 256, 0, stream>>>(h, big,
            ln2_g + (size_t)l * EDIM, ln2_b + (size_t)l * EDIM, h, h_bf);
    }

    pool1_kernel<<<32, 1024, 0, stream>>>(h, part);
    pool2_kernel<<<1, 1024, 0, stream>>>(part, pooled);

    wavedot2_kernel<<<512, 256, 0, stream>>>(
        pooled, pooled + EDIM, dec_w1, dec_b1, dbuf, dbuf + DECD, DECD, EDIM, 1);

    wavedot2_kernel<<<7683, 256, 0, stream>>>(
        dbuf, dbuf + DECD, dec_w2, dec_b2, flat, flat + TOTALW, TOTALW, DECD, 0);

    final_mlp_kernel<<<2048, 128, 0, stream>>>(x, flat, (float*)d_out);
}

// Round 9
// 539.758 us; speedup vs baseline: 5.8825x; 1.1599x over previous
//
#include <hip/hip_runtime.h>

// MotherNet forward — R9: flash v2 (8-wave kv-split, 2 waves/SIMD) +
// split-K proj/ff2 with reduction fused into add_ln3.

#define BATCH  2
#define FDIM   100
#define EDIM   512
#define NHEADS 8
#define HD     64
#define NHID   1024
#define NLAYER 4
#define HDIM   128
#define NOUTD  10
#define DECD   2048
#define SEPP   1024
#define TOTALW 30730
#define NTOK   2048

typedef unsigned short u16;
typedef __attribute__((ext_vector_type(8))) short bf16x8;
typedef __attribute__((ext_vector_type(4))) float f32x4;

__device__ __forceinline__ float nanfix(float v) {
    if (isnan(v)) return 0.f;
    if (isinf(v)) return v > 0.f ? 3.4028234663852886e38f : -3.4028234663852886e38f;
    return v;
}
__device__ __forceinline__ u16 f2bf(float f) {   // RTNE, finite inputs
    unsigned u = __float_as_uint(f);
    u += 0x7fffu + ((u >> 16) & 1u);
    return (u16)(u >> 16);
}

#define GLOAD16(gsrc, ldst) \
    __builtin_amdgcn_global_load_lds( \
        (const __attribute__((address_space(1))) void*)(gsrc), \
        (__attribute__((address_space(3))) void*)(ldst), 16, 0, 0)

// ---------------------------------------------------------------------------
// 2-phase double-buffered bf16 GEMM: C = act(alpha * A @ B^T + bias)
// A[M,K], B[N,K] bf16; 64x64 tile, BK=64, 4 waves (each 32x32 = 2x2 frags).
// blockIdx.z = K-chunk id: sources offset by z*K (K = chunk length),
// C offset by z*zCstride (f32 partial buffers for split-K).
// ---------------------------------------------------------------------------
__global__ __launch_bounds__(256) void gemm2(
    const u16* __restrict__ A, int lda,
    const u16* __restrict__ B, int ldb,
    void* __restrict__ Cv, int ldc, int cbf,
    int K, long long zCstride, float alpha,
    const float* __restrict__ bias, int act)
{
    __shared__ __align__(16) u16 lds[2][8192];

    int tid = threadIdx.x;
    int lane = tid & 63, w = tid >> 6;
    int wr = w >> 1, wc = w & 1;
    int mBase = blockIdx.y * 64, nBase = blockIdx.x * 64;
    int r16 = lane & 15, kg = lane >> 4;
    long long zk = (long long)blockIdx.z * K;
    long long offC = (long long)blockIdx.z * zCstride;

    int c0 = w * 64 + lane;
    int c1 = 256 + w * 64 + lane;
    int r0 = c0 >> 3, r1 = c1 >> 3;
    int e0 = ((((c0 & 7) * 16) ^ ((r0 & 7) << 4)) >> 1);
    int e1 = ((((c1 & 7) * 16) ^ ((r1 & 7) << 4)) >> 1);
    const u16* sA0 = A + (long long)(mBase + r0) * lda + e0 + zk;
    const u16* sA1 = A + (long long)(mBase + r1) * lda + e1 + zk;
    const u16* sB0 = B + (long long)(nBase + r0) * ldb + e0 + zk;
    const u16* sB1 = B + (long long)(nBase + r1) * ldb + e1 + zk;
    int dA0 = w * 512, dA1 = 2048 + w * 512;
    int dB0 = 4096 + w * 512, dB1 = 6144 + w * 512;

    int ra0 = wr * 32 + r16,      ra1 = wr * 32 + 16 + r16;
    int rb0 = wc * 32 + r16,      rb1 = wc * 32 + 16 + r16;
    int cb0 = kg * 16;
    int cb1 = 64 + kg * 16;
    int oa00 = (ra0 * 128 + (cb0 ^ ((ra0 & 7) << 4))) >> 1;
    int oa01 = (ra0 * 128 + (cb1 ^ ((ra0 & 7) << 4))) >> 1;
    int oa10 = (ra1 * 128 + (cb0 ^ ((ra1 & 7) << 4))) >> 1;
    int oa11 = (ra1 * 128 + (cb1 ^ ((ra1 & 7) << 4))) >> 1;
    int ob00 = 4096 + ((rb0 * 128 + (cb0 ^ ((rb0 & 7) << 4))) >> 1);
    int ob01 = 4096 + ((rb0 * 128 + (cb1 ^ ((rb0 & 7) << 4))) >> 1);
    int ob10 = 4096 + ((rb1 * 128 + (cb0 ^ ((rb1 & 7) << 4))) >> 1);
    int ob11 = 4096 + ((rb1 * 128 + (cb1 ^ ((rb1 & 7) << 4))) >> 1);

    f32x4 acc00 = {0.f, 0.f, 0.f, 0.f};
    f32x4 acc01 = acc00, acc10 = acc00, acc11 = acc00;

    int nt = K >> 6;
    GLOAD16(sA0, &lds[0][dA0]);
    GLOAD16(sA1, &lds[0][dA1]);
    GLOAD16(sB0, &lds[0][dB0]);
    GLOAD16(sB1, &lds[0][dB1]);
    __syncthreads();

    int cur = 0;
    for (int t = 0; t < nt; t++) {
        if (t + 1 < nt) {
            int ko = (t + 1) << 6;
            GLOAD16(sA0 + ko, &lds[cur ^ 1][dA0]);
            GLOAD16(sA1 + ko, &lds[cur ^ 1][dA1]);
            GLOAD16(sB0 + ko, &lds[cur ^ 1][dB0]);
            GLOAD16(sB1 + ko, &lds[cur ^ 1][dB1]);
        }
        const u16* L = &lds[cur][0];
        bf16x8 a0 = *(const bf16x8*)(L + oa00);
        bf16x8 a1 = *(const bf16x8*)(L + oa10);
        bf16x8 b0 = *(const bf16x8*)(L + ob00);
        bf16x8 b1 = *(const bf16x8*)(L + ob10);
        acc00 = __builtin_amdgcn_mfma_f32_16x16x32_bf16(a0, b0, acc00, 0, 0, 0);
        acc01 = __builtin_amdgcn_mfma_f32_16x16x32_bf16(a0, b1, acc01, 0, 0, 0);
        acc10 = __builtin_amdgcn_mfma_f32_16x16x32_bf16(a1, b0, acc10, 0, 0, 0);
        acc11 = __builtin_amdgcn_mfma_f32_16x16x32_bf16(a1, b1, acc11, 0, 0, 0);
        a0 = *(const bf16x8*)(L + oa01);
        a1 = *(const bf16x8*)(L + oa11);
        b0 = *(const bf16x8*)(L + ob01);
        b1 = *(const bf16x8*)(L + ob11);
        acc00 = __builtin_amdgcn_mfma_f32_16x16x32_bf16(a0, b0, acc00, 0, 0, 0);
        acc01 = __builtin_amdgcn_mfma_f32_16x16x32_bf16(a0, b1, acc01, 0, 0, 0);
        acc10 = __builtin_amdgcn_mfma_f32_16x16x32_bf16(a1, b0, acc10, 0, 0, 0);
        acc11 = __builtin_amdgcn_mfma_f32_16x16x32_bf16(a1, b1, acc11, 0, 0, 0);
        __syncthreads();
        cur ^= 1;
    }

    #pragma unroll
    for (int i = 0; i < 2; i++) {
        #pragma unroll
        for (int j = 0; j < 2; j++) {
            f32x4 v = (i == 0) ? (j == 0 ? acc00 : acc01) : (j == 0 ? acc10 : acc11);
            int col = nBase + wc * 32 + j * 16 + r16;
            float bv = bias ? bias[col] : 0.f;
            long long base = offC + (long long)(mBase + wr * 32 + i * 16 + kg * 4) * ldc + col;
            #pragma unroll
            for (int r = 0; r < 4; r++) {
                float c = v[r] * alpha + bv;
                if (act == 2) {  // jax.nn.gelu approximate=True
                    float u = 0.7978845608028654f * (c + 0.044715f * c * c * c);
                    c = 0.5f * c * (1.f + tanhf(u));
                }
                if (cbf) ((u16*)Cv)[base + (long long)r * ldc] = f2bf(c);
                else     ((float*)Cv)[base + (long long)r * ldc] = c;
            }
        }
    }
}

// ---------------------------------------------------------------------------
// Flash v2: 512 threads = 8 waves. Wave w: q-strip p=w&3 (16 rows), kv-half
// hf=w>>2 (512 keys). Per-wave private P tile in LDS (no loop barrier).
// Final merge of the two kv-halves via LDS.
// ---------------------------------------------------------------------------
__global__ __launch_bounds__(512) void flash_attn(
    const u16* __restrict__ qkvb, const u16* __restrict__ vtm,
    u16* __restrict__ attnb)
{
    int qt = blockIdx.x;
    int bh = blockIdx.y;
    int cb = bh >> 3, hh = bh & 7;
    int tid = threadIdx.x;
    int w = tid >> 6, lane = tid & 63;
    int p = w & 3, hf = w >> 2;
    int r16 = lane & 15, kg = lane >> 4;

    __shared__ __align__(16) u16 plds[8][2048];   // per-wave P tiles / merge buf
    u16* pl = &plds[w][0];

    int qrow = qt * 64 + p * 16 + r16;
    const u16* qp = qkvb + ((long long)qrow * 2 + cb) * 1536 + hh * 64 + kg * 8;
    bf16x8 qf0 = *(const bf16x8*)(qp);
    bf16x8 qf1 = *(const bf16x8*)(qp + 32);

    const u16* kbase = qkvb + (long long)cb * 1536 + 512 + hh * 64;
    const u16* vbase = vtm + ((long long)bh * 64) * 1024;

    f32x4 m = {-3e38f, -3e38f, -3e38f, -3e38f};
    f32x4 l = {0.f, 0.f, 0.f, 0.f};
    f32x4 o[4] = {};

    int rb0 = (((r16 * 64 + kg * 8) * 2) ^ ((r16 & 7) << 4)) >> 1;
    int rb1 = (((r16 * 64 + 32 + kg * 8) * 2) ^ ((r16 & 7) << 4)) >> 1;

    for (int kt = hf * 8; kt < hf * 8 + 8; kt++) {
        f32x4 s[4];
        #pragma unroll
        for (int nb = 0; nb < 4; nb++) {
            int key = kt * 64 + nb * 16 + r16;
            const u16* kp = kbase + (long long)key * 3072 + kg * 8;
            bf16x8 kf0 = *(const bf16x8*)(kp);
            bf16x8 kf1 = *(const bf16x8*)(kp + 32);
            f32x4 acc = {};
            acc = __builtin_amdgcn_mfma_f32_16x16x32_bf16(qf0, kf0, acc, 0, 0, 0);
            acc = __builtin_amdgcn_mfma_f32_16x16x32_bf16(qf1, kf1, acc, 0, 0, 0);
            s[nb] = acc;
        }
        #pragma unroll
        for (int nb = 0; nb < 4; nb++)
            #pragma unroll
            for (int r = 0; r < 4; r++) s[nb][r] *= 0.125f;

        f32x4 tm;
        #pragma unroll
        for (int r = 0; r < 4; r++)
            tm[r] = fmaxf(fmaxf(s[0][r], s[1][r]), fmaxf(s[2][r], s[3][r]));
        #pragma unroll
        for (int off = 1; off < 16; off <<= 1) {
            #pragma unroll
            for (int r = 0; r < 4; r++) tm[r] = fmaxf(tm[r], __shfl_xor(tm[r], off));
        }
        f32x4 mn, al;
        #pragma unroll
        for (int r = 0; r < 4; r++) {
            mn[r] = fmaxf(m[r], tm[r]);
            al[r] = __expf(m[r] - mn[r]);
            m[r] = mn[r];
        }
        f32x4 rs = {};
        #pragma unroll
        for (int nb = 0; nb < 4; nb++)
            #pragma unroll
            for (int r = 0; r < 4; r++) {
                float pv = __expf(s[nb][r] - mn[r]);
                s[nb][r] = pv;
                rs[r] += pv;
            }
        #pragma unroll
        for (int off = 1; off < 16; off <<= 1) {
            #pragma unroll
            for (int r = 0; r < 4; r++) rs[r] += __shfl_xor(rs[r], off);
        }
        #pragma unroll
        for (int r = 0; r < 4; r++) l[r] = l[r] * al[r] + rs[r];
        #pragma unroll
        for (int db = 0; db < 4; db++)
            #pragma unroll
            for (int r = 0; r < 4; r++) o[db][r] *= al[r];

        // P -> per-wave LDS (swizzled); wave-private, no barrier needed
        #pragma unroll
        for (int nb = 0; nb < 4; nb++)
            #pragma unroll
            for (int r = 0; r < 4; r++) {
                int row = kg * 4 + r;
                int col = nb * 16 + r16;
                int byi = (((row * 64 + col) * 2) ^ ((row & 7) << 4)) >> 1;
                pl[byi] = f2bf(s[nb][r]);
            }

        bf16x8 pa0 = *(const bf16x8*)(pl + rb0);
        bf16x8 pa1 = *(const bf16x8*)(pl + rb1);
        #pragma unroll
        for (int db = 0; db < 4; db++) {
            const u16* vp = vbase + (long long)(db * 16 + r16) * 1024 + kt * 64 + kg * 8;
            bf16x8 vf0 = *(const bf16x8*)(vp);
            bf16x8 vf1 = *(const bf16x8*)(vp + 32);
            o[db] = __builtin_amdgcn_mfma_f32_16x16x32_bf16(pa0, vf0, o[db], 0, 0, 0);
            o[db] = __builtin_amdgcn_mfma_f32_16x16x32_bf16(pa1, vf1, o[db], 0, 0, 0);
        }
    }

    // ---- merge the two kv-halves ----
    __syncthreads();                         // all waves done with P tiles
    float* fb = (float*)&plds[0][0];         // 4 waves x 64 lanes x 25 floats
    if (hf == 0) {
        int base = (w * 64 + lane) * 25;
        #pragma unroll
        for (int r = 0; r < 4; r++) { fb[base + r] = m[r]; fb[base + 4 + r] = l[r]; }
        #pragma unroll
        for (int db = 0; db < 4; db++)
            #pragma unroll
            for (int r = 0; r < 4; r++) fb[base + 8 + db * 4 + r] = o[db][r];
    }
    __syncthreads();
    if (hf == 1) {
        int base = ((w - 4) * 64 + lane) * 25;
        f32x4 a1, a2, linv;
        #pragma unroll
        for (int r = 0; r < 4; r++) {
            float m1 = fb[base + r], l1 = fb[base + 4 + r];
            float mm = fmaxf(m1, m[r]);
            a1[r] = __expf(m1 - mm);
            a2[r] = __expf(m[r] - mm);
            linv[r] = 1.f / (l1 * a1[r] + l[r] * a2[r]);
        }
        #pragma unroll
        for (int db = 0; db < 4; db++)
            #pragma unroll
            for (int r = 0; r < 4; r++) {
                float val = (fb[base + 8 + db * 4 + r] * a1[r] + o[db][r] * a2[r]) * linv[r];
                int row = qt * 64 + (w - 4) * 16 + kg * 4 + r;
                attnb[((long long)row * 2 + cb) * 512 + hh * 64 + db * 16 + r16] = f2bf(val);
            }
    }
}

// merged f32->bf16 convert for the 4 transformer weight tensors
__global__ __launch_bounds__(256) void cvt_all(
    const float* __restrict__ s0, const float* __restrict__ s1,
    const float* __restrict__ s2, const float* __restrict__ s3,
    u16* __restrict__ d0, u16* __restrict__ d1,
    u16* __restrict__ d2, u16* __restrict__ d3)
{
    const int n0 = 3145728, n1 = 1048576, n2 = 2097152, n3 = 2097152;
    int i = blockIdx.x * 256 + threadIdx.x;
    int st = gridDim.x * 256;
    for (; i < n0 + n1 + n2 + n3; i += st) {
        if (i < n0) d0[i] = f2bf(s0[i]);
        else if (i < n0 + n1) d1[i - n0] = f2bf(s1[i - n0]);
        else if (i < n0 + n1 + n2) d2[i - n0 - n1] = f2bf(s2[i - n0 - n1]);
        else d3[i - n0 - n1 - n2] = f2bf(s3[i - n0 - n1 - n2]);
    }
}

__global__ __launch_bounds__(512) void encoder_kernel(
    const float* __restrict__ x, const float* __restrict__ y,
    const float* __restrict__ enc_w, const float* __restrict__ enc_b,
    const float* __restrict__ yenc_w, const float* __restrict__ yenc_b,
    float* __restrict__ h, u16* __restrict__ h_bf)
{
    int t = blockIdx.x;
    __shared__ float xs[FDIM];
    int tid = threadIdx.x;
    if (tid < FDIM) xs[tid] = nanfix(x[(long long)t * FDIM + tid]);
    __syncthreads();
    float yv = y[t];
    int e = tid;
    float acc = enc_b[e] + yv * yenc_w[e] + yenc_b[e];
    const float* wr = enc_w + (long long)e * FDIM;
    #pragma unroll 4
    for (int f = 0; f < FDIM; f++) acc = fmaf(xs[f], wr[f], acc);
    h[(long long)t * EDIM + e] = acc;
    h_bf[(long long)t * EDIM + e] = f2bf(acc);
}

// out = LN(a + p0 + p1 + cbias)*g + be ; writes f32 + bf16. a may alias out.
__global__ __launch_bounds__(256) void add_ln3_kernel(
    const float* a, const float* __restrict__ p0, const float* __restrict__ p1,
    const float* __restrict__ cbias,
    const float* __restrict__ g, const float* __restrict__ be,
    float* out, u16* __restrict__ out_bf)
{
    int row = blockIdx.x;
    int tid = threadIdx.x;
    const float* pa = a + (long long)row * EDIM;
    const float* pr0 = p0 + (long long)row * EDIM;
    const float* pr1 = p1 + (long long)row * EDIM;
    float v0 = pa[tid] + pr0[tid] + pr1[tid] + cbias[tid];
    float v1 = pa[tid + 256] + pr0[tid + 256] + pr1[tid + 256] + cbias[tid + 256];
    float s = v0 + v1, q = v0 * v0 + v1 * v1;
    #pragma unroll
    for (int off = 32; off; off >>= 1) {
        s += __shfl_xor(s, off);
        q += __shfl_xor(q, off);
    }
    __shared__ float ss[4], sq[4];
    int w = tid >> 6, lane = tid & 63;
    if (lane == 0) { ss[w] = s; sq[w] = q; }
    __syncthreads();
    s = ss[0] + ss[1] + ss[2] + ss[3];
    q = sq[0] + sq[1] + sq[2] + sq[3];
    float mean = s * (1.f / EDIM);
    float var = q * (1.f / EDIM) - mean * mean;
    float rstd = rsqrtf(var + 1e-5f);
    float o0 = (v0 - mean) * rstd * g[tid] + be[tid];
    float o1 = (v1 - mean) * rstd * g[tid + 256] + be[tid + 256];
    float* po = out + (long long)row * EDIM;
    u16* pb = out_bf + (long long)row * EDIM;
    po[tid] = o0;        po[tid + 256] = o1;
    pb[tid] = f2bf(o0);  pb[tid + 256] = f2bf(o1);
}

// V transpose
__global__ __launch_bounds__(256) void vtrans_kernel(
    const u16* __restrict__ qkvb, u16* __restrict__ vt)
{
    __shared__ u16 tile[64][66];
    int bx = blockIdx.x;
    int by = blockIdx.y;
    int cb = by >> 3, hh = by & 7;
    int tid = threadIdx.x;
    int c = tid & 63, w4 = tid >> 6;
    #pragma unroll 4
    for (int i = 0; i < 16; i++) {
        int sl = w4 * 16 + i;
        tile[sl][c] = qkvb[((long long)((bx * 64 + sl) * 2 + cb)) * 1536 + 1024 + hh * 64 + c];
    }
    __syncthreads();
    #pragma unroll 4
    for (int i = 0; i < 16; i++) {
        int dl = w4 * 16 + i;
        vt[((long long)(by * 64 + dl)) * 1024 + bx * 64 + c] = tile[c][dl];
    }
}

// two-stage coalesced mean-pool
__global__ __launch_bounds__(1024) void pool1_kernel(
    const float* __restrict__ h, float* __restrict__ part)
{
    int j = blockIdx.x;
    int idx = threadIdx.x;
    float s = 0.f;
    #pragma unroll 8
    for (int k = 0; k < 32; k++)
        s += h[(long long)(j * 32 + k) * 1024 + idx];
    part[j * 1024 + idx] = s;
}
__global__ __launch_bounds__(1024) void pool2_kernel(
    const float* __restrict__ part, float* __restrict__ pooled)
{
    int idx = threadIdx.x;
    float s = 0.f;
    #pragma unroll 8
    for (int j = 0; j < 32; j++) s += part[j * 1024 + idx];
    pooled[idx] = s * (1.f / 1024.f);
}

__global__ __launch_bounds__(256) void wavedot2_kernel(
    const float* __restrict__ v0, const float* __restrict__ v1,
    const float* __restrict__ W, const float* __restrict__ bias,
    float* __restrict__ out0, float* __restrict__ out1,
    int R, int K, int act)
{
    int gw = (blockIdx.x * 256 + threadIdx.x) >> 6;
    int lane = threadIdx.x & 63;
    int nw = (gridDim.x * 256) >> 6;
    const float4* x0 = (const float4*)v0;
    const float4* x1 = (const float4*)v1;
    for (int r = gw; r < R; r += nw) {
        const float4* w4 = (const float4*)(W + (long long)r * K);
        float a0 = 0.f, a1 = 0.f;
        for (int i = lane; i < (K >> 2); i += 64) {
            float4 w = w4[i];
            float4 p = x0[i];
            float4 q = x1[i];
            a0 += w.x * p.x + w.y * p.y + w.z * p.z + w.w * p.w;
            a1 += w.x * q.x + w.y * q.y + w.z * q.z + w.w * q.w;
        }
        #pragma unroll
        for (int off = 32; off; off >>= 1) {
            a0 += __shfl_xor(a0, off);
            a1 += __shfl_xor(a1, off);
        }
        if (lane == 0) {
            float bb = bias[r];
            float o0 = a0 + bb, o1 = a1 + bb;
            if (act == 1) { o0 = fmaxf(o0, 0.f); o1 = fmaxf(o1, 0.f); }
            out0[r] = o0; out1[r] = o1;
        }
    }
}

__global__ __launch_bounds__(128) void final_mlp_kernel(
    const float* __restrict__ x, const float* __restrict__ flat,
    float* __restrict__ out)
{
    int t = blockIdx.x;
    int b = t & 1;
    int tid = threadIdx.x;
    const float* fl = flat + (long long)b * TOTALW;
    __shared__ float xs[FDIM], t1s[HDIM], t2s[HDIM];
    if (tid < FDIM) xs[tid] = nanfix(x[(long long)(NTOK + t) * FDIM + tid]);
    __syncthreads();
    {
        float acc = fl[tid];
        const float* w1 = fl + HDIM;
        #pragma unroll 4
        for (int f = 0; f < FDIM; f++) acc = fmaf(xs[f], w1[f * HDIM + tid], acc);
        t1s[tid] = fmaxf(acc, 0.f);
    }
    __syncthreads();
    {
        float acc = fl[12928 + tid];
        const float* w2 = fl + 13056;
        #pragma unroll 4
        for (int hh = 0; hh < HDIM; hh++) acc = fmaf(t1s[hh], w2[hh * HDIM + tid], acc);
        t2s[tid] = fmaxf(acc, 0.f);
    }
    __syncthreads();
    if (tid < NOUTD) {
        float acc = fl[29440 + tid];
        const float* w3 = fl + 29450;
        #pragma unroll 4
        for (int hh = 0; hh < HDIM; hh++) acc = fmaf(t2s[hh], w3[hh * NOUTD + tid], acc);
        out[(long long)t * NOUTD + tid] = acc;
    }
}

// ---------------------------------------------------------------------------
extern "C" void kernel_launch(void* const* d_in, const int* in_sizes, int n_in,
                              void* d_out, int out_size, void* d_ws, size_t ws_size,
                              hipStream_t stream) {
    const float* x      = (const float*)d_in[0];
    const float* y      = (const float*)d_in[1];
    const float* enc_w  = (const float*)d_in[2];
    const float* enc_b  = (const float*)d_in[3];
    const float* yenc_w = (const float*)d_in[4];
    const float* yenc_b = (const float*)d_in[5];
    const float* qkv_w  = (const float*)d_in[6];
    const float* qkv_b  = (const float*)d_in[7];
    const float* out_w  = (const float*)d_in[8];
    const float* out_b  = (const float*)d_in[9];
    const float* ln1_g  = (const float*)d_in[10];
    const float* ln1_b  = (const float*)d_in[11];
    const float* ln2_g  = (const float*)d_in[12];
    const float* ln2_b  = (const float*)d_in[13];
    const float* ff1_w  = (const float*)d_in[14];
    const float* ff1_b  = (const float*)d_in[15];
    const float* ff2_w  = (const float*)d_in[16];
    const float* ff2_b  = (const float*)d_in[17];
    const float* dec_w1 = (const float*)d_in[18];
    const float* dec_b1 = (const float*)d_in[19];
    const float* dec_w2 = (const float*)d_in[20];
    const float* dec_b2 = (const float*)d_in[21];

    float* ws     = (float*)d_ws;
    float* h      = ws;                                  // 1,048,576 f
    u16*   h_bf   = (u16*)(h + 1048576);                 // 1,048,576 u16
    u16*   qkv_bf = h_bf + 1048576;                      // 3,145,728 u16
    u16*   vt     = qkv_bf + 3145728;                    // 1,048,576 u16
    u16*   attn_bf= vt + 1048576;                        // 1,048,576 u16
    u16*   ffb_bf = attn_bf + 1048576;                   // 2,097,152 u16
    u16*   wq     = ffb_bf + 2097152;                    // 3,145,728 u16
    u16*   wo     = wq + 3145728;                        // 1,048,576 u16
    u16*   wf1    = wo + 1048576;                        // 2,097,152 u16
    u16*   wf2    = wf1 + 2097152;                       // 2,097,152 u16
    float* big    = (float*)(wf2 + 2097152);             // 1,048,576 f (partial 0)
    float* big2   = big + 1048576;                       // 1,048,576 f (partial 1)
    float* part   = big2 + 1048576;                      // 32,768
    float* pooled = part + 32768;                        // 1,024
    float* dbuf   = pooled + 1024;                       // 4,096
    float* flat   = dbuf + 4096;                         // 61,460

    cvt_all<<<4096, 256, 0, stream>>>(qkv_w, out_w, ff1_w, ff2_w, wq, wo, wf1, wf2);

    encoder_kernel<<<NTOK, EDIM, 0, stream>>>(x, y, enc_w, enc_b, yenc_w, yenc_b, h, h_bf);

    const long long PSTRIDE = (long long)NTOK * EDIM;   // partial-buffer z-stride

    for (int l = 0; l < NLAYER; l++) {
        // qkv = h @ qkv_w[l].T + qkv_b[l]  -> bf16 [2048 x 1536]
        gemm2<<<dim3(24, 32, 1), 256, 0, stream>>>(
            h_bf, EDIM, wq + (size_t)l * 786432, EDIM,
            qkv_bf, 1536, 1, EDIM, 0, 1.f, qkv_b + (size_t)l * 1536, 0);

        vtrans_kernel<<<dim3(16, 16), 256, 0, stream>>>(qkv_bf, vt);

        flash_attn<<<dim3(16, 16), 512, 0, stream>>>(qkv_bf, vt, attn_bf);

        // proj partials: split-K=2 -> big (z=0), big2 (z=1); bias folded into LN
        gemm2<<<dim3(8, 32, 2), 256, 0, stream>>>(
            attn_bf, EDIM, wo + (size_t)l * 262144, EDIM,
            big, EDIM, 0, 256, PSTRIDE, 1.f, nullptr, 0);

        add_ln3_kernel<<<NTOK, 256, 0, stream>>>(h, big, big2,
            out_b + (size_t)l * EDIM,
            ln1_g + (size_t)l * EDIM, ln1_b + (size_t)l * EDIM, h, h_bf);

        // ffb = gelu(h @ ff1_w[l].T + ff1_b[l]) -> bf16 [2048 x 1024]
        gemm2<<<dim3(16, 32, 1), 256, 0, stream>>>(
            h_bf, EDIM, wf1 + (size_t)l * 524288, EDIM,
            ffb_bf, NHID, 1, EDIM, 0, 1.f, ff1_b + (size_t)l * NHID, 2);

        // ff2 partials: split-K=2 (K=1024 -> chunks of 512)
        gemm2<<<dim3(8, 32, 2), 256, 0, stream>>>(
            ffb_bf, NHID, wf2 + (size_t)l * 524288, NHID,
            big, EDIM, 0, 512, PSTRIDE, 1.f, nullptr, 0);

        add_ln3_kernel<<<NTOK, 256, 0, stream>>>(h, big, big2,
            ff2_b + (size_t)l * EDIM,
            ln2_g + (size_t)l * EDIM, ln2_b + (size_t)l * EDIM, h, h_bf);
    }

    pool1_kernel<<<32, 1024, 0, stream>>>(h, part);
    pool2_kernel<<<1, 1024, 0, stream>>>(part, pooled);

    wavedot2_kernel<<<512, 256, 0, stream>>>(
        pooled, pooled + EDIM, dec_w1, dec_b1, dbuf, dbuf + DECD, DECD, EDIM, 1);

    wavedot2_kernel<<<7683, 256, 0, stream>>>(
        dbuf, dbuf + DECD, dec_w2, dec_b2, flat, flat + TOTALW, TOTALW, DECD, 0);

    final_mlp_kernel<<<2048, 128, 0, stream>>>(x, flat, (float*)d_out);
}

// Round 10
// 472.279 us; speedup vs baseline: 6.7229x; 1.1429x over previous
//
#include <hip/hip_runtime.h>

// MotherNet forward — R10: gemm2 with 3-buffer counted-vmcnt pipeline (T4),
// tiled encoder (16 tok/block), tiled final_mlp (8 tok/block).

#define BATCH  2
#define FDIM   100
#define EDIM   512
#define NHEADS 8
#define HD     64
#define NHID   1024
#define NLAYER 4
#define HDIM   128
#define NOUTD  10
#define DECD   2048
#define SEPP   1024
#define TOTALW 30730
#define NTOK   2048

typedef unsigned short u16;
typedef __attribute__((ext_vector_type(8))) short bf16x8;
typedef __attribute__((ext_vector_type(4))) float f32x4;

__device__ __forceinline__ float nanfix(float v) {
    if (isnan(v)) return 0.f;
    if (isinf(v)) return v > 0.f ? 3.4028234663852886e38f : -3.4028234663852886e38f;
    return v;
}
__device__ __forceinline__ u16 f2bf(float f) {   // RTNE, finite inputs
    unsigned u = __float_as_uint(f);
    u += 0x7fffu + ((u >> 16) & 1u);
    return (u16)(u >> 16);
}

#define GLOAD16(gsrc, ldst) \
    __builtin_amdgcn_global_load_lds( \
        (const __attribute__((address_space(1))) void*)(gsrc), \
        (__attribute__((address_space(3))) void*)(ldst), 16, 0, 0)

// ---------------------------------------------------------------------------
// 3-buffer counted-vmcnt bf16 GEMM: C = act(alpha * A @ B^T + bias)
// A[M,K], B[N,K] bf16; 64x64 tile, BK=64, 4 waves (each 32x32 = 2x2 frags).
// Pipeline: stage 2 tiles ahead; per step: vmcnt(4) -> s_barrier -> stage t+2
// -> compute t. Loads for t+1 stay in flight across the barrier (T4).
// blockIdx.z = K-chunk id for split-K (C offset z*zCstride, f32 partials).
// ---------------------------------------------------------------------------
__global__ __launch_bounds__(256) void gemm2(
    const u16* __restrict__ A, int lda,
    const u16* __restrict__ B, int ldb,
    void* __restrict__ Cv, int ldc, int cbf,
    int K, long long zCstride, float alpha,
    const float* __restrict__ bias, int act)
{
    __shared__ __align__(16) u16 lds[3][8192];

    int tid = threadIdx.x;
    int lane = tid & 63, w = tid >> 6;
    int wr = w >> 1, wc = w & 1;
    int mBase = blockIdx.y * 64, nBase = blockIdx.x * 64;
    int r16 = lane & 15, kg = lane >> 4;
    long long zk = (long long)blockIdx.z * K;
    long long offC = (long long)blockIdx.z * zCstride;

    int c0 = w * 64 + lane;
    int c1 = 256 + w * 64 + lane;
    int r0 = c0 >> 3, r1 = c1 >> 3;
    int e0 = ((((c0 & 7) * 16) ^ ((r0 & 7) << 4)) >> 1);
    int e1 = ((((c1 & 7) * 16) ^ ((r1 & 7) << 4)) >> 1);
    const u16* sA0 = A + (long long)(mBase + r0) * lda + e0 + zk;
    const u16* sA1 = A + (long long)(mBase + r1) * lda + e1 + zk;
    const u16* sB0 = B + (long long)(nBase + r0) * ldb + e0 + zk;
    const u16* sB1 = B + (long long)(nBase + r1) * ldb + e1 + zk;
    int dA0 = w * 512, dA1 = 2048 + w * 512;
    int dB0 = 4096 + w * 512, dB1 = 6144 + w * 512;

    int ra0 = wr * 32 + r16,      ra1 = wr * 32 + 16 + r16;
    int rb0 = wc * 32 + r16,      rb1 = wc * 32 + 16 + r16;
    int cb0 = kg * 16;
    int cb1 = 64 + kg * 16;
    int oa00 = (ra0 * 128 + (cb0 ^ ((ra0 & 7) << 4))) >> 1;
    int oa01 = (ra0 * 128 + (cb1 ^ ((ra0 & 7) << 4))) >> 1;
    int oa10 = (ra1 * 128 + (cb0 ^ ((ra1 & 7) << 4))) >> 1;
    int oa11 = (ra1 * 128 + (cb1 ^ ((ra1 & 7) << 4))) >> 1;
    int ob00 = 4096 + ((rb0 * 128 + (cb0 ^ ((rb0 & 7) << 4))) >> 1);
    int ob01 = 4096 + ((rb0 * 128 + (cb1 ^ ((rb0 & 7) << 4))) >> 1);
    int ob10 = 4096 + ((rb1 * 128 + (cb0 ^ ((rb1 & 7) << 4))) >> 1);
    int ob11 = 4096 + ((rb1 * 128 + (cb1 ^ ((rb1 & 7) << 4))) >> 1);

    f32x4 acc00 = {0.f, 0.f, 0.f, 0.f};
    f32x4 acc01 = acc00, acc10 = acc00, acc11 = acc00;

    int nt = K >> 6;   // >= 4 for all call sites

#define STAGE2(t, bi) { int ko_ = (t) << 6; \
    GLOAD16(sA0 + ko_, &lds[bi][dA0]); \
    GLOAD16(sA1 + ko_, &lds[bi][dA1]); \
    GLOAD16(sB0 + ko_, &lds[bi][dB0]); \
    GLOAD16(sB1 + ko_, &lds[bi][dB1]); }

    // prologue: 2 tiles in flight
    STAGE2(0, 0);
    STAGE2(1, 1);

    int cur = 0;   // buffer of tile t; stage target = (cur+2)%3
    for (int t = 0; t < nt; t++) {
        if (t == nt - 1) {
            asm volatile("s_waitcnt vmcnt(0)" ::: "memory");
        } else {
            asm volatile("s_waitcnt vmcnt(4)" ::: "memory");
        }
        __builtin_amdgcn_s_barrier();   // buf[cur] ready; all waves past compute(t-1)
        if (t + 2 < nt) {
            int tgt = cur - 1; if (tgt < 0) tgt += 3;   // (cur+2)%3
            STAGE2(t + 2, tgt);
        }
        const u16* L = &lds[cur][0];
        bf16x8 a0 = *(const bf16x8*)(L + oa00);
        bf16x8 a1 = *(const bf16x8*)(L + oa10);
        bf16x8 b0 = *(const bf16x8*)(L + ob00);
        bf16x8 b1 = *(const bf16x8*)(L + ob10);
        acc00 = __builtin_amdgcn_mfma_f32_16x16x32_bf16(a0, b0, acc00, 0, 0, 0);
        acc01 = __builtin_amdgcn_mfma_f32_16x16x32_bf16(a0, b1, acc01, 0, 0, 0);
        acc10 = __builtin_amdgcn_mfma_f32_16x16x32_bf16(a1, b0, acc10, 0, 0, 0);
        acc11 = __builtin_amdgcn_mfma_f32_16x16x32_bf16(a1, b1, acc11, 0, 0, 0);
        a0 = *(const bf16x8*)(L + oa01);
        a1 = *(const bf16x8*)(L + oa11);
        b0 = *(const bf16x8*)(L + ob01);
        b1 = *(const bf16x8*)(L + ob11);
        acc00 = __builtin_amdgcn_mfma_f32_16x16x32_bf16(a0, b0, acc00, 0, 0, 0);
        acc01 = __builtin_amdgcn_mfma_f32_16x16x32_bf16(a0, b1, acc01, 0, 0, 0);
        acc10 = __builtin_amdgcn_mfma_f32_16x16x32_bf16(a1, b0, acc10, 0, 0, 0);
        acc11 = __builtin_amdgcn_mfma_f32_16x16x32_bf16(a1, b1, acc11, 0, 0, 0);
        cur++; if (cur == 3) cur = 0;
    }
#undef STAGE2

    #pragma unroll
    for (int i = 0; i < 2; i++) {
        #pragma unroll
        for (int j = 0; j < 2; j++) {
            f32x4 v = (i == 0) ? (j == 0 ? acc00 : acc01) : (j == 0 ? acc10 : acc11);
            int col = nBase + wc * 32 + j * 16 + r16;
            float bv = bias ? bias[col] : 0.f;
            long long base = offC + (long long)(mBase + wr * 32 + i * 16 + kg * 4) * ldc + col;
            #pragma unroll
            for (int r = 0; r < 4; r++) {
                float c = v[r] * alpha + bv;
                if (act == 2) {  // jax.nn.gelu approximate=True
                    float u = 0.7978845608028654f * (c + 0.044715f * c * c * c);
                    c = 0.5f * c * (1.f + tanhf(u));
                }
                if (cbf) ((u16*)Cv)[base + (long long)r * ldc] = f2bf(c);
                else     ((float*)Cv)[base + (long long)r * ldc] = c;
            }
        }
    }
}

// ---------------------------------------------------------------------------
// Flash v2 (unchanged from R9): 8 waves, kv-split x2, LDS merge.
// ---------------------------------------------------------------------------
__global__ __launch_bounds__(512) void flash_attn(
    const u16* __restrict__ qkvb, const u16* __restrict__ vtm,
    u16* __restrict__ attnb)
{
    int qt = blockIdx.x;
    int bh = blockIdx.y;
    int cb = bh >> 3, hh = bh & 7;
    int tid = threadIdx.x;
    int w = tid >> 6, lane = tid & 63;
    int p = w & 3, hf = w >> 2;
    int r16 = lane & 15, kg = lane >> 4;

    __shared__ __align__(16) u16 plds[8][2048];
    u16* pl = &plds[w][0];

    int qrow = qt * 64 + p * 16 + r16;
    const u16* qp = qkvb + ((long long)qrow * 2 + cb) * 1536 + hh * 64 + kg * 8;
    bf16x8 qf0 = *(const bf16x8*)(qp);
    bf16x8 qf1 = *(const bf16x8*)(qp + 32);

    const u16* kbase = qkvb + (long long)cb * 1536 + 512 + hh * 64;
    const u16* vbase = vtm + ((long long)bh * 64) * 1024;

    f32x4 m = {-3e38f, -3e38f, -3e38f, -3e38f};
    f32x4 l = {0.f, 0.f, 0.f, 0.f};
    f32x4 o[4] = {};

    int rb0 = (((r16 * 64 + kg * 8) * 2) ^ ((r16 & 7) << 4)) >> 1;
    int rb1 = (((r16 * 64 + 32 + kg * 8) * 2) ^ ((r16 & 7) << 4)) >> 1;

    for (int kt = hf * 8; kt < hf * 8 + 8; kt++) {
        f32x4 s[4];
        #pragma unroll
        for (int nb = 0; nb < 4; nb++) {
            int key = kt * 64 + nb * 16 + r16;
            const u16* kp = kbase + (long long)key * 3072 + kg * 8;
            bf16x8 kf0 = *(const bf16x8*)(kp);
            bf16x8 kf1 = *(const bf16x8*)(kp + 32);
            f32x4 acc = {};
            acc = __builtin_amdgcn_mfma_f32_16x16x32_bf16(qf0, kf0, acc, 0, 0, 0);
            acc = __builtin_amdgcn_mfma_f32_16x16x32_bf16(qf1, kf1, acc, 0, 0, 0);
            s[nb] = acc;
        }
        #pragma unroll
        for (int nb = 0; nb < 4; nb++)
            #pragma unroll
            for (int r = 0; r < 4; r++) s[nb][r] *= 0.125f;

        f32x4 tm;
        #pragma unroll
        for (int r = 0; r < 4; r++)
            tm[r] = fmaxf(fmaxf(s[0][r], s[1][r]), fmaxf(s[2][r], s[3][r]));
        #pragma unroll
        for (int off = 1; off < 16; off <<= 1) {
            #pragma unroll
            for (int r = 0; r < 4; r++) tm[r] = fmaxf(tm[r], __shfl_xor(tm[r], off));
        }
        f32x4 mn, al;
        #pragma unroll
        for (int r = 0; r < 4; r++) {
            mn[r] = fmaxf(m[r], tm[r]);
            al[r] = __expf(m[r] - mn[r]);
            m[r] = mn[r];
        }
        f32x4 rs = {};
        #pragma unroll
        for (int nb = 0; nb < 4; nb++)
            #pragma unroll
            for (int r = 0; r < 4; r++) {
                float pv = __expf(s[nb][r] - mn[r]);
                s[nb][r] = pv;
                rs[r] += pv;
            }
        #pragma unroll
        for (int off = 1; off < 16; off <<= 1) {
            #pragma unroll
            for (int r = 0; r < 4; r++) rs[r] += __shfl_xor(rs[r], off);
        }
        #pragma unroll
        for (int r = 0; r < 4; r++) l[r] = l[r] * al[r] + rs[r];
        #pragma unroll
        for (int db = 0; db < 4; db++)
            #pragma unroll
            for (int r = 0; r < 4; r++) o[db][r] *= al[r];

        #pragma unroll
        for (int nb = 0; nb < 4; nb++)
            #pragma unroll
            for (int r = 0; r < 4; r++) {
                int row = kg * 4 + r;
                int col = nb * 16 + r16;
                int byi = (((row * 64 + col) * 2) ^ ((row & 7) << 4)) >> 1;
                pl[byi] = f2bf(s[nb][r]);
            }

        bf16x8 pa0 = *(const bf16x8*)(pl + rb0);
        bf16x8 pa1 = *(const bf16x8*)(pl + rb1);
        #pragma unroll
        for (int db = 0; db < 4; db++) {
            const u16* vp = vbase + (long long)(db * 16 + r16) * 1024 + kt * 64 + kg * 8;
            bf16x8 vf0 = *(const bf16x8*)(vp);
            bf16x8 vf1 = *(const bf16x8*)(vp + 32);
            o[db] = __builtin_amdgcn_mfma_f32_16x16x32_bf16(pa0, vf0, o[db], 0, 0, 0);
            o[db] = __builtin_amdgcn_mfma_f32_16x16x32_bf16(pa1, vf1, o[db], 0, 0, 0);
        }
    }

    __syncthreads();
    float* fb = (float*)&plds[0][0];
    if (hf == 0) {
        int base = (w * 64 + lane) * 25;
        #pragma unroll
        for (int r = 0; r < 4; r++) { fb[base + r] = m[r]; fb[base + 4 + r] = l[r]; }
        #pragma unroll
        for (int db = 0; db < 4; db++)
            #pragma unroll
            for (int r = 0; r < 4; r++) fb[base + 8 + db * 4 + r] = o[db][r];
    }
    __syncthreads();
    if (hf == 1) {
        int base = ((w - 4) * 64 + lane) * 25;
        f32x4 a1, a2, linv;
        #pragma unroll
        for (int r = 0; r < 4; r++) {
            float m1 = fb[base + r], l1 = fb[base + 4 + r];
            float mm = fmaxf(m1, m[r]);
            a1[r] = __expf(m1 - mm);
            a2[r] = __expf(m[r] - mm);
            linv[r] = 1.f / (l1 * a1[r] + l[r] * a2[r]);
        }
        #pragma unroll
        for (int db = 0; db < 4; db++)
            #pragma unroll
            for (int r = 0; r < 4; r++) {
                float val = (fb[base + 8 + db * 4 + r] * a1[r] + o[db][r] * a2[r]) * linv[r];
                int row = qt * 64 + (w - 4) * 16 + kg * 4 + r;
                attnb[((long long)row * 2 + cb) * 512 + hh * 64 + db * 16 + r16] = f2bf(val);
            }
    }
}

// merged f32->bf16 convert for the 4 transformer weight tensors
__global__ __launch_bounds__(256) void cvt_all(
    const float* __restrict__ s0, const float* __restrict__ s1,
    const float* __restrict__ s2, const float* __restrict__ s3,
    u16* __restrict__ d0, u16* __restrict__ d1,
    u16* __restrict__ d2, u16* __restrict__ d3)
{
    const int n0 = 3145728, n1 = 1048576, n2 = 2097152, n3 = 2097152;
    int i = blockIdx.x * 256 + threadIdx.x;
    int st = gridDim.x * 256;
    for (; i < n0 + n1 + n2 + n3; i += st) {
        if (i < n0) d0[i] = f2bf(s0[i]);
        else if (i < n0 + n1) d1[i - n0] = f2bf(s1[i - n0]);
        else if (i < n0 + n1 + n2) d2[i - n0 - n1] = f2bf(s2[i - n0 - n1]);
        else d3[i - n0 - n1 - n2] = f2bf(s3[i - n0 - n1 - n2]);
    }
}

// Encoder, 16 tokens per block: cuts enc_w L2 re-reads 16x.
__global__ __launch_bounds__(512) void encoder_kernel(
    const float* __restrict__ x, const float* __restrict__ y,
    const float* __restrict__ enc_w, const float* __restrict__ enc_b,
    const float* __restrict__ yenc_w, const float* __restrict__ yenc_b,
    float* __restrict__ h, u16* __restrict__ h_bf)
{
    int g = blockIdx.x;            // 128 blocks
    int tid = threadIdx.x;         // col e
    __shared__ float xs[16][FDIM];
    __shared__ float ys[16];
    for (int i = tid; i < 16 * FDIM; i += 512) {
        int tk = i / FDIM, f = i % FDIM;
        xs[tk][f] = nanfix(x[(long long)(g * 16 + tk) * FDIM + f]);
    }
    if (tid < 16) ys[tid] = y[g * 16 + tid];
    __syncthreads();
    float base = enc_b[tid] + yenc_b[tid];
    float yw = yenc_w[tid];
    const float* wr = enc_w + (long long)tid * FDIM;
    float acc[16];
    #pragma unroll
    for (int j = 0; j < 16; j++) acc[j] = 0.f;
    for (int f = 0; f < FDIM; f++) {
        float wv = wr[f];
        #pragma unroll
        for (int j = 0; j < 16; j++) acc[j] = fmaf(xs[j][f], wv, acc[j]);
    }
    #pragma unroll
    for (int j = 0; j < 16; j++) {
        float v = base + ys[j] * yw + acc[j];
        long long t = g * 16 + j;
        h[t * EDIM + tid] = v;
        h_bf[t * EDIM + tid] = f2bf(v);
    }
}

// out = LN(a + p0 + p1 + cbias)*g + be ; writes f32 + bf16. a may alias out.
__global__ __launch_bounds__(256) void add_ln3_kernel(
    const float* a, const float* __restrict__ p0, const float* __restrict__ p1,
    const float* __restrict__ cbias,
    const float* __restrict__ g, const float* __restrict__ be,
    float* out, u16* __restrict__ out_bf)
{
    int row = blockIdx.x;
    int tid = threadIdx.x;
    const float* pa = a + (long long)row * EDIM;
    const float* pr0 = p0 + (long long)row * EDIM;
    const float* pr1 = p1 + (long long)row * EDIM;
    float v0 = pa[tid] + pr0[tid] + pr1[tid] + cbias[tid];
    float v1 = pa[tid + 256] + pr0[tid + 256] + pr1[tid + 256] + cbias[tid + 256];
    float s = v0 + v1, q = v0 * v0 + v1 * v1;
    #pragma unroll
    for (int off = 32; off; off >>= 1) {
        s += __shfl_xor(s, off);
        q += __shfl_xor(q, off);
    }
    __shared__ float ss[4], sq[4];
    int w = tid >> 6, lane = tid & 63;
    if (lane == 0) { ss[w] = s; sq[w] = q; }
    __syncthreads();
    s = ss[0] + ss[1] + ss[2] + ss[3];
    q = sq[0] + sq[1] + sq[2] + sq[3];
    float mean = s * (1.f / EDIM);
    float var = q * (1.f / EDIM) - mean * mean;
    float rstd = rsqrtf(var + 1e-5f);
    float o0 = (v0 - mean) * rstd * g[tid] + be[tid];
    float o1 = (v1 - mean) * rstd * g[tid + 256] + be[tid + 256];
    float* po = out + (long long)row * EDIM;
    u16* pb = out_bf + (long long)row * EDIM;
    po[tid] = o0;        po[tid + 256] = o1;
    pb[tid] = f2bf(o0);  pb[tid + 256] = f2bf(o1);
}

// V transpose
__global__ __launch_bounds__(256) void vtrans_kernel(
    const u16* __restrict__ qkvb, u16* __restrict__ vt)
{
    __shared__ u16 tile[64][66];
    int bx = blockIdx.x;
    int by = blockIdx.y;
    int cb = by >> 3, hh = by & 7;
    int tid = threadIdx.x;
    int c = tid & 63, w4 = tid >> 6;
    #pragma unroll 4
    for (int i = 0; i < 16; i++) {
        int sl = w4 * 16 + i;
        tile[sl][c] = qkvb[((long long)((bx * 64 + sl) * 2 + cb)) * 1536 + 1024 + hh * 64 + c];
    }
    __syncthreads();
    #pragma unroll 4
    for (int i = 0; i < 16; i++) {
        int dl = w4 * 16 + i;
        vt[((long long)(by * 64 + dl)) * 1024 + bx * 64 + c] = tile[c][dl];
    }
}

// two-stage coalesced mean-pool
__global__ __launch_bounds__(1024) void pool1_kernel(
    const float* __restrict__ h, float* __restrict__ part)
{
    int j = blockIdx.x;
    int idx = threadIdx.x;
    float s = 0.f;
    #pragma unroll 8
    for (int k = 0; k < 32; k++)
        s += h[(long long)(j * 32 + k) * 1024 + idx];
    part[j * 1024 + idx] = s;
}
__global__ __launch_bounds__(1024) void pool2_kernel(
    const float* __restrict__ part, float* __restrict__ pooled)
{
    int idx = threadIdx.x;
    float s = 0.f;
    #pragma unroll 8
    for (int j = 0; j < 32; j++) s += part[j * 1024 + idx];
    pooled[idx] = s * (1.f / 1024.f);
}

__global__ __launch_bounds__(256) void wavedot2_kernel(
    const float* __restrict__ v0, const float* __restrict__ v1,
    const float* __restrict__ W, const float* __restrict__ bias,
    float* __restrict__ out0, float* __restrict__ out1,
    int R, int K, int act)
{
    int gw = (blockIdx.x * 256 + threadIdx.x) >> 6;
    int lane = threadIdx.x & 63;
    int nw = (gridDim.x * 256) >> 6;
    const float4* x0 = (const float4*)v0;
    const float4* x1 = (const float4*)v1;
    for (int r = gw; r < R; r += nw) {
        const float4* w4 = (const float4*)(W + (long long)r * K);
        float a0 = 0.f, a1 = 0.f;
        for (int i = lane; i < (K >> 2); i += 64) {
            float4 w = w4[i];
            float4 p = x0[i];
            float4 q = x1[i];
            a0 += w.x * p.x + w.y * p.y + w.z * p.z + w.w * p.w;
            a1 += w.x * q.x + w.y * q.y + w.z * q.z + w.w * q.w;
        }
        #pragma unroll
        for (int off = 32; off; off >>= 1) {
            a0 += __shfl_xor(a0, off);
            a1 += __shfl_xor(a1, off);
        }
        if (lane == 0) {
            float bb = bias[r];
            float o0 = a0 + bb, o1 = a1 + bb;
            if (act == 1) { o0 = fmaxf(o0, 0.f); o1 = fmaxf(o1, 0.f); }
            out0[r] = o0; out1[r] = o1;
        }
    }
}

// Final per-sample MLP, 8 same-parity tokens per block (weight re-reads /8).
__global__ __launch_bounds__(128) void final_mlp_kernel(
    const float* __restrict__ x, const float* __restrict__ flat,
    float* __restrict__ out)
{
    int g = blockIdx.x;            // 256 blocks
    int b = g >> 7;
    int j0 = (g & 127) * 8;
    int tid = threadIdx.x;
    const float* fl = flat + (long long)b * TOTALW;
    __shared__ float xs[8][FDIM], t1s[8][HDIM], t2s[8][HDIM];
    for (int i = tid; i < 8 * FDIM; i += 128) {
        int j = i / FDIM, f = i % FDIM;
        int t = (j0 + j) * 2 + b;
        xs[j][f] = nanfix(x[(long long)(NTOK + t) * FDIM + f]);
    }
    __syncthreads();
    {
        float acc[8];
        float b1 = fl[tid];
        #pragma unroll
        for (int j = 0; j < 8; j++) acc[j] = b1;
        const float* w1 = fl + HDIM;
        for (int f = 0; f < FDIM; f++) {
            float wv = w1[f * HDIM + tid];
            #pragma unroll
            for (int j = 0; j < 8; j++) acc[j] = fmaf(xs[j][f], wv, acc[j]);
        }
        #pragma unroll
        for (int j = 0; j < 8; j++) t1s[j][tid] = fmaxf(acc[j], 0.f);
    }
    __syncthreads();
    {
        float acc[8];
        float b2 = fl[12928 + tid];
        #pragma unroll
        for (int j = 0; j < 8; j++) acc[j] = b2;
        const float* w2 = fl + 13056;
        for (int hh = 0; hh < HDIM; hh++) {
            float wv = w2[hh * HDIM + tid];
            #pragma unroll
            for (int j = 0; j < 8; j++) acc[j] = fmaf(t1s[j][hh], wv, acc[j]);
        }
        #pragma unroll
        for (int j = 0; j < 8; j++) t2s[j][tid] = fmaxf(acc[j], 0.f);
    }
    __syncthreads();
    if (tid < NOUTD) {
        float acc[8];
        float b3 = fl[29440 + tid];
        #pragma unroll
        for (int j = 0; j < 8; j++) acc[j] = b3;
        const float* w3 = fl + 29450;
        for (int hh = 0; hh < HDIM; hh++) {
            float wv = w3[hh * NOUTD + tid];
            #pragma unroll
            for (int j = 0; j < 8; j++) acc[j] = fmaf(t2s[j][hh], wv, acc[j]);
        }
        #pragma unroll
        for (int j = 0; j < 8; j++) {
            int t = (j0 + j) * 2 + b;
            out[(long long)t * NOUTD + tid] = acc[j];
        }
    }
}

// ---------------------------------------------------------------------------
extern "C" void kernel_launch(void* const* d_in, const int* in_sizes, int n_in,
                              void* d_out, int out_size, void* d_ws, size_t ws_size,
                              hipStream_t stream) {
    const float* x      = (const float*)d_in[0];
    const float* y      = (const float*)d_in[1];
    const float* enc_w  = (const float*)d_in[2];
    const float* enc_b  = (const float*)d_in[3];
    const float* yenc_w = (const float*)d_in[4];
    const float* yenc_b = (const float*)d_in[5];
    const float* qkv_w  = (const float*)d_in[6];
    const float* qkv_b  = (const float*)d_in[7];
    const float* out_w  = (const float*)d_in[8];
    const float* out_b  = (const float*)d_in[9];
    const float* ln1_g  = (const float*)d_in[10];
    const float* ln1_b  = (const float*)d_in[11];
    const float* ln2_g  = (const float*)d_in[12];
    const float* ln2_b  = (const float*)d_in[13];
    const float* ff1_w  = (const float*)d_in[14];
    const float* ff1_b  = (const float*)d_in[15];
    const float* ff2_w  = (const float*)d_in[16];
    const float* ff2_b  = (const float*)d_in[17];
    const float* dec_w1 = (const float*)d_in[18];
    const float* dec_b1 = (const float*)d_in[19];
    const float* dec_w2 = (const float*)d_in[20];
    const float* dec_b2 = (const float*)d_in[21];

    float* ws     = (float*)d_ws;
    float* h      = ws;                                  // 1,048,576 f
    u16*   h_bf   = (u16*)(h + 1048576);                 // 1,048,576 u16
    u16*   qkv_bf = h_bf + 1048576;                      // 3,145,728 u16
    u16*   vt     = qkv_bf + 3145728;                    // 1,048,576 u16
    u16*   attn_bf= vt + 1048576;                        // 1,048,576 u16
    u16*   ffb_bf = attn_bf + 1048576;                   // 2,097,152 u16
    u16*   wq     = ffb_bf + 2097152;                    // 3,145,728 u16
    u16*   wo     = wq + 3145728;                        // 1,048,576 u16
    u16*   wf1    = wo + 1048576;                        // 2,097,152 u16
    u16*   wf2    = wf1 + 2097152;                       // 2,097,152 u16
    float* big    = (float*)(wf2 + 2097152);             // 1,048,576 f (partial 0)
    float* big2   = big + 1048576;                       // 1,048,576 f (partial 1)
    float* part   = big2 + 1048576;                      // 32,768
    float* pooled = part + 32768;                        // 1,024
    float* dbuf   = pooled + 1024;                       // 4,096
    float* flat   = dbuf + 4096;                         // 61,460

    cvt_all<<<4096, 256, 0, stream>>>(qkv_w, out_w, ff1_w, ff2_w, wq, wo, wf1, wf2);

    encoder_kernel<<<128, 512, 0, stream>>>(x, y, enc_w, enc_b, yenc_w, yenc_b, h, h_bf);

    const long long PSTRIDE = (long long)NTOK * EDIM;

    for (int l = 0; l < NLAYER; l++) {
        // qkv = h @ qkv_w[l].T + qkv_b[l]  -> bf16 [2048 x 1536]
        gemm2<<<dim3(24, 32, 1), 256, 0, stream>>>(
            h_bf, EDIM, wq + (size_t)l * 786432, EDIM,
            qkv_bf, 1536, 1, EDIM, 0, 1.f, qkv_b + (size_t)l * 1536, 0);

        vtrans_kernel<<<dim3(16, 16), 256, 0, stream>>>(qkv_bf, vt);

        flash_attn<<<dim3(16, 16), 512, 0, stream>>>(qkv_bf, vt, attn_bf);

        // proj partials: split-K=2; bias folded into LN
        gemm2<<<dim3(8, 32, 2), 256, 0, stream>>>(
            attn_bf, EDIM, wo + (size_t)l * 262144, EDIM,
            big, EDIM, 0, 256, PSTRIDE, 1.f, nullptr, 0);

        add_ln3_kernel<<<NTOK, 256, 0, stream>>>(h, big, big2,
            out_b + (size_t)l * EDIM,
            ln1_g + (size_t)l * EDIM, ln1_b + (size_t)l * EDIM, h, h_bf);

        // ffb = gelu(h @ ff1_w[l].T + ff1_b[l]) -> bf16 [2048 x 1024]
        gemm2<<<dim3(16, 32, 1), 256, 0, stream>>>(
            h_bf, EDIM, wf1 + (size_t)l * 524288, EDIM,
            ffb_bf, NHID, 1, EDIM, 0, 1.f, ff1_b + (size_t)l * NHID, 2);

        // ff2 partials: split-K=2 (chunks of 512)
        gemm2<<<dim3(8, 32, 2), 256, 0, stream>>>(
            ffb_bf, NHID, wf2 + (size_t)l * 524288, NHID,
            big, EDIM, 0, 512, PSTRIDE, 1.f, nullptr, 0);

        add_ln3_kernel<<<NTOK, 256, 0, stream>>>(h, big, big2,
            ff2_b + (size_t)l * EDIM,
            ln2_g + (size_t)l * EDIM, ln2_b + (size_t)l * EDIM, h, h_bf);
    }

    pool1_kernel<<<32, 1024, 0, stream>>>(h, part);
    pool2_kernel<<<1, 1024, 0, stream>>>(part, pooled);

    wavedot2_kernel<<<512, 256, 0, stream>>>(
        pooled, pooled + EDIM, dec_w1, dec_b1, dbuf, dbuf + DECD, DECD, EDIM, 1);

    wavedot2_kernel<<<7683, 256, 0, stream>>>(
        dbuf, dbuf + DECD, dec_w2, dec_b2, flat, flat + TOTALW, TOTALW, DECD, 0);

    final_mlp_kernel<<<256, 128, 0, stream>>>(x, flat, (float*)d_out);
}

// Round 11
// 432.184 us; speedup vs baseline: 7.3467x; 1.0928x over previous
//
#include <hip/hip_runtime.h>

// MotherNet forward — R11: defer-max flash (m==0, analytic bound), V-transpose
// fused into qkv GEMM epilogue (vtrans kernel removed).

#define BATCH  2
#define FDIM   100
#define EDIM   512
#define NHEADS 8
#define HD     64
#define NHID   1024
#define NLAYER 4
#define HDIM   128
#define NOUTD  10
#define DECD   2048
#define SEPP   1024
#define TOTALW 30730
#define NTOK   2048

typedef unsigned short u16;
typedef __attribute__((ext_vector_type(8))) short bf16x8;
typedef __attribute__((ext_vector_type(4))) float f32x4;

__device__ __forceinline__ float nanfix(float v) {
    if (isnan(v)) return 0.f;
    if (isinf(v)) return v > 0.f ? 3.4028234663852886e38f : -3.4028234663852886e38f;
    return v;
}
__device__ __forceinline__ u16 f2bf(float f) {   // RTNE, finite inputs
    unsigned u = __float_as_uint(f);
    u += 0x7fffu + ((u >> 16) & 1u);
    return (u16)(u >> 16);
}
__device__ __forceinline__ float bf2f(u16 h) {
    return __uint_as_float(((unsigned)h) << 16);
}
// exact power-of-2 scale of a bf16x8 (unpack-mul-repack; mantissa preserved)
__device__ __forceinline__ bf16x8 scale8(bf16x8 a, float s) {
    bf16x8 r;
    #pragma unroll
    for (int i = 0; i < 8; i++) {
        float v = bf2f((u16)a[i]) * s;
        r[i] = (short)f2bf(v);
    }
    return r;
}

#define GLOAD16(gsrc, ldst) \
    __builtin_amdgcn_global_load_lds( \
        (const __attribute__((address_space(1))) void*)(gsrc), \
        (__attribute__((address_space(3))) void*)(ldst), 16, 0, 0)

// ---------------------------------------------------------------------------
// 3-buffer counted-vmcnt bf16 GEMM (R10 pipeline): C = act(alpha*A@B^T + bias)
// If vtout != nullptr and this block's cols are in the V range (>=1024), the
// tile is written TRANSPOSED to vt[((cb*8+hh)*64+d)*1024 + s] instead of C.
// ---------------------------------------------------------------------------
__global__ __launch_bounds__(256) void gemm2(
    const u16* __restrict__ A, int lda,
    const u16* __restrict__ B, int ldb,
    void* __restrict__ Cv, int ldc, int cbf,
    int K, long long zCstride, float alpha,
    const float* __restrict__ bias, int act,
    u16* __restrict__ vtout)
{
    __shared__ __align__(16) u16 lds[3][8192];

    int tid = threadIdx.x;
    int lane = tid & 63, w = tid >> 6;
    int wr = w >> 1, wc = w & 1;
    int mBase = blockIdx.y * 64, nBase = blockIdx.x * 64;
    int r16 = lane & 15, kg = lane >> 4;
    long long zk = (long long)blockIdx.z * K;
    long long offC = (long long)blockIdx.z * zCstride;

    int c0 = w * 64 + lane;
    int c1 = 256 + w * 64 + lane;
    int r0 = c0 >> 3, r1 = c1 >> 3;
    int e0 = ((((c0 & 7) * 16) ^ ((r0 & 7) << 4)) >> 1);
    int e1 = ((((c1 & 7) * 16) ^ ((r1 & 7) << 4)) >> 1);
    const u16* sA0 = A + (long long)(mBase + r0) * lda + e0 + zk;
    const u16* sA1 = A + (long long)(mBase + r1) * lda + e1 + zk;
    const u16* sB0 = B + (long long)(nBase + r0) * ldb + e0 + zk;
    const u16* sB1 = B + (long long)(nBase + r1) * ldb + e1 + zk;
    int dA0 = w * 512, dA1 = 2048 + w * 512;
    int dB0 = 4096 + w * 512, dB1 = 6144 + w * 512;

    int ra0 = wr * 32 + r16,      ra1 = wr * 32 + 16 + r16;
    int rb0 = wc * 32 + r16,      rb1 = wc * 32 + 16 + r16;
    int cb0 = kg * 16;
    int cb1 = 64 + kg * 16;
    int oa00 = (ra0 * 128 + (cb0 ^ ((ra0 & 7) << 4))) >> 1;
    int oa01 = (ra0 * 128 + (cb1 ^ ((ra0 & 7) << 4))) >> 1;
    int oa10 = (ra1 * 128 + (cb0 ^ ((ra1 & 7) << 4))) >> 1;
    int oa11 = (ra1 * 128 + (cb1 ^ ((ra1 & 7) << 4))) >> 1;
    int ob00 = 4096 + ((rb0 * 128 + (cb0 ^ ((rb0 & 7) << 4))) >> 1);
    int ob01 = 4096 + ((rb0 * 128 + (cb1 ^ ((rb0 & 7) << 4))) >> 1);
    int ob10 = 4096 + ((rb1 * 128 + (cb0 ^ ((rb1 & 7) << 4))) >> 1);
    int ob11 = 4096 + ((rb1 * 128 + (cb1 ^ ((rb1 & 7) << 4))) >> 1);

    f32x4 acc00 = {0.f, 0.f, 0.f, 0.f};
    f32x4 acc01 = acc00, acc10 = acc00, acc11 = acc00;

    int nt = K >> 6;   // >= 4 for all call sites

#define STAGE2(t, bi) { int ko_ = (t) << 6; \
    GLOAD16(sA0 + ko_, &lds[bi][dA0]); \
    GLOAD16(sA1 + ko_, &lds[bi][dA1]); \
    GLOAD16(sB0 + ko_, &lds[bi][dB0]); \
    GLOAD16(sB1 + ko_, &lds[bi][dB1]); }

    STAGE2(0, 0);
    STAGE2(1, 1);

    int cur = 0;
    for (int t = 0; t < nt; t++) {
        if (t == nt - 1) {
            asm volatile("s_waitcnt vmcnt(0)" ::: "memory");
        } else {
            asm volatile("s_waitcnt vmcnt(4)" ::: "memory");
        }
        __builtin_amdgcn_s_barrier();
        if (t + 2 < nt) {
            int tgt = cur - 1; if (tgt < 0) tgt += 3;
            STAGE2(t + 2, tgt);
        }
        const u16* L = &lds[cur][0];
        bf16x8 a0 = *(const bf16x8*)(L + oa00);
        bf16x8 a1 = *(const bf16x8*)(L + oa10);
        bf16x8 b0 = *(const bf16x8*)(L + ob00);
        bf16x8 b1 = *(const bf16x8*)(L + ob10);
        acc00 = __builtin_amdgcn_mfma_f32_16x16x32_bf16(a0, b0, acc00, 0, 0, 0);
        acc01 = __builtin_amdgcn_mfma_f32_16x16x32_bf16(a0, b1, acc01, 0, 0, 0);
        acc10 = __builtin_amdgcn_mfma_f32_16x16x32_bf16(a1, b0, acc10, 0, 0, 0);
        acc11 = __builtin_amdgcn_mfma_f32_16x16x32_bf16(a1, b1, acc11, 0, 0, 0);
        a0 = *(const bf16x8*)(L + oa01);
        a1 = *(const bf16x8*)(L + oa11);
        b0 = *(const bf16x8*)(L + ob01);
        b1 = *(const bf16x8*)(L + ob11);
        acc00 = __builtin_amdgcn_mfma_f32_16x16x32_bf16(a0, b0, acc00, 0, 0, 0);
        acc01 = __builtin_amdgcn_mfma_f32_16x16x32_bf16(a0, b1, acc01, 0, 0, 0);
        acc10 = __builtin_amdgcn_mfma_f32_16x16x32_bf16(a1, b0, acc10, 0, 0, 0);
        acc11 = __builtin_amdgcn_mfma_f32_16x16x32_bf16(a1, b1, acc11, 0, 0, 0);
        cur++; if (cur == 3) cur = 0;
    }
#undef STAGE2

    if (vtout && nBase >= 1024) {
        // ---- V block: transpose via LDS into vt, skip C store ----
        u16* T = &lds[0][0];                 // [m_local][d_local] 64x64 u16
        __syncthreads();                     // all waves done reading K-loop LDS
        #pragma unroll
        for (int i = 0; i < 2; i++) {
            #pragma unroll
            for (int j = 0; j < 2; j++) {
                f32x4 v = (i == 0) ? (j == 0 ? acc00 : acc01) : (j == 0 ? acc10 : acc11);
                int dl = wc * 32 + j * 16 + r16;
                float bv = bias ? bias[nBase + dl] : 0.f;
                #pragma unroll
                for (int r = 0; r < 4; r++) {
                    int ml = wr * 32 + i * 16 + kg * 4 + r;
                    T[ml * 64 + dl] = f2bf(v[r] * alpha + bv);
                }
            }
        }
        __syncthreads();
        int d = tid & 63, cbv = (tid >> 6) & 1, half = tid >> 7;
        int hh = (nBase - 1024) >> 6;
        long long orow = ((long long)(cbv * 8 + hh) * 64 + d) * 1024 + (mBase >> 1) + half * 16;
        bf16x8 v0, v1;
        #pragma unroll
        for (int k = 0; k < 8; k++) {
            v0[k] = (short)T[((half * 16 + k) * 2 + cbv) * 64 + d];
            v1[k] = (short)T[((half * 16 + 8 + k) * 2 + cbv) * 64 + d];
        }
        *(bf16x8*)(vtout + orow) = v0;
        *(bf16x8*)(vtout + orow + 8) = v1;
        return;
    }

    #pragma unroll
    for (int i = 0; i < 2; i++) {
        #pragma unroll
        for (int j = 0; j < 2; j++) {
            f32x4 v = (i == 0) ? (j == 0 ? acc00 : acc01) : (j == 0 ? acc10 : acc11);
            int col = nBase + wc * 32 + j * 16 + r16;
            float bv = bias ? bias[col] : 0.f;
            long long base = offC + (long long)(mBase + wr * 32 + i * 16 + kg * 4) * ldc + col;
            #pragma unroll
            for (int r = 0; r < 4; r++) {
                float c = v[r] * alpha + bv;
                if (act == 2) {  // jax.nn.gelu approximate=True
                    float u = 0.7978845608028654f * (c + 0.044715f * c * c * c);
                    c = 0.5f * c * (1.f + tanhf(u));
                }
                if (cbf) ((u16*)Cv)[base + (long long)r * ldc] = f2bf(c);
                else     ((float*)Cv)[base + (long long)r * ldc] = c;
            }
        }
    }
}

// ---------------------------------------------------------------------------
// Flash v3: defer-max (m == 0; scores bounded |s| <~ 2 analytically).
// 8 waves: q-strip p=w&3, kv-half hf=w>>2. Q pre-scaled by 1/8 (exact).
// Merge = plain sums (no rescale).
// ---------------------------------------------------------------------------
__global__ __launch_bounds__(512) void flash_attn(
    const u16* __restrict__ qkvb, const u16* __restrict__ vtm,
    u16* __restrict__ attnb)
{
    int qt = blockIdx.x;
    int bh = blockIdx.y;
    int cb = bh >> 3, hh = bh & 7;
    int tid = threadIdx.x;
    int w = tid >> 6, lane = tid & 63;
    int p = w & 3, hf = w >> 2;
    int r16 = lane & 15, kg = lane >> 4;

    __shared__ __align__(16) u16 plds[8][2048];
    u16* pl = &plds[w][0];

    int qrow = qt * 64 + p * 16 + r16;
    const u16* qp = qkvb + ((long long)qrow * 2 + cb) * 1536 + hh * 64 + kg * 8;
    bf16x8 qf0 = scale8(*(const bf16x8*)(qp), 0.125f);
    bf16x8 qf1 = scale8(*(const bf16x8*)(qp + 32), 0.125f);

    const u16* kbase = qkvb + (long long)cb * 1536 + 512 + hh * 64;
    const u16* vbase = vtm + ((long long)bh * 64) * 1024;

    f32x4 l = {0.f, 0.f, 0.f, 0.f};
    f32x4 o[4] = {};

    int rb0 = (((r16 * 64 + kg * 8) * 2) ^ ((r16 & 7) << 4)) >> 1;
    int rb1 = (((r16 * 64 + 32 + kg * 8) * 2) ^ ((r16 & 7) << 4)) >> 1;

    for (int kt = hf * 8; kt < hf * 8 + 8; kt++) {
        f32x4 s[4];
        #pragma unroll
        for (int nb = 0; nb < 4; nb++) {
            int key = kt * 64 + nb * 16 + r16;
            const u16* kp = kbase + (long long)key * 3072 + kg * 8;
            bf16x8 kf0 = *(const bf16x8*)(kp);
            bf16x8 kf1 = *(const bf16x8*)(kp + 32);
            f32x4 acc = {};
            acc = __builtin_amdgcn_mfma_f32_16x16x32_bf16(qf0, kf0, acc, 0, 0, 0);
            acc = __builtin_amdgcn_mfma_f32_16x16x32_bf16(qf1, kf1, acc, 0, 0, 0);
            s[nb] = acc;
        }
        // P = exp(S) (no max subtraction), accumulate row-sums
        f32x4 rs = {};
        #pragma unroll
        for (int nb = 0; nb < 4; nb++)
            #pragma unroll
            for (int r = 0; r < 4; r++) {
                float pv = __expf(s[nb][r]);
                s[nb][r] = pv;
                rs[r] += pv;
            }
        #pragma unroll
        for (int off = 1; off < 16; off <<= 1) {
            #pragma unroll
            for (int r = 0; r < 4; r++) rs[r] += __shfl_xor(rs[r], off);
        }
        #pragma unroll
        for (int r = 0; r < 4; r++) l[r] += rs[r];

        // P -> per-wave LDS (swizzled, wave-private)
        #pragma unroll
        for (int nb = 0; nb < 4; nb++)
            #pragma unroll
            for (int r = 0; r < 4; r++) {
                int row = kg * 4 + r;
                int col = nb * 16 + r16;
                int byi = (((row * 64 + col) * 2) ^ ((row & 7) << 4)) >> 1;
                pl[byi] = f2bf(s[nb][r]);
            }

        bf16x8 pa0 = *(const bf16x8*)(pl + rb0);
        bf16x8 pa1 = *(const bf16x8*)(pl + rb1);
        #pragma unroll
        for (int db = 0; db < 4; db++) {
            const u16* vp = vbase + (long long)(db * 16 + r16) * 1024 + kt * 64 + kg * 8;
            bf16x8 vf0 = *(const bf16x8*)(vp);
            bf16x8 vf1 = *(const bf16x8*)(vp + 32);
            o[db] = __builtin_amdgcn_mfma_f32_16x16x32_bf16(pa0, vf0, o[db], 0, 0, 0);
            o[db] = __builtin_amdgcn_mfma_f32_16x16x32_bf16(pa1, vf1, o[db], 0, 0, 0);
        }
    }

    // ---- merge: plain sums (both halves used m == 0) ----
    __syncthreads();
    float* fb = (float*)&plds[0][0];
    if (hf == 0) {
        int base = (w * 64 + lane) * 20;
        #pragma unroll
        for (int r = 0; r < 4; r++) fb[base + r] = l[r];
        #pragma unroll
        for (int db = 0; db < 4; db++)
            #pragma unroll
            for (int r = 0; r < 4; r++) fb[base + 4 + db * 4 + r] = o[db][r];
    }
    __syncthreads();
    if (hf == 1) {
        int base = ((w - 4) * 64 + lane) * 20;
        f32x4 linv;
        #pragma unroll
        for (int r = 0; r < 4; r++) linv[r] = 1.f / (fb[base + r] + l[r]);
        #pragma unroll
        for (int db = 0; db < 4; db++)
            #pragma unroll
            for (int r = 0; r < 4; r++) {
                float val = (fb[base + 4 + db * 4 + r] + o[db][r]) * linv[r];
                int row = qt * 64 + (w - 4) * 16 + kg * 4 + r;
                attnb[((long long)row * 2 + cb) * 512 + hh * 64 + db * 16 + r16] = f2bf(val);
            }
    }
}

// merged f32->bf16 convert for the 4 transformer weight tensors
__global__ __launch_bounds__(256) void cvt_all(
    const float* __restrict__ s0, const float* __restrict__ s1,
    const float* __restrict__ s2, const float* __restrict__ s3,
    u16* __restrict__ d0, u16* __restrict__ d1,
    u16* __restrict__ d2, u16* __restrict__ d3)
{
    const int n0 = 3145728, n1 = 1048576, n2 = 2097152, n3 = 2097152;
    int i = blockIdx.x * 256 + threadIdx.x;
    int st = gridDim.x * 256;
    for (; i < n0 + n1 + n2 + n3; i += st) {
        if (i < n0) d0[i] = f2bf(s0[i]);
        else if (i < n0 + n1) d1[i - n0] = f2bf(s1[i - n0]);
        else if (i < n0 + n1 + n2) d2[i - n0 - n1] = f2bf(s2[i - n0 - n1]);
        else d3[i - n0 - n1 - n2] = f2bf(s3[i - n0 - n1 - n2]);
    }
}

// Encoder, 16 tokens per block
__global__ __launch_bounds__(512) void encoder_kernel(
    const float* __restrict__ x, const float* __restrict__ y,
    const float* __restrict__ enc_w, const float* __restrict__ enc_b,
    const float* __restrict__ yenc_w, const float* __restrict__ yenc_b,
    float* __restrict__ h, u16* __restrict__ h_bf)
{
    int g = blockIdx.x;
    int tid = threadIdx.x;
    __shared__ float xs[16][FDIM];
    __shared__ float ys[16];
    for (int i = tid; i < 16 * FDIM; i += 512) {
        int tk = i / FDIM, f = i % FDIM;
        xs[tk][f] = nanfix(x[(long long)(g * 16 + tk) * FDIM + f]);
    }
    if (tid < 16) ys[tid] = y[g * 16 + tid];
    __syncthreads();
    float base = enc_b[tid] + yenc_b[tid];
    float yw = yenc_w[tid];
    const float* wr = enc_w + (long long)tid * FDIM;
    float acc[16];
    #pragma unroll
    for (int j = 0; j < 16; j++) acc[j] = 0.f;
    for (int f = 0; f < FDIM; f++) {
        float wv = wr[f];
        #pragma unroll
        for (int j = 0; j < 16; j++) acc[j] = fmaf(xs[j][f], wv, acc[j]);
    }
    #pragma unroll
    for (int j = 0; j < 16; j++) {
        float v = base + ys[j] * yw + acc[j];
        long long t = g * 16 + j;
        h[t * EDIM + tid] = v;
        h_bf[t * EDIM + tid] = f2bf(v);
    }
}

// out = LN(a + p0 + p1 + cbias)*g + be ; writes f32 + bf16. a may alias out.
__global__ __launch_bounds__(256) void add_ln3_kernel(
    const float* a, const float* __restrict__ p0, const float* __restrict__ p1,
    const float* __restrict__ cbias,
    const float* __restrict__ g, const float* __restrict__ be,
    float* out, u16* __restrict__ out_bf)
{
    int row = blockIdx.x;
    int tid = threadIdx.x;
    const float* pa = a + (long long)row * EDIM;
    const float* pr0 = p0 + (long long)row * EDIM;
    const float* pr1 = p1 + (long long)row * EDIM;
    float v0 = pa[tid] + pr0[tid] + pr1[tid] + cbias[tid];
    float v1 = pa[tid + 256] + pr0[tid + 256] + pr1[tid + 256] + cbias[tid + 256];
    float s = v0 + v1, q = v0 * v0 + v1 * v1;
    #pragma unroll
    for (int off = 32; off; off >>= 1) {
        s += __shfl_xor(s, off);
        q += __shfl_xor(q, off);
    }
    __shared__ float ss[4], sq[4];
    int w = tid >> 6, lane = tid & 63;
    if (lane == 0) { ss[w] = s; sq[w] = q; }
    __syncthreads();
    s = ss[0] + ss[1] + ss[2] + ss[3];
    q = sq[0] + sq[1] + sq[2] + sq[3];
    float mean = s * (1.f / EDIM);
    float var = q * (1.f / EDIM) - mean * mean;
    float rstd = rsqrtf(var + 1e-5f);
    float o0 = (v0 - mean) * rstd * g[tid] + be[tid];
    float o1 = (v1 - mean) * rstd * g[tid + 256] + be[tid + 256];
    float* po = out + (long long)row * EDIM;
    u16* pb = out_bf + (long long)row * EDIM;
    po[tid] = o0;        po[tid + 256] = o1;
    pb[tid] = f2bf(o0);  pb[tid + 256] = f2bf(o1);
}

// two-stage coalesced mean-pool
__global__ __launch_bounds__(1024) void pool1_kernel(
    const float* __restrict__ h, float* __restrict__ part)
{
    int j = blockIdx.x;
    int idx = threadIdx.x;
    float s = 0.f;
    #pragma unroll 8
    for (int k = 0; k < 32; k++)
        s += h[(long long)(j * 32 + k) * 1024 + idx];
    part[j * 1024 + idx] = s;
}
__global__ __launch_bounds__(1024) void pool2_kernel(
    const float* __restrict__ part, float* __restrict__ pooled)
{
    int idx = threadIdx.x;
    float s = 0.f;
    #pragma unroll 8
    for (int j = 0; j < 32; j++) s += part[j * 1024 + idx];
    pooled[idx] = s * (1.f / 1024.f);
}

__global__ __launch_bounds__(256) void wavedot2_kernel(
    const float* __restrict__ v0, const float* __restrict__ v1,
    const float* __restrict__ W, const float* __restrict__ bias,
    float* __restrict__ out0, float* __restrict__ out1,
    int R, int K, int act)
{
    int gw = (blockIdx.x * 256 + threadIdx.x) >> 6;
    int lane = threadIdx.x & 63;
    int nw = (gridDim.x * 256) >> 6;
    const float4* x0 = (const float4*)v0;
    const float4* x1 = (const float4*)v1;
    for (int r = gw; r < R; r += nw) {
        const float4* w4 = (const float4*)(W + (long long)r * K);
        float a0 = 0.f, a1 = 0.f;
        for (int i = lane; i < (K >> 2); i += 64) {
            float4 w = w4[i];
            float4 p = x0[i];
            float4 q = x1[i];
            a0 += w.x * p.x + w.y * p.y + w.z * p.z + w.w * p.w;
            a1 += w.x * q.x + w.y * q.y + w.z * q.z + w.w * q.w;
        }
        #pragma unroll
        for (int off = 32; off; off >>= 1) {
            a0 += __shfl_xor(a0, off);
            a1 += __shfl_xor(a1, off);
        }
        if (lane == 0) {
            float bb = bias[r];
            float o0 = a0 + bb, o1 = a1 + bb;
            if (act == 1) { o0 = fmaxf(o0, 0.f); o1 = fmaxf(o1, 0.f); }
            out0[r] = o0; out1[r] = o1;
        }
    }
}

// Final per-sample MLP, 8 same-parity tokens per block.
__global__ __launch_bounds__(128) void final_mlp_kernel(
    const float* __restrict__ x, const float* __restrict__ flat,
    float* __restrict__ out)
{
    int g = blockIdx.x;
    int b = g >> 7;
    int j0 = (g & 127) * 8;
    int tid = threadIdx.x;
    const float* fl = flat + (long long)b * TOTALW;
    __shared__ float xs[8][FDIM], t1s[8][HDIM], t2s[8][HDIM];
    for (int i = tid; i < 8 * FDIM; i += 128) {
        int j = i / FDIM, f = i % FDIM;
        int t = (j0 + j) * 2 + b;
        xs[j][f] = nanfix(x[(long long)(NTOK + t) * FDIM + f]);
    }
    __syncthreads();
    {
        float acc[8];
        float b1 = fl[tid];
        #pragma unroll
        for (int j = 0; j < 8; j++) acc[j] = b1;
        const float* w1 = fl + HDIM;
        for (int f = 0; f < FDIM; f++) {
            float wv = w1[f * HDIM + tid];
            #pragma unroll
            for (int j = 0; j < 8; j++) acc[j] = fmaf(xs[j][f], wv, acc[j]);
        }
        #pragma unroll
        for (int j = 0; j < 8; j++) t1s[j][tid] = fmaxf(acc[j], 0.f);
    }
    __syncthreads();
    {
        float acc[8];
        float b2 = fl[12928 + tid];
        #pragma unroll
        for (int j = 0; j < 8; j++) acc[j] = b2;
        const float* w2 = fl + 13056;
        for (int hh = 0; hh < HDIM; hh++) {
            float wv = w2[hh * HDIM + tid];
            #pragma unroll
            for (int j = 0; j < 8; j++) acc[j] = fmaf(t1s[j][hh], wv, acc[j]);
        }
        #pragma unroll
        for (int j = 0; j < 8; j++) t2s[j][tid] = fmaxf(acc[j], 0.f);
    }
    __syncthreads();
    if (tid < NOUTD) {
        float acc[8];
        float b3 = fl[29440 + tid];
        #pragma unroll
        for (int j = 0; j < 8; j++) acc[j] = b3;
        const float* w3 = fl + 29450;
        for (int hh = 0; hh < HDIM; hh++) {
            float wv = w3[hh * NOUTD + tid];
            #pragma unroll
            for (int j = 0; j < 8; j++) acc[j] = fmaf(t2s[j][hh], wv, acc[j]);
        }
        #pragma unroll
        for (int j = 0; j < 8; j++) {
            int t = (j0 + j) * 2 + b;
            out[(long long)t * NOUTD + tid] = acc[j];
        }
    }
}

// ---------------------------------------------------------------------------
extern "C" void kernel_launch(void* const* d_in, const int* in_sizes, int n_in,
                              void* d_out, int out_size, void* d_ws, size_t ws_size,
                              hipStream_t stream) {
    const float* x      = (const float*)d_in[0];
    const float* y      = (const float*)d_in[1];
    const float* enc_w  = (const float*)d_in[2];
    const float* enc_b  = (const float*)d_in[3];
    const float* yenc_w = (const float*)d_in[4];
    const float* yenc_b = (const float*)d_in[5];
    const float* qkv_w  = (const float*)d_in[6];
    const float* qkv_b  = (const float*)d_in[7];
    const float* out_w  = (const float*)d_in[8];
    const float* out_b  = (const float*)d_in[9];
    const float* ln1_g  = (const float*)d_in[10];
    const float* ln1_b  = (const float*)d_in[11];
    const float* ln2_g  = (const float*)d_in[12];
    const float* ln2_b  = (const float*)d_in[13];
    const float* ff1_w  = (const float*)d_in[14];
    const float* ff1_b  = (const float*)d_in[15];
    const float* ff2_w  = (const float*)d_in[16];
    const float* ff2_b  = (const float*)d_in[17];
    const float* dec_w1 = (const float*)d_in[18];
    const float* dec_b1 = (const float*)d_in[19];
    const float* dec_w2 = (const float*)d_in[20];
    const float* dec_b2 = (const float*)d_in[21];

    float* ws     = (float*)d_ws;
    float* h      = ws;                                  // 1,048,576 f
    u16*   h_bf   = (u16*)(h + 1048576);                 // 1,048,576 u16
    u16*   qkv_bf = h_bf + 1048576;                      // 3,145,728 u16
    u16*   vt     = qkv_bf + 3145728;                    // 1,048,576 u16
    u16*   attn_bf= vt + 1048576;                        // 1,048,576 u16
    u16*   ffb_bf = attn_bf + 1048576;                   // 2,097,152 u16
    u16*   wq     = ffb_bf + 2097152;                    // 3,145,728 u16
    u16*   wo     = wq + 3145728;                        // 1,048,576 u16
    u16*   wf1    = wo + 1048576;                        // 2,097,152 u16
    u16*   wf2    = wf1 + 2097152;                       // 2,097,152 u16
    float* big    = (float*)(wf2 + 2097152);             // 1,048,576 f (partial 0)
    float* big2   = big + 1048576;                       // 1,048,576 f (partial 1)
    float* part   = big2 + 1048576;                      // 32,768
    float* pooled = part + 32768;                        // 1,024
    float* dbuf   = pooled + 1024;                       // 4,096
    float* flat   = dbuf + 4096;                         // 61,460

    cvt_all<<<4096, 256, 0, stream>>>(qkv_w, out_w, ff1_w, ff2_w, wq, wo, wf1, wf2);

    encoder_kernel<<<128, 512, 0, stream>>>(x, y, enc_w, enc_b, yenc_w, yenc_b, h, h_bf);

    const long long PSTRIDE = (long long)NTOK * EDIM;

    for (int l = 0; l < NLAYER; l++) {
        // qkv = h @ qkv_w[l].T + qkv_b[l]; Q,K -> qkv_bf, V -> vt (transposed)
        gemm2<<<dim3(24, 32, 1), 256, 0, stream>>>(
            h_bf, EDIM, wq + (size_t)l * 786432, EDIM,
            qkv_bf, 1536, 1, EDIM, 0, 1.f, qkv_b + (size_t)l * 1536, 0, vt);

        flash_attn<<<dim3(16, 16), 512, 0, stream>>>(qkv_bf, vt, attn_bf);

        // proj partials: split-K=2; bias folded into LN
        gemm2<<<dim3(8, 32, 2), 256, 0, stream>>>(
            attn_bf, EDIM, wo + (size_t)l * 262144, EDIM,
            big, EDIM, 0, 256, PSTRIDE, 1.f, nullptr, 0, nullptr);

        add_ln3_kernel<<<NTOK, 256, 0, stream>>>(h, big, big2,
            out_b + (size_t)l * EDIM,
            ln1_g + (size_t)l * EDIM, ln1_b + (size_t)l * EDIM, h, h_bf);

        // ffb = gelu(h @ ff1_w[l].T + ff1_b[l]) -> bf16 [2048 x 1024]
        gemm2<<<dim3(16, 32, 1), 256, 0, stream>>>(
            h_bf, EDIM, wf1 + (size_t)l * 524288, EDIM,
            ffb_bf, NHID, 1, EDIM, 0, 1.f, ff1_b + (size_t)l * NHID, 2, nullptr);

        // ff2 partials: split-K=2 (chunks of 512)
        gemm2<<<dim3(8, 32, 2), 256, 0, stream>>>(
            ffb_bf, NHID, wf2 + (size_t)l * 524288, NHID,
            big, EDIM, 0, 512, PSTRIDE, 1.f, nullptr, 0, nullptr);

        add_ln3_kernel<<<NTOK, 256, 0, stream>>>(h, big, big2,
            ff2_b + (size_t)l * EDIM,
            ln2_g + (size_t)l * EDIM, ln2_b + (size_t)l * EDIM, h, h_bf);
    }

    pool1_kernel<<<32, 1024, 0, stream>>>(h, part);
    pool2_kernel<<<1, 1024, 0, stream>>>(part, pooled);

    wavedot2_kernel<<<512, 256, 0, stream>>>(
        pooled, pooled + EDIM, dec_w1, dec_b1, dbuf, dbuf + DECD, DECD, EDIM, 1);

    wavedot2_kernel<<<7683, 256, 0, stream>>>(
        dbuf, dbuf + DECD, dec_w2, dec_b2, flat, flat + TOTALW, TOTALW, DECD, 0);

    final_mlp_kernel<<<256, 128, 0, stream>>>(x, flat, (float*)d_out);
}

// Round 12
// 427.902 us; speedup vs baseline: 7.4202x; 1.0100x over previous
//
#include <hip/hip_runtime.h>

// MotherNet forward — R12: flash kv-split x4 (1024-thread blocks, 4 waves/SIMD).
// Everything else identical to R11.

#define BATCH  2
#define FDIM   100
#define EDIM   512
#define NHEADS 8
#define HD     64
#define NHID   1024
#define NLAYER 4
#define HDIM   128
#define NOUTD  10
#define DECD   2048
#define SEPP   1024
#define TOTALW 30730
#define NTOK   2048

typedef unsigned short u16;
typedef __attribute__((ext_vector_type(8))) short bf16x8;
typedef __attribute__((ext_vector_type(4))) float f32x4;

__device__ __forceinline__ float nanfix(float v) {
    if (isnan(v)) return 0.f;
    if (isinf(v)) return v > 0.f ? 3.4028234663852886e38f : -3.4028234663852886e38f;
    return v;
}
__device__ __forceinline__ u16 f2bf(float f) {   // RTNE, finite inputs
    unsigned u = __float_as_uint(f);
    u += 0x7fffu + ((u >> 16) & 1u);
    return (u16)(u >> 16);
}
__device__ __forceinline__ float bf2f(u16 h) {
    return __uint_as_float(((unsigned)h) << 16);
}
// exact power-of-2 scale of a bf16x8 (unpack-mul-repack; mantissa preserved)
__device__ __forceinline__ bf16x8 scale8(bf16x8 a, float s) {
    bf16x8 r;
    #pragma unroll
    for (int i = 0; i < 8; i++) {
        float v = bf2f((u16)a[i]) * s;
        r[i] = (short)f2bf(v);
    }
    return r;
}

#define GLOAD16(gsrc, ldst) \
    __builtin_amdgcn_global_load_lds( \
        (const __attribute__((address_space(1))) void*)(gsrc), \
        (__attribute__((address_space(3))) void*)(ldst), 16, 0, 0)

// ---------------------------------------------------------------------------
// 3-buffer counted-vmcnt bf16 GEMM (R10 pipeline): C = act(alpha*A@B^T + bias)
// If vtout != nullptr and this block's cols are in the V range (>=1024), the
// tile is written TRANSPOSED to vt[((cb*8+hh)*64+d)*1024 + s] instead of C.
// ---------------------------------------------------------------------------
__global__ __launch_bounds__(256) void gemm2(
    const u16* __restrict__ A, int lda,
    const u16* __restrict__ B, int ldb,
    void* __restrict__ Cv, int ldc, int cbf,
    int K, long long zCstride, float alpha,
    const float* __restrict__ bias, int act,
    u16* __restrict__ vtout)
{
    __shared__ __align__(16) u16 lds[3][8192];

    int tid = threadIdx.x;
    int lane = tid & 63, w = tid >> 6;
    int wr = w >> 1, wc = w & 1;
    int mBase = blockIdx.y * 64, nBase = blockIdx.x * 64;
    int r16 = lane & 15, kg = lane >> 4;
    long long zk = (long long)blockIdx.z * K;
    long long offC = (long long)blockIdx.z * zCstride;

    int c0 = w * 64 + lane;
    int c1 = 256 + w * 64 + lane;
    int r0 = c0 >> 3, r1 = c1 >> 3;
    int e0 = ((((c0 & 7) * 16) ^ ((r0 & 7) << 4)) >> 1);
    int e1 = ((((c1 & 7) * 16) ^ ((r1 & 7) << 4)) >> 1);
    const u16* sA0 = A + (long long)(mBase + r0) * lda + e0 + zk;
    const u16* sA1 = A + (long long)(mBase + r1) * lda + e1 + zk;
    const u16* sB0 = B + (long long)(nBase + r0) * ldb + e0 + zk;
    const u16* sB1 = B + (long long)(nBase + r1) * ldb + e1 + zk;
    int dA0 = w * 512, dA1 = 2048 + w * 512;
    int dB0 = 4096 + w * 512, dB1 = 6144 + w * 512;

    int ra0 = wr * 32 + r16,      ra1 = wr * 32 + 16 + r16;
    int rb0 = wc * 32 + r16,      rb1 = wc * 32 + 16 + r16;
    int cb0 = kg * 16;
    int cb1 = 64 + kg * 16;
    int oa00 = (ra0 * 128 + (cb0 ^ ((ra0 & 7) << 4))) >> 1;
    int oa01 = (ra0 * 128 + (cb1 ^ ((ra0 & 7) << 4))) >> 1;
    int oa10 = (ra1 * 128 + (cb0 ^ ((ra1 & 7) << 4))) >> 1;
    int oa11 = (ra1 * 128 + (cb1 ^ ((ra1 & 7) << 4))) >> 1;
    int ob00 = 4096 + ((rb0 * 128 + (cb0 ^ ((rb0 & 7) << 4))) >> 1);
    int ob01 = 4096 + ((rb0 * 128 + (cb1 ^ ((rb0 & 7) << 4))) >> 1);
    int ob10 = 4096 + ((rb1 * 128 + (cb0 ^ ((rb1 & 7) << 4))) >> 1);
    int ob11 = 4096 + ((rb1 * 128 + (cb1 ^ ((rb1 & 7) << 4))) >> 1);

    f32x4 acc00 = {0.f, 0.f, 0.f, 0.f};
    f32x4 acc01 = acc00, acc10 = acc00, acc11 = acc00;

    int nt = K >> 6;   // >= 4 for all call sites

#define STAGE2(t, bi) { int ko_ = (t) << 6; \
    GLOAD16(sA0 + ko_, &lds[bi][dA0]); \
    GLOAD16(sA1 + ko_, &lds[bi][dA1]); \
    GLOAD16(sB0 + ko_, &lds[bi][dB0]); \
    GLOAD16(sB1 + ko_, &lds[bi][dB1]); }

    STAGE2(0, 0);
    STAGE2(1, 1);

    int cur = 0;
    for (int t = 0; t < nt; t++) {
        if (t == nt - 1) {
            asm volatile("s_waitcnt vmcnt(0)" ::: "memory");
        } else {
            asm volatile("s_waitcnt vmcnt(4)" ::: "memory");
        }
        __builtin_amdgcn_s_barrier();
        if (t + 2 < nt) {
            int tgt = cur - 1; if (tgt < 0) tgt += 3;
            STAGE2(t + 2, tgt);
        }
        const u16* L = &lds[cur][0];
        bf16x8 a0 = *(const bf16x8*)(L + oa00);
        bf16x8 a1 = *(const bf16x8*)(L + oa10);
        bf16x8 b0 = *(const bf16x8*)(L + ob00);
        bf16x8 b1 = *(const bf16x8*)(L + ob10);
        acc00 = __builtin_amdgcn_mfma_f32_16x16x32_bf16(a0, b0, acc00, 0, 0, 0);
        acc01 = __builtin_amdgcn_mfma_f32_16x16x32_bf16(a0, b1, acc01, 0, 0, 0);
        acc10 = __builtin_amdgcn_mfma_f32_16x16x32_bf16(a1, b0, acc10, 0, 0, 0);
        acc11 = __builtin_amdgcn_mfma_f32_16x16x32_bf16(a1, b1, acc11, 0, 0, 0);
        a0 = *(const bf16x8*)(L + oa01);
        a1 = *(const bf16x8*)(L + oa11);
        b0 = *(const bf16x8*)(L + ob01);
        b1 = *(const bf16x8*)(L + ob11);
        acc00 = __builtin_amdgcn_mfma_f32_16x16x32_bf16(a0, b0, acc00, 0, 0, 0);
        acc01 = __builtin_amdgcn_mfma_f32_16x16x32_bf16(a0, b1, acc01, 0, 0, 0);
        acc10 = __builtin_amdgcn_mfma_f32_16x16x32_bf16(a1, b0, acc10, 0, 0, 0);
        acc11 = __builtin_amdgcn_mfma_f32_16x16x32_bf16(a1, b1, acc11, 0, 0, 0);
        cur++; if (cur == 3) cur = 0;
    }
#undef STAGE2

    if (vtout && nBase >= 1024) {
        // ---- V block: transpose via LDS into vt, skip C store ----
        u16* T = &lds[0][0];                 // [m_local][d_local] 64x64 u16
        __syncthreads();
        #pragma unroll
        for (int i = 0; i < 2; i++) {
            #pragma unroll
            for (int j = 0; j < 2; j++) {
                f32x4 v = (i == 0) ? (j == 0 ? acc00 : acc01) : (j == 0 ? acc10 : acc11);
                int dl = wc * 32 + j * 16 + r16;
                float bv = bias ? bias[nBase + dl] : 0.f;
                #pragma unroll
                for (int r = 0; r < 4; r++) {
                    int ml = wr * 32 + i * 16 + kg * 4 + r;
                    T[ml * 64 + dl] = f2bf(v[r] * alpha + bv);
                }
            }
        }
        __syncthreads();
        int d = tid & 63, cbv = (tid >> 6) & 1, half = tid >> 7;
        int hh = (nBase - 1024) >> 6;
        long long orow = ((long long)(cbv * 8 + hh) * 64 + d) * 1024 + (mBase >> 1) + half * 16;
        bf16x8 v0, v1;
        #pragma unroll
        for (int k = 0; k < 8; k++) {
            v0[k] = (short)T[((half * 16 + k) * 2 + cbv) * 64 + d];
            v1[k] = (short)T[((half * 16 + 8 + k) * 2 + cbv) * 64 + d];
        }
        *(bf16x8*)(vtout + orow) = v0;
        *(bf16x8*)(vtout + orow + 8) = v1;
        return;
    }

    #pragma unroll
    for (int i = 0; i < 2; i++) {
        #pragma unroll
        for (int j = 0; j < 2; j++) {
            f32x4 v = (i == 0) ? (j == 0 ? acc00 : acc01) : (j == 0 ? acc10 : acc11);
            int col = nBase + wc * 32 + j * 16 + r16;
            float bv = bias ? bias[col] : 0.f;
            long long base = offC + (long long)(mBase + wr * 32 + i * 16 + kg * 4) * ldc + col;
            #pragma unroll
            for (int r = 0; r < 4; r++) {
                float c = v[r] * alpha + bv;
                if (act == 2) {  // jax.nn.gelu approximate=True
                    float u = 0.7978845608028654f * (c + 0.044715f * c * c * c);
                    c = 0.5f * c * (1.f + tanhf(u));
                }
                if (cbf) ((u16*)Cv)[base + (long long)r * ldc] = f2bf(c);
                else     ((float*)Cv)[base + (long long)r * ldc] = c;
            }
        }
    }
}

// ---------------------------------------------------------------------------
// Flash v4: defer-max (m == 0), kv-split x4. 1024 threads = 16 waves.
// Wave w: q-strip p=w&3 (16 rows), kv-quarter qf=w>>2 (256 keys).
// Per-wave private P tile in LDS; 4-way plain-sum merge at the end.
// ---------------------------------------------------------------------------
__global__ __launch_bounds__(1024) void flash_attn(
    const u16* __restrict__ qkvb, const u16* __restrict__ vtm,
    u16* __restrict__ attnb)
{
    int qt = blockIdx.x;
    int bh = blockIdx.y;
    int cb = bh >> 3, hh = bh & 7;
    int tid = threadIdx.x;
    int w = tid >> 6, lane = tid & 63;
    int p = w & 3, qf = w >> 2;
    int r16 = lane & 15, kg = lane >> 4;

    __shared__ __align__(16) u16 plds[16][2048];   // 64 KB: P tiles, then merge buf
    u16* pl = &plds[w][0];

    int qrow = qt * 64 + p * 16 + r16;
    const u16* qp = qkvb + ((long long)qrow * 2 + cb) * 1536 + hh * 64 + kg * 8;
    bf16x8 qf0 = scale8(*(const bf16x8*)(qp), 0.125f);
    bf16x8 qf1 = scale8(*(const bf16x8*)(qp + 32), 0.125f);

    const u16* kbase = qkvb + (long long)cb * 1536 + 512 + hh * 64;
    const u16* vbase = vtm + ((long long)bh * 64) * 1024;

    f32x4 l = {0.f, 0.f, 0.f, 0.f};
    f32x4 o[4] = {};

    int rb0 = (((r16 * 64 + kg * 8) * 2) ^ ((r16 & 7) << 4)) >> 1;
    int rb1 = (((r16 * 64 + 32 + kg * 8) * 2) ^ ((r16 & 7) << 4)) >> 1;

    for (int kt = qf * 4; kt < qf * 4 + 4; kt++) {
        f32x4 s[4];
        #pragma unroll
        for (int nb = 0; nb < 4; nb++) {
            int key = kt * 64 + nb * 16 + r16;
            const u16* kp = kbase + (long long)key * 3072 + kg * 8;
            bf16x8 kf0 = *(const bf16x8*)(kp);
            bf16x8 kf1 = *(const bf16x8*)(kp + 32);
            f32x4 acc = {};
            acc = __builtin_amdgcn_mfma_f32_16x16x32_bf16(qf0, kf0, acc, 0, 0, 0);
            acc = __builtin_amdgcn_mfma_f32_16x16x32_bf16(qf1, kf1, acc, 0, 0, 0);
            s[nb] = acc;
        }
        // P = exp(S) (no max subtraction), accumulate row-sums
        f32x4 rs = {};
        #pragma unroll
        for (int nb = 0; nb < 4; nb++)
            #pragma unroll
            for (int r = 0; r < 4; r++) {
                float pv = __expf(s[nb][r]);
                s[nb][r] = pv;
                rs[r] += pv;
            }
        #pragma unroll
        for (int off = 1; off < 16; off <<= 1) {
            #pragma unroll
            for (int r = 0; r < 4; r++) rs[r] += __shfl_xor(rs[r], off);
        }
        #pragma unroll
        for (int r = 0; r < 4; r++) l[r] += rs[r];

        // P -> per-wave LDS (swizzled, wave-private)
        #pragma unroll
        for (int nb = 0; nb < 4; nb++)
            #pragma unroll
            for (int r = 0; r < 4; r++) {
                int row = kg * 4 + r;
                int col = nb * 16 + r16;
                int byi = (((row * 64 + col) * 2) ^ ((row & 7) << 4)) >> 1;
                pl[byi] = f2bf(s[nb][r]);
            }

        bf16x8 pa0 = *(const bf16x8*)(pl + rb0);
        bf16x8 pa1 = *(const bf16x8*)(pl + rb1);
        #pragma unroll
        for (int db = 0; db < 4; db++) {
            const u16* vp = vbase + (long long)(db * 16 + r16) * 1024 + kt * 64 + kg * 8;
            bf16x8 vf0 = *(const bf16x8*)(vp);
            bf16x8 vf1 = *(const bf16x8*)(vp + 32);
            o[db] = __builtin_amdgcn_mfma_f32_16x16x32_bf16(pa0, vf0, o[db], 0, 0, 0);
            o[db] = __builtin_amdgcn_mfma_f32_16x16x32_bf16(pa1, vf1, o[db], 0, 0, 0);
        }
    }

    // ---- 4-way merge: plain sums (all quarters used m == 0) ----
    __syncthreads();
    float* fb = (float*)&plds[0][0];        // 12 producer waves x 64 lanes x 20 f
    if (qf < 3) {
        int base = ((qf * 4 + p) * 64 + lane) * 20;
        #pragma unroll
        for (int r = 0; r < 4; r++) fb[base + r] = l[r];
        #pragma unroll
        for (int db = 0; db < 4; db++)
            #pragma unroll
            for (int r = 0; r < 4; r++) fb[base + 4 + db * 4 + r] = o[db][r];
    }
    __syncthreads();
    if (qf == 3) {
        #pragma unroll
        for (int q2 = 0; q2 < 3; q2++) {
            int base = ((q2 * 4 + p) * 64 + lane) * 20;
            #pragma unroll
            for (int r = 0; r < 4; r++) l[r] += fb[base + r];
            #pragma unroll
            for (int db = 0; db < 4; db++)
                #pragma unroll
                for (int r = 0; r < 4; r++) o[db][r] += fb[base + 4 + db * 4 + r];
        }
        f32x4 linv;
        #pragma unroll
        for (int r = 0; r < 4; r++) linv[r] = 1.f / l[r];
        #pragma unroll
        for (int db = 0; db < 4; db++)
            #pragma unroll
            for (int r = 0; r < 4; r++) {
                float val = o[db][r] * linv[r];
                int row = qt * 64 + p * 16 + kg * 4 + r;
                attnb[((long long)row * 2 + cb) * 512 + hh * 64 + db * 16 + r16] = f2bf(val);
            }
    }
}

// merged f32->bf16 convert for the 4 transformer weight tensors
__global__ __launch_bounds__(256) void cvt_all(
    const float* __restrict__ s0, const float* __restrict__ s1,
    const float* __restrict__ s2, const float* __restrict__ s3,
    u16* __restrict__ d0, u16* __restrict__ d1,
    u16* __restrict__ d2, u16* __restrict__ d3)
{
    const int n0 = 3145728, n1 = 1048576, n2 = 2097152, n3 = 2097152;
    int i = blockIdx.x * 256 + threadIdx.x;
    int st = gridDim.x * 256;
    for (; i < n0 + n1 + n2 + n3; i += st) {
        if (i < n0) d0[i] = f2bf(s0[i]);
        else if (i < n0 + n1) d1[i - n0] = f2bf(s1[i - n0]);
        else if (i < n0 + n1 + n2) d2[i - n0 - n1] = f2bf(s2[i - n0 - n1]);
        else d3[i - n0 - n1 - n2] = f2bf(s3[i - n0 - n1 - n2]);
    }
}

// Encoder, 16 tokens per block
__global__ __launch_bounds__(512) void encoder_kernel(
    const float* __restrict__ x, const float* __restrict__ y,
    const float* __restrict__ enc_w, const float* __restrict__ enc_b,
    const float* __restrict__ yenc_w, const float* __restrict__ yenc_b,
    float* __restrict__ h, u16* __restrict__ h_bf)
{
    int g = blockIdx.x;
    int tid = threadIdx.x;
    __shared__ float xs[16][FDIM];
    __shared__ float ys[16];
    for (int i = tid; i < 16 * FDIM; i += 512) {
        int tk = i / FDIM, f = i % FDIM;
        xs[tk][f] = nanfix(x[(long long)(g * 16 + tk) * FDIM + f]);
    }
    if (tid < 16) ys[tid] = y[g * 16 + tid];
    __syncthreads();
    float base = enc_b[tid] + yenc_b[tid];
    float yw = yenc_w[tid];
    const float* wr = enc_w + (long long)tid * FDIM;
    float acc[16];
    #pragma unroll
    for (int j = 0; j < 16; j++) acc[j] = 0.f;
    for (int f = 0; f < FDIM; f++) {
        float wv = wr[f];
        #pragma unroll
        for (int j = 0; j < 16; j++) acc[j] = fmaf(xs[j][f], wv, acc[j]);
    }
    #pragma unroll
    for (int j = 0; j < 16; j++) {
        float v = base + ys[j] * yw + acc[j];
        long long t = g * 16 + j;
        h[t * EDIM + tid] = v;
        h_bf[t * EDIM + tid] = f2bf(v);
    }
}

// out = LN(a + p0 + p1 + cbias)*g + be ; writes f32 + bf16. a may alias out.
__global__ __launch_bounds__(256) void add_ln3_kernel(
    const float* a, const float* __restrict__ p0, const float* __restrict__ p1,
    const float* __restrict__ cbias,
    const float* __restrict__ g, const float* __restrict__ be,
    float* out, u16* __restrict__ out_bf)
{
    int row = blockIdx.x;
    int tid = threadIdx.x;
    const float* pa = a + (long long)row * EDIM;
    const float* pr0 = p0 + (long long)row * EDIM;
    const float* pr1 = p1 + (long long)row * EDIM;
    float v0 = pa[tid] + pr0[tid] + pr1[tid] + cbias[tid];
    float v1 = pa[tid + 256] + pr0[tid + 256] + pr1[tid + 256] + cbias[tid + 256];
    float s = v0 + v1, q = v0 * v0 + v1 * v1;
    #pragma unroll
    for (int off = 32; off; off >>= 1) {
        s += __shfl_xor(s, off);
        q += __shfl_xor(q, off);
    }
    __shared__ float ss[4], sq[4];
    int w = tid >> 6, lane = tid & 63;
    if (lane == 0) { ss[w] = s; sq[w] = q; }
    __syncthreads();
    s = ss[0] + ss[1] + ss[2] + ss[3];
    q = sq[0] + sq[1] + sq[2] + sq[3];
    float mean = s * (1.f / EDIM);
    float var = q * (1.f / EDIM) - mean * mean;
    float rstd = rsqrtf(var + 1e-5f);
    float o0 = (v0 - mean) * rstd * g[tid] + be[tid];
    float o1 = (v1 - mean) * rstd * g[tid + 256] + be[tid + 256];
    float* po = out + (long long)row * EDIM;
    u16* pb = out_bf + (long long)row * EDIM;
    po[tid] = o0;        po[tid + 256] = o1;
    pb[tid] = f2bf(o0);  pb[tid + 256] = f2bf(o1);
}

// two-stage coalesced mean-pool
__global__ __launch_bounds__(1024) void pool1_kernel(
    const float* __restrict__ h, float* __restrict__ part)
{
    int j = blockIdx.x;
    int idx = threadIdx.x;
    float s = 0.f;
    #pragma unroll 8
    for (int k = 0; k < 32; k++)
        s += h[(long long)(j * 32 + k) * 1024 + idx];
    part[j * 1024 + idx] = s;
}
__global__ __launch_bounds__(1024) void pool2_kernel(
    const float* __restrict__ part, float* __restrict__ pooled)
{
    int idx = threadIdx.x;
    float s = 0.f;
    #pragma unroll 8
    for (int j = 0; j < 32; j++) s += part[j * 1024 + idx];
    pooled[idx] = s * (1.f / 1024.f);
}

__global__ __launch_bounds__(256) void wavedot2_kernel(
    const float* __restrict__ v0, const float* __restrict__ v1,
    const float* __restrict__ W, const float* __restrict__ bias,
    float* __restrict__ out0, float* __restrict__ out1,
    int R, int K, int act)
{
    int gw = (blockIdx.x * 256 + threadIdx.x) >> 6;
    int lane = threadIdx.x & 63;
    int nw = (gridDim.x * 256) >> 6;
    const float4* x0 = (const float4*)v0;
    const float4* x1 = (const float4*)v1;
    for (int r = gw; r < R; r += nw) {
        const float4* w4 = (const float4*)(W + (long long)r * K);
        float a0 = 0.f, a1 = 0.f;
        for (int i = lane; i < (K >> 2); i += 64) {
            float4 w = w4[i];
            float4 p = x0[i];
            float4 q = x1[i];
            a0 += w.x * p.x + w.y * p.y + w.z * p.z + w.w * p.w;
            a1 += w.x * q.x + w.y * q.y + w.z * q.z + w.w * q.w;
        }
        #pragma unroll
        for (int off = 32; off; off >>= 1) {
            a0 += __shfl_xor(a0, off);
            a1 += __shfl_xor(a1, off);
        }
        if (lane == 0) {
            float bb = bias[r];
            float o0 = a0 + bb, o1 = a1 + bb;
            if (act == 1) { o0 = fmaxf(o0, 0.f); o1 = fmaxf(o1, 0.f); }
            out0[r] = o0; out1[r] = o1;
        }
    }
}

// Final per-sample MLP, 8 same-parity tokens per block.
__global__ __launch_bounds__(128) void final_mlp_kernel(
    const float* __restrict__ x, const float* __restrict__ flat,
    float* __restrict__ out)
{
    int g = blockIdx.x;
    int b = g >> 7;
    int j0 = (g & 127) * 8;
    int tid = threadIdx.x;
    const float* fl = flat + (long long)b * TOTALW;
    __shared__ float xs[8][FDIM], t1s[8][HDIM], t2s[8][HDIM];
    for (int i = tid; i < 8 * FDIM; i += 128) {
        int j = i / FDIM, f = i % FDIM;
        int t = (j0 + j) * 2 + b;
        xs[j][f] = nanfix(x[(long long)(NTOK + t) * FDIM + f]);
    }
    __syncthreads();
    {
        float acc[8];
        float b1 = fl[tid];
        #pragma unroll
        for (int j = 0; j < 8; j++) acc[j] = b1;
        const float* w1 = fl + HDIM;
        for (int f = 0; f < FDIM; f++) {
            float wv = w1[f * HDIM + tid];
            #pragma unroll
            for (int j = 0; j < 8; j++) acc[j] = fmaf(xs[j][f], wv, acc[j]);
        }
        #pragma unroll
        for (int j = 0; j < 8; j++) t1s[j][tid] = fmaxf(acc[j], 0.f);
    }
    __syncthreads();
    {
        float acc[8];
        float b2 = fl[12928 + tid];
        #pragma unroll
        for (int j = 0; j < 8; j++) acc[j] = b2;
        const float* w2 = fl + 13056;
        for (int hh = 0; hh < HDIM; hh++) {
            float wv = w2[hh * HDIM + tid];
            #pragma unroll
            for (int j = 0; j < 8; j++) acc[j] = fmaf(t1s[j][hh], wv, acc[j]);
        }
        #pragma unroll
        for (int j = 0; j < 8; j++) t2s[j][tid] = fmaxf(acc[j], 0.f);
    }
    __syncthreads();
    if (tid < NOUTD) {
        float acc[8];
        float b3 = fl[29440 + tid];
        #pragma unroll
        for (int j = 0; j < 8; j++) acc[j] = b3;
        const float* w3 = fl + 29450;
        for (int hh = 0; hh < HDIM; hh++) {
            float wv = w3[hh * NOUTD + tid];
            #pragma unroll
            for (int j = 0; j < 8; j++) acc[j] = fmaf(t2s[j][hh], wv, acc[j]);
        }
        #pragma unroll
        for (int j = 0; j < 8; j++) {
            int t = (j0 + j) * 2 + b;
            out[(long long)t * NOUTD + tid] = acc[j];
        }
    }
}

// ---------------------------------------------------------------------------
extern "C" void kernel_launch(void* const* d_in, const int* in_sizes, int n_in,
                              void* d_out, int out_size, void* d_ws, size_t ws_size,
                              hipStream_t stream) {
    const float* x      = (const float*)d_in[0];
    const float* y      = (const float*)d_in[1];
    const float* enc_w  = (const float*)d_in[2];
    const float* enc_b  = (const float*)d_in[3];
    const float* yenc_w = (const float*)d_in[4];
    const float* yenc_b = (const float*)d_in[5];
    const float* qkv_w  = (const float*)d_in[6];
    const float* qkv_b  = (const float*)d_in[7];
    const float* out_w  = (const float*)d_in[8];
    const float* out_b  = (const float*)d_in[9];
    const float* ln1_g  = (const float*)d_in[10];
    const float* ln1_b  = (const float*)d_in[11];
    const float* ln2_g  = (const float*)d_in[12];
    const float* ln2_b  = (const float*)d_in[13];
    const float* ff1_w  = (const float*)d_in[14];
    const float* ff1_b  = (const float*)d_in[15];
    const float* ff2_w  = (const float*)d_in[16];
    const float* ff2_b  = (const float*)d_in[17];
    const float* dec_w1 = (const float*)d_in[18];
    const float* dec_b1 = (const float*)d_in[19];
    const float* dec_w2 = (const float*)d_in[20];
    const float* dec_b2 = (const float*)d_in[21];

    float* ws     = (float*)d_ws;
    float* h      = ws;                                  // 1,048,576 f
    u16*   h_bf   = (u16*)(h + 1048576);                 // 1,048,576 u16
    u16*   qkv_bf = h_bf + 1048576;                      // 3,145,728 u16
    u16*   vt     = qkv_bf + 3145728;                    // 1,048,576 u16
    u16*   attn_bf= vt + 1048576;                        // 1,048,576 u16
    u16*   ffb_bf = attn_bf + 1048576;                   // 2,097,152 u16
    u16*   wq     = ffb_bf + 2097152;                    // 3,145,728 u16
    u16*   wo     = wq + 3145728;                        // 1,048,576 u16
    u16*   wf1    = wo + 1048576;                        // 2,097,152 u16
    u16*   wf2    = wf1 + 2097152;                       // 2,097,152 u16
    float* big    = (float*)(wf2 + 2097152);             // 1,048,576 f (partial 0)
    float* big2   = big + 1048576;                       // 1,048,576 f (partial 1)
    float* part   = big2 + 1048576;                      // 32,768
    float* pooled = part + 32768;                        // 1,024
    float* dbuf   = pooled + 1024;                       // 4,096
    float* flat   = dbuf + 4096;                         // 61,460

    cvt_all<<<4096, 256, 0, stream>>>(qkv_w, out_w, ff1_w, ff2_w, wq, wo, wf1, wf2);

    encoder_kernel<<<128, 512, 0, stream>>>(x, y, enc_w, enc_b, yenc_w, yenc_b, h, h_bf);

    const long long PSTRIDE = (long long)NTOK * EDIM;

    for (int l = 0; l < NLAYER; l++) {
        // qkv = h @ qkv_w[l].T + qkv_b[l]; Q,K -> qkv_bf, V -> vt (transposed)
        gemm2<<<dim3(24, 32, 1), 256, 0, stream>>>(
            h_bf, EDIM, wq + (size_t)l * 786432, EDIM,
            qkv_bf, 1536, 1, EDIM, 0, 1.f, qkv_b + (size_t)l * 1536, 0, vt);

        flash_attn<<<dim3(16, 16), 1024, 0, stream>>>(qkv_bf, vt, attn_bf);

        // proj partials: split-K=2; bias folded into LN
        gemm2<<<dim3(8, 32, 2), 256, 0, stream>>>(
            attn_bf, EDIM, wo + (size_t)l * 262144, EDIM,
            big, EDIM, 0, 256, PSTRIDE, 1.f, nullptr, 0, nullptr);

        add_ln3_kernel<<<NTOK, 256, 0, stream>>>(h, big, big2,
            out_b + (size_t)l * EDIM,
            ln1_g + (size_t)l * EDIM, ln1_b + (size_t)l * EDIM, h, h_bf);

        // ffb = gelu(h @ ff1_w[l].T + ff1_b[l]) -> bf16 [2048 x 1024]
        gemm2<<<dim3(16, 32, 1), 256, 0, stream>>>(
            h_bf, EDIM, wf1 + (size_t)l * 524288, EDIM,
            ffb_bf, NHID, 1, EDIM, 0, 1.f, ff1_b + (size_t)l * NHID, 2, nullptr);

        // ff2 partials: split-K=2 (chunks of 512)
        gemm2<<<dim3(8, 32, 2), 256, 0, stream>>>(
            ffb_bf, NHID, wf2 + (size_t)l * 524288, NHID,
            big, EDIM, 0, 512, PSTRIDE, 1.f, nullptr, 0, nullptr);

        add_ln3_kernel<<<NTOK, 256, 0, stream>>>(h, big, big2,
            ff2_b + (size_t)l * EDIM,
            ln2_g + (size_t)l * EDIM, ln2_b + (size_t)l * EDIM, h, h_bf);
    }

    pool1_kernel<<<32, 1024, 0, stream>>>(h, part);
    pool2_kernel<<<1, 1024, 0, stream>>>(part, pooled);

    wavedot2_kernel<<<512, 256, 0, stream>>>(
        pooled, pooled + EDIM, dec_w1, dec_b1, dbuf, dbuf + DECD, DECD, EDIM, 1);

    wavedot2_kernel<<<7683, 256, 0, stream>>>(
        dbuf, dbuf + DECD, dec_w2, dec_b2, flat, flat + TOTALW, TOTALW, DECD, 0);

    final_mlp_kernel<<<256, 128, 0, stream>>>(x, flat, (float*)d_out);
}